// Round 1
// baseline (1773.901 us; speedup 1.0000x reference)
//
#include <hip/hip_runtime.h>
#include <math.h>

#define LN_EPS 1e-5f

__global__ __launch_bounds__(128) void asmlp_fwd(
    const float* __restrict__ x,
    const float* __restrict__ Wv, const float* __restrict__ bv,
    const float* __restrict__ Wm, const float* __restrict__ bm,
    const float* __restrict__ Wi, const float* __restrict__ bi,
    const float* __restrict__ Wb, const float* __restrict__ bb,
    const float* __restrict__ Wc, const float* __restrict__ bc,
    const float* __restrict__ Wf, const float* __restrict__ bff,
    const float* __restrict__ Pv, const float* __restrict__ pv,
    const float* __restrict__ Pm, const float* __restrict__ pm,
    const float* __restrict__ Pi, const float* __restrict__ pii,
    const float* __restrict__ Pb, const float* __restrict__ pb,
    const float* __restrict__ Pc, const float* __restrict__ pc,
    const float* __restrict__ Pf, const float* __restrict__ pf,
    const float* __restrict__ Wqkv, const float* __restrict__ bqkv,
    const float* __restrict__ Wo, const float* __restrict__ bo,
    const float* __restrict__ gg, const float* __restrict__ beta,
    const float* __restrict__ Wp, const float* __restrict__ bp,
    float* __restrict__ out)
{
    const int row = blockIdx.x;
    const int t   = threadIdx.x;

    __shared__ float sx[32];
    __shared__ float sh[384];        // hv[0:64] hm[64:128] hi[128:160] hb[160:192] hc[192:256] hf[256:384]
    __shared__ float stok[6][128];
    __shared__ float sqkv[6][384];
    __shared__ float sattn[4][6][6];
    __shared__ float sctx[6][128];
    __shared__ float sh2[6][128];
    __shared__ float spool[128];
    __shared__ float sred[2][2];

    // ---- load x row ----
    if (t < 29) sx[t] = x[(size_t)row * 29 + t];
    __syncthreads();

    // ---- component encoders (Linear + ReLU) ----
    #pragma unroll
    for (int rep = 0; rep < 3; ++rep) {
        int u = t + rep * 128;
        const float* W; const float* bias; int din, xoff, j, dout;
        if (u < 64)       { W = Wv;  bias = bv;  din = 3;  xoff = 0;  j = u;       dout = 64;  }
        else if (u < 128) { W = Wm;  bias = bm;  din = 5;  xoff = 3;  j = u - 64;  dout = 64;  }
        else if (u < 160) { W = Wi;  bias = bi;  din = 2;  xoff = 8;  j = u - 128; dout = 32;  }
        else if (u < 192) { W = Wb;  bias = bb;  din = 3;  xoff = 10; j = u - 160; dout = 32;  }
        else if (u < 256) { W = Wc;  bias = bc;  din = 6;  xoff = 13; j = u - 192; dout = 64;  }
        else              { W = Wf;  bias = bff; din = 10; xoff = 19; j = u - 256; dout = 128; }
        float acc = bias[j];
        for (int i = 0; i < din; ++i) acc += sx[xoff + i] * W[i * dout + j];
        sh[u] = fmaxf(acc, 0.0f);
    }
    __syncthreads();

    // ---- projections to 6 tokens of dim 128 ----
#define PROJ(cidx, base, K, P, pvec)                                   \
    {                                                                  \
        float acc = pvec[t];                                           \
        _Pragma("unroll 8")                                            \
        for (int k = 0; k < K; ++k) acc += sh[(base) + k] * P[k * 128 + t]; \
        stok[cidx][t] = acc;                                           \
    }
    PROJ(0, 0,   64,  Pv, pv)
    PROJ(1, 64,  64,  Pm, pm)
    PROJ(2, 128, 32,  Pi, pii)
    PROJ(3, 160, 32,  Pb, pb)
    PROJ(4, 192, 64,  Pc, pc)
    PROJ(5, 256, 128, Pf, pf)
#undef PROJ
    __syncthreads();

    // ---- QKV: [6,128] @ [128,384] + bias ----
    for (int rep = 0; rep < 3; ++rep) {
        int j = t + rep * 128;
        float bj = bqkv[j];
        float acc[6];
        #pragma unroll
        for (int c = 0; c < 6; ++c) acc[c] = bj;
        #pragma unroll 4
        for (int k = 0; k < 128; ++k) {
            float w = Wqkv[k * 384 + j];
            #pragma unroll
            for (int c = 0; c < 6; ++c) acc[c] += stok[c][k] * w;
        }
        #pragma unroll
        for (int c = 0; c < 6; ++c) sqkv[c][j] = acc[c];
    }
    __syncthreads();

    // ---- attention scores + softmax (4 heads, 6x6) ----
    for (int idx = t; idx < 144; idx += 128) {
        int h = idx / 36, r = idx % 36, qi = r / 6, ki = r % 6;
        const float* q  = &sqkv[qi][h * 32];
        const float* kk = &sqkv[ki][128 + h * 32];
        float s = 0.0f;
        #pragma unroll 8
        for (int d = 0; d < 32; ++d) s += q[d] * kk[d];
        sattn[h][qi][ki] = s * 0.17677669529663687f;   // 1/sqrt(32)
    }
    __syncthreads();
    if (t < 24) {
        int h = t / 6, qi = t % 6;
        float m = sattn[h][qi][0];
        #pragma unroll
        for (int ki = 1; ki < 6; ++ki) m = fmaxf(m, sattn[h][qi][ki]);
        float e[6]; float s = 0.0f;
        #pragma unroll
        for (int ki = 0; ki < 6; ++ki) { e[ki] = __expf(sattn[h][qi][ki] - m); s += e[ki]; }
        float inv = 1.0f / s;
        #pragma unroll
        for (int ki = 0; ki < 6; ++ki) sattn[h][qi][ki] = e[ki] * inv;
    }
    __syncthreads();

    // ---- ctx = attn @ v ----
    {
        int h = t >> 5, d = t & 31;
        #pragma unroll
        for (int qi = 0; qi < 6; ++qi) {
            float acc = 0.0f;
            #pragma unroll
            for (int ki = 0; ki < 6; ++ki)
                acc += sattn[h][qi][ki] * sqkv[ki][256 + h * 32 + d];
            sctx[qi][t] = acc;
        }
    }
    __syncthreads();

    // ---- out proj + residual ----
    {
        float bj = bo[t];
        float acc[6];
        #pragma unroll
        for (int c = 0; c < 6; ++c) acc[c] = bj;
        #pragma unroll 4
        for (int k = 0; k < 128; ++k) {
            float w = Wo[k * 128 + t];
            #pragma unroll
            for (int c = 0; c < 6; ++c) acc[c] += sctx[c][k] * w;
        }
        #pragma unroll
        for (int c = 0; c < 6; ++c) sh2[c][t] = stok[c][t] + acc[c];
    }
    __syncthreads();

    // ---- layernorm per token + mean-pool ----
    {
        float gt = gg[t], bt = beta[t];
        float pool = 0.0f;
        for (int c = 0; c < 6; ++c) {
            float val = sh2[c][t];
            float s1 = val, s2 = val * val;
            #pragma unroll
            for (int off = 32; off > 0; off >>= 1) {
                s1 += __shfl_xor(s1, off, 64);
                s2 += __shfl_xor(s2, off, 64);
            }
            int wid = t >> 6, lane = t & 63;
            if (lane == 0) { sred[wid][0] = s1; sred[wid][1] = s2; }
            __syncthreads();
            float sum   = sred[0][0] + sred[1][0];
            float sumsq = sred[0][1] + sred[1][1];
            __syncthreads();
            float mu  = sum * (1.0f / 128.0f);
            float var = sumsq * (1.0f / 128.0f) - mu * mu;
            float nv  = (val - mu) * rsqrtf(var + LN_EPS) * gt + bt;
            pool += nv;
        }
        spool[t] = pool * (1.0f / 6.0f);
    }
    __syncthreads();

    // ---- pool projection + relu ----
    {
        float* orow = out + (size_t)row * 256;
        #pragma unroll
        for (int rep = 0; rep < 2; ++rep) {
            int o = t + rep * 128;
            float acc = bp[o];
            #pragma unroll 4
            for (int k = 0; k < 128; ++k) acc += spool[k] * Wp[k * 256 + o];
            orow[o] = fmaxf(acc, 0.0f);
        }
    }
}

extern "C" void kernel_launch(void* const* d_in, const int* in_sizes, int n_in,
                              void* d_out, int out_size, void* d_ws, size_t ws_size,
                              hipStream_t stream) {
    const float* x    = (const float*)d_in[0];
    const float* Wv   = (const float*)d_in[1];
    const float* bv   = (const float*)d_in[2];
    const float* Wm   = (const float*)d_in[3];
    const float* bm   = (const float*)d_in[4];
    const float* Wi   = (const float*)d_in[5];
    const float* bi   = (const float*)d_in[6];
    const float* Wb   = (const float*)d_in[7];
    const float* bb   = (const float*)d_in[8];
    const float* Wc   = (const float*)d_in[9];
    const float* bc   = (const float*)d_in[10];
    const float* Wf   = (const float*)d_in[11];
    const float* bff  = (const float*)d_in[12];
    const float* Pv   = (const float*)d_in[13];
    const float* pv   = (const float*)d_in[14];
    const float* Pm   = (const float*)d_in[15];
    const float* pm   = (const float*)d_in[16];
    const float* Pi   = (const float*)d_in[17];
    const float* pii  = (const float*)d_in[18];
    const float* Pb   = (const float*)d_in[19];
    const float* pb   = (const float*)d_in[20];
    const float* Pc   = (const float*)d_in[21];
    const float* pc   = (const float*)d_in[22];
    const float* Pf   = (const float*)d_in[23];
    const float* pf   = (const float*)d_in[24];
    const float* Wqkv = (const float*)d_in[25];
    const float* bqkv = (const float*)d_in[26];
    const float* Wo   = (const float*)d_in[27];
    const float* bo   = (const float*)d_in[28];
    const float* gg   = (const float*)d_in[29];
    const float* beta = (const float*)d_in[30];
    const float* Wp   = (const float*)d_in[31];
    const float* bp   = (const float*)d_in[32];
    float* out = (float*)d_out;

    const int Bn = in_sizes[0] / 29;
    asmlp_fwd<<<Bn, 128, 0, stream>>>(
        x, Wv, bv, Wm, bm, Wi, bi, Wb, bb, Wc, bc, Wf, bff,
        Pv, pv, Pm, pm, Pi, pii, Pb, pb, Pc, pc, Pf, pf,
        Wqkv, bqkv, Wo, bo, gg, beta, Wp, bp, out);
}

// Round 2
// 338.128 us; speedup vs baseline: 5.2462x; 5.2462x over previous
//
#include <hip/hip_runtime.h>
#include <math.h>

typedef float f32x4 __attribute__((ext_vector_type(4)));
typedef short short8 __attribute__((ext_vector_type(8)));
typedef unsigned short u16;

#define LN_EPS 1e-5f

__device__ __forceinline__ u16 f2bf(float f) {
    unsigned int x = __float_as_uint(f);
    return (u16)((x + 0x7fffu + ((x >> 16) & 1u)) >> 16);
}
__device__ __forceinline__ float bf2f(u16 u) {
    return __uint_as_float(((unsigned int)u) << 16);
}

// ws segment offsets (ushort elements), MFMA-B-fragment-linear layout:
// idx = ((ntile*Ksteps + kk)*64 + lane)*8 + j  ->  W[kk*32+(lane>>4)*8+j][ntile*16+(lane&15)]
#define OFF_QKV 0
#define OFF_WO  49152
#define OFF_WP  65536
#define OFF_PV  98304
#define OFF_PM  106496
#define OFF_PI  114688
#define OFF_PB  118784
#define OFF_PC  122880
#define OFF_PF  131072
#define WS_ELEMS 147456

__global__ __launch_bounds__(512) void convert_weights(
    const float* __restrict__ Wqkv, const float* __restrict__ Wo, const float* __restrict__ Wp,
    const float* __restrict__ Pv, const float* __restrict__ Pm, const float* __restrict__ Pi,
    const float* __restrict__ Pb, const float* __restrict__ Pc, const float* __restrict__ Pf,
    u16* __restrict__ ws)
{
    int gid = blockIdx.x * 512 + threadIdx.x;
    if (gid >= WS_ELEMS) return;
    const float* src; int N, Ksteps, local;
    if (gid < OFF_WO)      { src = Wqkv; N = 384; Ksteps = 4; local = gid; }
    else if (gid < OFF_WP) { src = Wo;   N = 128; Ksteps = 4; local = gid - OFF_WO; }
    else if (gid < OFF_PV) { src = Wp;   N = 256; Ksteps = 4; local = gid - OFF_WP; }
    else if (gid < OFF_PM) { src = Pv;   N = 128; Ksteps = 2; local = gid - OFF_PV; }
    else if (gid < OFF_PI) { src = Pm;   N = 128; Ksteps = 2; local = gid - OFF_PM; }
    else if (gid < OFF_PB) { src = Pi;   N = 128; Ksteps = 1; local = gid - OFF_PI; }
    else if (gid < OFF_PC) { src = Pb;   N = 128; Ksteps = 1; local = gid - OFF_PB; }
    else if (gid < OFF_PF) { src = Pc;   N = 128; Ksteps = 2; local = gid - OFF_PC; }
    else                   { src = Pf;   N = 128; Ksteps = 4; local = gid - OFF_PF; }
    int j  = local & 7;
    int l  = (local >> 3) & 63;
    int r2 = local >> 9;
    int kk = r2 % Ksteps;
    int nt = r2 / Ksteps;
    int srow = kk * 32 + (l >> 4) * 8 + j;
    int scol = nt * 16 + (l & 15);
    ws[gid] = f2bf(src[srow * N + scol]);
}

// 8 rows/block, 48 tokens (token index = comp*8 + row), 512 threads = 8 waves.
// LDS bf16 tiles are granule-swizzled: 16B granule g stored at g ^ (row & 15).
__global__ __launch_bounds__(512, 4) void asmlp_mfma(
    const float* __restrict__ x,
    const float* __restrict__ Wv, const float* __restrict__ bv,
    const float* __restrict__ Wm, const float* __restrict__ bm,
    const float* __restrict__ Wi, const float* __restrict__ bi,
    const float* __restrict__ Wb, const float* __restrict__ bb,
    const float* __restrict__ Wc, const float* __restrict__ bc,
    const float* __restrict__ Wf, const float* __restrict__ bf_,
    const float* __restrict__ pv, const float* __restrict__ pm,
    const float* __restrict__ pi_, const float* __restrict__ pb_,
    const float* __restrict__ pc_, const float* __restrict__ pf_,
    const float* __restrict__ bqkv, const float* __restrict__ bo,
    const float* __restrict__ gg, const float* __restrict__ beta,
    const float* __restrict__ bp,
    const u16* __restrict__ ws,
    float* __restrict__ out)
{
    const int blk  = blockIdx.x;
    const int t    = threadIdx.x;
    const int lane = t & 63;
    const int wv   = t >> 6;
    const int col  = lane & 15;
    const int lg   = lane >> 4;

    // 63744 bytes total
    __shared__ u16 sm[31872];
    u16*   s_tok  = sm;                        // [48 tok][16 gran] 12288 B
    u16*   s_qkv  = sm + 6144;                 // [48 tok][48 gran] 36864 B
    u16*   s_ctx  = sm + 24576;                // [48 tok][16 gran] 12288 B
    u16*   s_att  = sm + 30720;                // [8][4][6][6] bf16 probs
    float* s_x    = (float*)(sm + 24576);      // 232 f32 (overlays ctx; dead before ctx)
    u16*   s_h    = sm + 25088;                // [8 rows][48 gran] (overlays ctx)
    u16*   s_pool = sm + 30720;                // [8 rows][16 gran] (overlays att)
    float* s_out  = (float*)(sm + 6144);       // [8][260] f32 (overlays qkv)

    // ---- S0: load x rows ----
    if (t < 232) s_x[t] = x[(size_t)blk * 232 + t];
    __syncthreads();

    // ---- S1: component encoders (VALU fp32) -> h bf16 ----
    for (int i = 0; i < 6; ++i) {
        int u = t + i * 512;
        int row = u / 384;
        int jj = u - row * 384;
        const float* W; const float* bias; int din, xo, j, dout;
        if (jj < 64)       { W = Wv; bias = bv;  din = 3;  xo = 0;  j = jj;       dout = 64; }
        else if (jj < 128) { W = Wm; bias = bm;  din = 5;  xo = 3;  j = jj - 64;  dout = 64; }
        else if (jj < 160) { W = Wi; bias = bi;  din = 2;  xo = 8;  j = jj - 128; dout = 32; }
        else if (jj < 192) { W = Wb; bias = bb;  din = 3;  xo = 10; j = jj - 160; dout = 32; }
        else if (jj < 256) { W = Wc; bias = bc;  din = 6;  xo = 13; j = jj - 192; dout = 64; }
        else               { W = Wf; bias = bf_; din = 10; xo = 19; j = jj - 256; dout = 128; }
        float acc = bias[j];
        for (int i2 = 0; i2 < din; ++i2) acc += s_x[row * 29 + xo + i2] * W[i2 * dout + j];
        acc = fmaxf(acc, 0.f);
        s_h[((row * 48 + ((jj >> 3) ^ row)) << 3) + (jj & 7)] = f2bf(acc);
    }
    __syncthreads();

    // ---- S2: projections -> tokens (MFMA, M-tile=16 w/ 8 valid rows) ----
    for (int q = 0; q < 6; ++q) {
        int unit = wv * 6 + q;
        int c = unit >> 3, n = unit & 7;
        const float* bias; int ks, hg, wso;
        switch (c) {
            case 0:  bias = pv;  ks = 2; hg = 0;  wso = OFF_PV; break;
            case 1:  bias = pm;  ks = 2; hg = 8;  wso = OFF_PM; break;
            case 2:  bias = pi_; ks = 1; hg = 16; wso = OFF_PI; break;
            case 3:  bias = pb_; ks = 1; hg = 20; wso = OFF_PB; break;
            case 4:  bias = pc_; ks = 2; hg = 24; wso = OFF_PC; break;
            default: bias = pf_; ks = 4; hg = 32; wso = OFF_PF; break;
        }
        float bcol = bias[n * 16 + col];
        f32x4 acc = {bcol, bcol, bcol, bcol};
        int arow = col & 7;   // clamp 16-row tile to 8 valid rows
        for (int kk = 0; kk < ks; ++kk) {
            int g = hg + kk * 4 + lg;
            short8 a = *(const short8*)&s_h[(arow * 48 + (g ^ arow)) << 3];
            short8 b = *(const short8*)&ws[wso + (((n * ks + kk) * 64 + lane) << 3)];
            acc = __builtin_amdgcn_mfma_f32_16x16x32_bf16(a, b, acc, 0, 0, 0);
        }
        if (lg < 2) {
            #pragma unroll
            for (int r = 0; r < 4; ++r) {
                int row = lg * 4 + r;            // 0..7
                int tok = c * 8 + row;
                int cn  = n * 16 + col;
                s_tok[((tok * 16 + ((cn >> 3) ^ (tok & 15))) << 3) + (cn & 7)] = f2bf(acc[r]);
            }
        }
    }
    __syncthreads();

    // ---- S3: QKV = tokens @ Wqkv + bqkv (MFMA, M=48, N=384, K=128) ----
    {
        short8 Bf[3][4];
        float  bb_[3];
        #pragma unroll
        for (int ni = 0; ni < 3; ++ni) {
            int n = wv * 3 + ni;
            bb_[ni] = bqkv[n * 16 + col];
            #pragma unroll
            for (int kk = 0; kk < 4; ++kk)
                Bf[ni][kk] = *(const short8*)&ws[OFF_QKV + (((n * 4 + kk) * 64 + lane) << 3)];
        }
        for (int mt = 0; mt < 3; ++mt) {
            int arow = mt * 16 + col;
            short8 A[4];
            #pragma unroll
            for (int kk = 0; kk < 4; ++kk) {
                int g = kk * 4 + lg;
                A[kk] = *(const short8*)&s_tok[(arow * 16 + (g ^ (arow & 15))) << 3];
            }
            #pragma unroll
            for (int ni = 0; ni < 3; ++ni) {
                f32x4 acc = {bb_[ni], bb_[ni], bb_[ni], bb_[ni]};
                #pragma unroll
                for (int kk = 0; kk < 4; ++kk)
                    acc = __builtin_amdgcn_mfma_f32_16x16x32_bf16(A[kk], Bf[ni][kk], acc, 0, 0, 0);
                int cn = (wv * 3 + ni) * 16 + col;
                #pragma unroll
                for (int r = 0; r < 4; ++r) {
                    int row = mt * 16 + lg * 4 + r;   // token 0..47
                    s_qkv[((row * 48 + ((cn >> 3) ^ (row & 15))) << 3) + (cn & 7)] = f2bf(acc[r]);
                }
            }
        }
    }
    __syncthreads();

    // ---- S4: scores + softmax (VALU fp32, probs -> bf16) ----
    if (t < 192) {
        int row = t / 24;
        int rem = t - row * 24;
        int h   = rem / 6;
        int qi  = rem - h * 6;
        int tq  = qi * 8 + row;
        float qf[32];
        #pragma unroll
        for (int gi = 0; gi < 4; ++gi) {
            int g = h * 4 + gi;
            short8 v = *(const short8*)&s_qkv[(tq * 48 + (g ^ (tq & 15))) << 3];
            #pragma unroll
            for (int j = 0; j < 8; ++j) qf[gi * 8 + j] = bf2f((u16)v[j]);
        }
        float sc[6];
        #pragma unroll
        for (int ki = 0; ki < 6; ++ki) {
            int tk = ki * 8 + row;
            float d = 0.f;
            #pragma unroll
            for (int gi = 0; gi < 4; ++gi) {
                int g = 16 + h * 4 + gi;
                short8 v = *(const short8*)&s_qkv[(tk * 48 + (g ^ (tk & 15))) << 3];
                #pragma unroll
                for (int j = 0; j < 8; ++j) d += qf[gi * 8 + j] * bf2f((u16)v[j]);
            }
            sc[ki] = d * 0.17677669529663687f;   // 1/sqrt(32)
        }
        float mx = sc[0];
        #pragma unroll
        for (int ki = 1; ki < 6; ++ki) mx = fmaxf(mx, sc[ki]);
        float e[6], s = 0.f;
        #pragma unroll
        for (int ki = 0; ki < 6; ++ki) { e[ki] = __expf(sc[ki] - mx); s += e[ki]; }
        float inv = 1.f / s;
        #pragma unroll
        for (int ki = 0; ki < 6; ++ki)
            s_att[((row * 4 + h) * 6 + qi) * 6 + ki] = f2bf(e[ki] * inv);
    }
    __syncthreads();

    // ---- S5: ctx = attn @ v (VALU, granule-vectorized) ----
    for (int u = t; u < 768; u += 512) {
        int m = u >> 4, gch = u & 15;
        int row = m & 7, qi = m >> 3, h = gch >> 2;
        float accs[8] = {0, 0, 0, 0, 0, 0, 0, 0};
        #pragma unroll
        for (int ki = 0; ki < 6; ++ki) {
            float p = bf2f(s_att[((row * 4 + h) * 6 + qi) * 6 + ki]);
            int tv = ki * 8 + row;
            int g  = 32 + gch;
            short8 v = *(const short8*)&s_qkv[(tv * 48 + (g ^ (tv & 15))) << 3];
            #pragma unroll
            for (int j = 0; j < 8; ++j) accs[j] += p * bf2f((u16)v[j]);
        }
        short8 o;
        #pragma unroll
        for (int j = 0; j < 8; ++j) o[j] = (short)f2bf(accs[j]);
        *(short8*)&s_ctx[(m * 16 + (gch ^ (m & 15))) << 3] = o;
    }
    __syncthreads();

    // ---- S6: out-proj + residual + LayerNorm (MFMA + in-register LN) ----
    if (wv < 3) {
        int mt = wv;
        int arow = mt * 16 + col;
        short8 A[4];
        #pragma unroll
        for (int kk = 0; kk < 4; ++kk) {
            int g = kk * 4 + lg;
            A[kk] = *(const short8*)&s_ctx[(arow * 16 + (g ^ (arow & 15))) << 3];
        }
        f32x4 acc[8];
        #pragma unroll
        for (int n = 0; n < 8; ++n) {
            float b = bo[n * 16 + col];
            acc[n] = (f32x4){b, b, b, b};
            #pragma unroll
            for (int kk = 0; kk < 4; ++kk) {
                short8 Bf = *(const short8*)&ws[OFF_WO + (((n * 4 + kk) * 64 + lane) << 3)];
                acc[n] = __builtin_amdgcn_mfma_f32_16x16x32_bf16(A[kk], Bf, acc[n], 0, 0, 0);
            }
        }
        #pragma unroll
        for (int n = 0; n < 8; ++n) {     // residual
            int cn = n * 16 + col;
            #pragma unroll
            for (int r = 0; r < 4; ++r) {
                int row = mt * 16 + lg * 4 + r;
                acc[n][r] += bf2f(s_tok[((row * 16 + ((cn >> 3) ^ (row & 15))) << 3) + (cn & 7)]);
            }
        }
        float mu_[4], rs_[4];
        #pragma unroll
        for (int r = 0; r < 4; ++r) {     // LN stats: 8 local + 16-lane shuffle reduce
            float s1 = 0.f, s2 = 0.f;
            #pragma unroll
            for (int n = 0; n < 8; ++n) { float v = acc[n][r]; s1 += v; s2 += v * v; }
            #pragma unroll
            for (int off = 1; off <= 8; off <<= 1) {
                s1 += __shfl_xor(s1, off, 64);
                s2 += __shfl_xor(s2, off, 64);
            }
            float mu  = s1 * (1.f / 128.f);
            float var = s2 * (1.f / 128.f) - mu * mu;
            mu_[r] = mu;
            rs_[r] = rsqrtf(var + LN_EPS);
        }
        #pragma unroll
        for (int n = 0; n < 8; ++n) {
            int cn = n * 16 + col;
            float gw = gg[cn], bw = beta[cn];
            #pragma unroll
            for (int r = 0; r < 4; ++r) {
                int row = mt * 16 + lg * 4 + r;
                float val = (acc[n][r] - mu_[r]) * rs_[r] * gw + bw;
                s_tok[((row * 16 + ((cn >> 3) ^ (row & 15))) << 3) + (cn & 7)] = f2bf(val);
            }
        }
    }
    __syncthreads();

    // ---- S7: mean-pool over 6 tokens ----
    if (t < 128) {
        int row = t >> 4, gch = t & 15;
        float fa[8] = {0, 0, 0, 0, 0, 0, 0, 0};
        #pragma unroll
        for (int c = 0; c < 6; ++c) {
            int tok = c * 8 + row;
            short8 v = *(const short8*)&s_tok[(tok * 16 + (gch ^ (tok & 15))) << 3];
            #pragma unroll
            for (int j = 0; j < 8; ++j) fa[j] += bf2f((u16)v[j]);
        }
        short8 o;
        #pragma unroll
        for (int j = 0; j < 8; ++j) o[j] = (short)f2bf(fa[j] * (1.f / 6.f));
        *(short8*)&s_pool[(row * 16 + (gch ^ row)) << 3] = o;
    }
    __syncthreads();

    // ---- S8: pooled @ Wp + bp, ReLU (MFMA, M-tile=16 w/ 8 valid rows) ----
    {
        int arow = col & 7;
        short8 A[4];
        #pragma unroll
        for (int kk = 0; kk < 4; ++kk) {
            int g = kk * 4 + lg;
            A[kk] = *(const short8*)&s_pool[(arow * 16 + (g ^ arow)) << 3];
        }
        #pragma unroll
        for (int ni = 0; ni < 2; ++ni) {
            int n = wv * 2 + ni;
            float b = bp[n * 16 + col];
            f32x4 acc = {b, b, b, b};
            #pragma unroll
            for (int kk = 0; kk < 4; ++kk) {
                short8 Bf = *(const short8*)&ws[OFF_WP + (((n * 4 + kk) * 64 + lane) << 3)];
                acc = __builtin_amdgcn_mfma_f32_16x16x32_bf16(A[kk], Bf, acc, 0, 0, 0);
            }
            if (lg < 2) {
                #pragma unroll
                for (int r = 0; r < 4; ++r) {
                    int row = lg * 4 + r;
                    s_out[row * 260 + n * 16 + col] = fmaxf(acc[r], 0.f);
                }
            }
        }
    }
    __syncthreads();

    // ---- S9: coalesced store ----
    if (t < 256) {
        int row = t >> 5, c8 = (t & 31) * 8;
        f32x4 v0 = *(const f32x4*)&s_out[row * 260 + c8];
        f32x4 v1 = *(const f32x4*)&s_out[row * 260 + c8 + 4];
        float* dst = out + ((size_t)blk * 8 + row) * 256 + c8;
        *(f32x4*)dst = v0;
        *(f32x4*)(dst + 4) = v1;
    }
}

extern "C" void kernel_launch(void* const* d_in, const int* in_sizes, int n_in,
                              void* d_out, int out_size, void* d_ws, size_t ws_size,
                              hipStream_t stream) {
    const float* x    = (const float*)d_in[0];
    const float* Wv   = (const float*)d_in[1];
    const float* bv   = (const float*)d_in[2];
    const float* Wm   = (const float*)d_in[3];
    const float* bm   = (const float*)d_in[4];
    const float* Wi   = (const float*)d_in[5];
    const float* bi   = (const float*)d_in[6];
    const float* Wb   = (const float*)d_in[7];
    const float* bb   = (const float*)d_in[8];
    const float* Wc   = (const float*)d_in[9];
    const float* bc   = (const float*)d_in[10];
    const float* Wf   = (const float*)d_in[11];
    const float* bf_  = (const float*)d_in[12];
    const float* Pv   = (const float*)d_in[13];
    const float* pv   = (const float*)d_in[14];
    const float* Pm   = (const float*)d_in[15];
    const float* pm   = (const float*)d_in[16];
    const float* Pi   = (const float*)d_in[17];
    const float* pii  = (const float*)d_in[18];
    const float* Pb   = (const float*)d_in[19];
    const float* pb   = (const float*)d_in[20];
    const float* Pc   = (const float*)d_in[21];
    const float* pc   = (const float*)d_in[22];
    const float* Pf   = (const float*)d_in[23];
    const float* pf   = (const float*)d_in[24];
    const float* Wqkv = (const float*)d_in[25];
    const float* bqkv = (const float*)d_in[26];
    const float* Wo   = (const float*)d_in[27];
    const float* bo   = (const float*)d_in[28];
    const float* gg   = (const float*)d_in[29];
    const float* beta = (const float*)d_in[30];
    const float* Wp   = (const float*)d_in[31];
    const float* bp   = (const float*)d_in[32];
    float* out = (float*)d_out;
    u16* ws = (u16*)d_ws;

    convert_weights<<<288, 512, 0, stream>>>(Wqkv, Wo, Wp, Pv, Pm, Pi, Pb, Pc, Pf, ws);

    const int Bn = in_sizes[0] / 29;       // 65536
    asmlp_mfma<<<Bn / 8, 512, 0, stream>>>(
        x, Wv, bv, Wm, bm, Wi, bi, Wb, bb, Wc, bc, Wf, bf_,
        pv, pm, pii, pb, pc, pf,
        bqkv, bo, gg, beta, bp, ws, out);
}

// Round 3
// 309.828 us; speedup vs baseline: 5.7254x; 1.0913x over previous
//
#include <hip/hip_runtime.h>
#include <math.h>

typedef float f32x4 __attribute__((ext_vector_type(4)));
typedef short short8 __attribute__((ext_vector_type(8)));
typedef unsigned short u16;

#define LN_EPS 1e-5f

__device__ __forceinline__ unsigned cvt_pk_bf16(float lo, float hi) {
    unsigned r;
    asm("v_cvt_pk_bf16_f32 %0, %1, %2" : "=v"(r) : "v"(lo), "v"(hi));
    return r;
}
__device__ __forceinline__ u16 f2bf(float f) { return (u16)cvt_pk_bf16(f, f); }
__device__ __forceinline__ float bf2f(u16 u) {
    return __uint_as_float(((unsigned)u) << 16);
}

// ws segment offsets (u16 elements). B-fragment-linear layout:
// idx = ((ntile*Ksteps + kk)*64 + lane)*8 + j -> W[kk*32+(lane>>4)*8+j][ntile*16+(lane&15)]
#define OFF_QKV 0
#define OFF_WO  49152
#define OFF_WP  65536
#define OFF_PV  98304
#define OFF_PM  106496
#define OFF_PI  114688
#define OFF_PB  118784
#define OFF_PC  122880
#define OFF_PF  131072
#define OFF_WENC 147456     // block-diag encoder weight, stacked hi/lo: 24 ntiles x 2 ksteps
#define OFF_BENC 172032     // f32 region (384 floats) starts at this u16 index
#define CW_TOTAL 172416

__global__ __launch_bounds__(512) void convert_weights(
    const float* __restrict__ Wqkv, const float* __restrict__ Wo, const float* __restrict__ Wp,
    const float* __restrict__ Pv, const float* __restrict__ Pm, const float* __restrict__ Pi,
    const float* __restrict__ Pb, const float* __restrict__ Pc, const float* __restrict__ Pf,
    const float* __restrict__ Wv, const float* __restrict__ Wm, const float* __restrict__ Wi,
    const float* __restrict__ Wb, const float* __restrict__ Wc, const float* __restrict__ Wf,
    const float* __restrict__ bv, const float* __restrict__ bm, const float* __restrict__ bi,
    const float* __restrict__ bb, const float* __restrict__ bc, const float* __restrict__ bf_,
    u16* __restrict__ ws)
{
    int gid = blockIdx.x * 512 + threadIdx.x;
    if (gid < OFF_WENC) {
        const float* src; int N, Ksteps, local;
        if (gid < OFF_WO)      { src = Wqkv; N = 384; Ksteps = 4; local = gid; }
        else if (gid < OFF_WP) { src = Wo;   N = 128; Ksteps = 4; local = gid - OFF_WO; }
        else if (gid < OFF_PV) { src = Wp;   N = 256; Ksteps = 4; local = gid - OFF_WP; }
        else if (gid < OFF_PM) { src = Pv;   N = 128; Ksteps = 2; local = gid - OFF_PV; }
        else if (gid < OFF_PI) { src = Pm;   N = 128; Ksteps = 2; local = gid - OFF_PM; }
        else if (gid < OFF_PB) { src = Pi;   N = 128; Ksteps = 1; local = gid - OFF_PI; }
        else if (gid < OFF_PC) { src = Pb;   N = 128; Ksteps = 1; local = gid - OFF_PB; }
        else if (gid < OFF_PF) { src = Pc;   N = 128; Ksteps = 2; local = gid - OFF_PC; }
        else                   { src = Pf;   N = 128; Ksteps = 4; local = gid - OFF_PF; }
        int j  = local & 7;
        int l  = (local >> 3) & 63;
        int r2 = local >> 9;
        int kk = r2 % Ksteps;
        int nt = r2 / Ksteps;
        int srow = kk * 32 + (l >> 4) * 8 + j;
        int scol = nt * 16 + (l & 15);
        ws[gid] = f2bf(src[srow * N + scol]);
    } else if (gid < OFF_BENC) {
        // block-diagonal encoder weight, rows 0-31 = hi copy, 32-63 = lo copy (same values)
        int local = gid - OFF_WENC;
        int j = local & 7, l = (local >> 3) & 63, r2 = local >> 9;
        int kk = r2 & 1, nt = r2 >> 1;
        int k = kk * 32 + (l >> 4) * 8 + j;
        int r = k & 31;                    // x input dim (0..31, valid <29)
        int scol = nt * 16 + (l & 15);     // 0..383
        const float* W; int cb, xo, din, dout;
        if (scol < 64)       { W = Wv; cb = 0;   xo = 0;  din = 3;  dout = 64; }
        else if (scol < 128) { W = Wm; cb = 64;  xo = 3;  din = 5;  dout = 64; }
        else if (scol < 160) { W = Wi; cb = 128; xo = 8;  din = 2;  dout = 32; }
        else if (scol < 192) { W = Wb; cb = 160; xo = 10; din = 3;  dout = 32; }
        else if (scol < 256) { W = Wc; cb = 192; xo = 13; din = 6;  dout = 64; }
        else                 { W = Wf; cb = 256; xo = 19; din = 10; dout = 128; }
        int rr = r - xo;
        float val = (r < 29 && rr >= 0 && rr < din) ? W[rr * dout + (scol - cb)] : 0.f;
        ws[gid] = f2bf(val);
    } else if (gid < CW_TOTAL) {
        int j = gid - OFF_BENC;
        const float* b; int off;
        if (j < 64)       { b = bv;  off = 0; }
        else if (j < 128) { b = bm;  off = 64; }
        else if (j < 160) { b = bi;  off = 128; }
        else if (j < 192) { b = bb;  off = 160; }
        else if (j < 256) { b = bc;  off = 192; }
        else              { b = bf_; off = 256; }
        ((float*)(ws + OFF_BENC))[j] = b[j - off];
    }
}

// 8 rows/block, 48 tokens (token = comp*8 + row), 512 threads = 8 waves.
__global__ __launch_bounds__(512, 4) void asmlp_mfma(
    const float* __restrict__ x,
    const float* __restrict__ pv, const float* __restrict__ pm,
    const float* __restrict__ pi_, const float* __restrict__ pb_,
    const float* __restrict__ pc_, const float* __restrict__ pf_,
    const float* __restrict__ bqkv, const float* __restrict__ bo,
    const float* __restrict__ gg, const float* __restrict__ beta,
    const float* __restrict__ bp,
    const u16* __restrict__ ws,
    float* __restrict__ out)
{
    const int blk  = blockIdx.x;
    const int t    = threadIdx.x;
    const int lane = t & 63;
    const int wv   = t >> 6;
    const int col  = lane & 15;
    const int lg   = lane >> 4;

    // 61440 bytes
    __shared__ __attribute__((aligned(16))) u16 sm[30720];
    u16*   s_tok  = sm;                      // [48 tok][16 gran][8]           12288 B
    u16*   s_qk   = sm + 6144;               // col-major [256 col][48 tok]    24576 B
    u16*   s_vt   = sm + 18432;              // [16 g][2 ch][16 n][16 k]       16384 B
    u16*   s_ppad = sm + 26624;              // [8 wv][2 slot][16 k][16 m]      8192 B
    u16*   s_xa   = sm + 18432;              // [8 row][64 k] hi/lo x (overlay vt; dead before S3)
    u16*   s_h    = sm + 18944;              // [8 row][48 gran][8] (overlay vt; dead after S2)
    u16*   s_ctx  = sm + 6144;               // [48 tok][16 gran][8] (overlay qk; after scores barrier)
    float* s_out  = (float*)(sm + 12288);    // [8][260] f32 (overlay qk upper; after S6)
    u16*   s_pool = sm + 26624;              // [8 row][16 gran][8] (overlay ppad; after PV)

    // ---- S0: stage x as hi/lo bf16 (exact fp32 split) ----
    if (t < 232) {
        int row = t / 29, cc = t - row * 29;
        float f = x[(size_t)blk * 232 + t];
        u16 hi = f2bf(f);
        float lo = f - bf2f(hi);
        s_xa[row * 64 + cc]      = hi;
        s_xa[row * 64 + 32 + cc] = f2bf(lo);
    }
    if (t < 48) {
        int row = t / 6, sl = t - (t / 6) * 6;
        int k = (sl < 3) ? (29 + sl) : (58 + sl);
        s_xa[row * 64 + k] = 0;
    }
    __syncthreads();

    // ---- S1: component encoders via MFMA (block-diag Wenc, K=64 hi/lo) ----
    {
        int arow = col & 7;
        short8 A0 = *(const short8*)&s_xa[arow * 64 + lg * 8];
        short8 A1 = *(const short8*)&s_xa[arow * 64 + 32 + lg * 8];
        const float* benc = (const float*)(ws + OFF_BENC);
        #pragma unroll
        for (int q = 0; q < 3; ++q) {
            int nt = wv * 3 + q;
            float b = benc[nt * 16 + col];
            f32x4 acc = {b, b, b, b};
            short8 B0 = *(const short8*)&ws[OFF_WENC + (((nt * 2 + 0) * 64 + lane) << 3)];
            short8 B1 = *(const short8*)&ws[OFF_WENC + (((nt * 2 + 1) * 64 + lane) << 3)];
            acc = __builtin_amdgcn_mfma_f32_16x16x32_bf16(A0, B0, acc, 0, 0, 0);
            acc = __builtin_amdgcn_mfma_f32_16x16x32_bf16(A1, B1, acc, 0, 0, 0);
            if (lg < 2) {
                #pragma unroll
                for (int r = 0; r < 4; ++r) {
                    int row = lg * 4 + r;
                    int cn = nt * 16 + col;
                    s_h[((row * 48 + ((cn >> 3) ^ row)) << 3) + (cn & 7)] =
                        f2bf(fmaxf(acc[r], 0.f));
                }
            }
        }
    }
    __syncthreads();

    // ---- S2: projections -> tokens (MFMA, M-tile=16 w/ 8 valid rows) ----
    #pragma unroll
    for (int q = 0; q < 6; ++q) {
        int unit = wv * 6 + q;
        int c = unit >> 3, n = unit & 7;
        const float* bias; int ks, hg, wso;
        switch (c) {
            case 0:  bias = pv;  ks = 2; hg = 0;  wso = OFF_PV; break;
            case 1:  bias = pm;  ks = 2; hg = 8;  wso = OFF_PM; break;
            case 2:  bias = pi_; ks = 1; hg = 16; wso = OFF_PI; break;
            case 3:  bias = pb_; ks = 1; hg = 20; wso = OFF_PB; break;
            case 4:  bias = pc_; ks = 2; hg = 24; wso = OFF_PC; break;
            default: bias = pf_; ks = 4; hg = 32; wso = OFF_PF; break;
        }
        float bcol = bias[n * 16 + col];
        f32x4 acc = {bcol, bcol, bcol, bcol};
        int arow = col & 7;
        for (int kk = 0; kk < ks; ++kk) {
            int g = hg + kk * 4 + lg;
            short8 a = *(const short8*)&s_h[(arow * 48 + (g ^ arow)) << 3];
            short8 b = *(const short8*)&ws[wso + (((n * ks + kk) * 64 + lane) << 3)];
            acc = __builtin_amdgcn_mfma_f32_16x16x32_bf16(a, b, acc, 0, 0, 0);
        }
        if (lg < 2) {
            #pragma unroll
            for (int r = 0; r < 4; ++r) {
                int row = lg * 4 + r;
                int tok = c * 8 + row;
                int cn  = n * 16 + col;
                s_tok[((tok * 16 + ((cn >> 3) ^ (tok & 15))) << 3) + (cn & 7)] = f2bf(acc[r]);
            }
        }
    }
    __syncthreads();

    // ---- S3: QKV (MFMA). Q/K -> col-major s_qk (cvt_pk + b64); V -> s_vt ----
    {
        short8 Bf[3][4];
        float  bb_[3];
        #pragma unroll
        for (int ni = 0; ni < 3; ++ni) {
            int n = wv * 3 + ni;
            bb_[ni] = bqkv[n * 16 + col];
            #pragma unroll
            for (int kk = 0; kk < 4; ++kk)
                Bf[ni][kk] = *(const short8*)&ws[OFF_QKV + (((n * 4 + kk) * 64 + lane) << 3)];
        }
        // zero s_vt k-pad (k 12..15), one b64 per thread
        { uint2 z; z.x = 0u; z.y = 0u; *(uint2*)&s_vt[t * 16 + 12] = z; }
        for (int mt = 0; mt < 3; ++mt) {
            short8 A[4];
            int arow = mt * 16 + col;
            #pragma unroll
            for (int kk = 0; kk < 4; ++kk) {
                int g = kk * 4 + lg;
                A[kk] = *(const short8*)&s_tok[(arow * 16 + (g ^ (arow & 15))) << 3];
            }
            #pragma unroll
            for (int ni = 0; ni < 3; ++ni) {
                f32x4 acc = {bb_[ni], bb_[ni], bb_[ni], bb_[ni]};
                #pragma unroll
                for (int kk = 0; kk < 4; ++kk)
                    acc = __builtin_amdgcn_mfma_f32_16x16x32_bf16(A[kk], Bf[ni][kk], acc, 0, 0, 0);
                int cn = wv * 3 + ni;
                int cg = cn * 16 + col;                 // global qkv column
                if (cn < 16) {
                    // Q/K: col-major, token index XOR-swizzled by ((cg>>3)&3)<<2
                    int q4 = ((cg >> 3) & 3) << 2;
                    int tb = (mt * 16 + lg * 4) ^ q4;
                    uint2 w;
                    w.x = cvt_pk_bf16(acc[0], acc[1]);
                    w.y = cvt_pk_bf16(acc[2], acc[3]);
                    *(uint2*)&s_qk[cg * 48 + tb] = w;
                } else {
                    int d = cg - 256;
                    int h = d >> 5, ch = (d >> 4) & 1, nn = d & 15;
                    #pragma unroll
                    for (int r = 0; r < 4; ++r) {
                        int token = mt * 16 + lg * 4 + r;
                        int c2 = token >> 3, rb = token & 7;
                        int g2 = rb * 2 + (h >> 1);
                        int kidx = (h & 1) * 6 + c2;
                        s_vt[((g2 * 2 + ch) * 16 + nn) * 16 + kidx] = f2bf(acc[r]);
                    }
                }
            }
        }
    }
    __syncthreads();

    // ---- SCORES: 2 (row,head) pairs per MFMA; softmax in C-regs -> s_ppad ----
    {
        const int rb = wv;
        #pragma unroll
        for (int i = 0; i < 2; ++i) {
            const int hp = i;
            int p  = (col >= 6 && col < 12) ? 1 : 0;
            int qi = (col < 6) ? col : ((col < 12) ? col - 6 : 0);
            int tt = qi * 8 + rb;
            int h  = hp * 2 + p;
            int tsw = tt ^ (lg << 2);
            int abase = (h * 32 + lg * 8) * 48 + tsw;          // Q cols 0..127
            int bbase = (128 + h * 32 + lg * 8) * 48 + tsw;    // K cols 128..255
            short8 Aq, Bk;
            #pragma unroll
            for (int j = 0; j < 8; ++j) {
                Aq[j] = (short)s_qk[abase + j * 48];
                Bk[j] = (short)s_qk[bbase + j * 48];
            }
            f32x4 sc = {0.f, 0.f, 0.f, 0.f};
            sc = __builtin_amdgcn_mfma_f32_16x16x32_bf16(Aq, Bk, sc, 0, 0, 0);
            u16* pp = s_ppad + (wv * 2 + i) * 256;
            f32x4 pr4;
            #pragma unroll
            for (int r = 0; r < 4; ++r) {
                int mr = lg * 4 + r;
                int prr = (mr >= 6 && mr < 12) ? 1 : 0;
                float v = sc[r] * 0.17677669529663687f;   // 1/sqrt(32)
                bool inR = (col >= 6 * prr) && (col < 6 * prr + 6);
                float mv = inR ? v : -1e30f;
                #pragma unroll
                for (int off = 1; off < 16; off <<= 1)
                    mv = fmaxf(mv, __shfl_xor(mv, off, 16));
                float e = inR ? __expf(v - mv) : 0.f;
                float s = e;
                #pragma unroll
                for (int off = 1; off < 16; off <<= 1)
                    s += __shfl_xor(s, off, 16);
                pr4[r] = (mr < 12) ? (e / s) : 0.f;
            }
            uint2 w;
            w.x = cvt_pk_bf16(pr4[0], pr4[1]);
            w.y = cvt_pk_bf16(pr4[2], pr4[3]);
            *(uint2*)&pp[col * 16 + lg * 4] = w;   // Ppad[k=col][m quad]
        }
    }
    __syncthreads();

    // ---- PV: ctx = P @ V via MFMA (A from ppad block-diag, B b128 from s_vt) ----
    {
        const int rb = wv;
        #pragma unroll
        for (int i = 0; i < 2; ++i) {
            const int hp = i;
            u16* pp = s_ppad + (wv * 2 + i) * 256;
            short8 Ap;
            if (lg < 2) {
                #pragma unroll
                for (int j = 0; j < 8; ++j)
                    Ap[j] = (short)pp[(lg * 8 + j) * 16 + col];
            } else {
                #pragma unroll
                for (int j = 0; j < 8; ++j) Ap[j] = 0;
            }
            int g2 = rb * 2 + hp;
            #pragma unroll
            for (int ch = 0; ch < 2; ++ch) {
                short8 Bv = *(const short8*)&s_vt[(((g2 * 2 + ch) * 16 + col) * 16) + ((lg & 1) * 8)];
                f32x4 c = {0.f, 0.f, 0.f, 0.f};
                c = __builtin_amdgcn_mfma_f32_16x16x32_bf16(Ap, Bv, c, 0, 0, 0);
                #pragma unroll
                for (int r = 0; r < 4; ++r) {
                    int mr = lg * 4 + r;
                    if (mr < 12) {
                        int pq = mr >= 6 ? 1 : 0;
                        int qi = mr - 6 * pq;
                        int token = qi * 8 + rb;
                        int d = (hp * 2 + pq) * 32 + ch * 16 + col;
                        s_ctx[((token * 16 + ((d >> 3) ^ (token & 15))) << 3) + (d & 7)] = f2bf(c[r]);
                    }
                }
            }
        }
    }
    __syncthreads();

    // ---- S6: out-proj + residual + LayerNorm (MFMA + in-register LN) ----
    if (wv < 3) {
        int mt = wv;
        int arow = mt * 16 + col;
        short8 A[4];
        #pragma unroll
        for (int kk = 0; kk < 4; ++kk) {
            int g = kk * 4 + lg;
            A[kk] = *(const short8*)&s_ctx[(arow * 16 + (g ^ (arow & 15))) << 3];
        }
        f32x4 acc[8];
        #pragma unroll
        for (int n = 0; n < 8; ++n) {
            float b = bo[n * 16 + col];
            acc[n] = (f32x4){b, b, b, b};
            #pragma unroll
            for (int kk = 0; kk < 4; ++kk) {
                short8 Bf = *(const short8*)&ws[OFF_WO + (((n * 4 + kk) * 64 + lane) << 3)];
                acc[n] = __builtin_amdgcn_mfma_f32_16x16x32_bf16(A[kk], Bf, acc[n], 0, 0, 0);
            }
        }
        #pragma unroll
        for (int n = 0; n < 8; ++n) {
            int cn = n * 16 + col;
            #pragma unroll
            for (int r = 0; r < 4; ++r) {
                int row = mt * 16 + lg * 4 + r;
                acc[n][r] += bf2f(s_tok[((row * 16 + ((cn >> 3) ^ (row & 15))) << 3) + (cn & 7)]);
            }
        }
        float mu_[4], rs_[4];
        #pragma unroll
        for (int r = 0; r < 4; ++r) {
            float s1 = 0.f, s2 = 0.f;
            #pragma unroll
            for (int n = 0; n < 8; ++n) { float v = acc[n][r]; s1 += v; s2 += v * v; }
            #pragma unroll
            for (int off = 1; off <= 8; off <<= 1) {
                s1 += __shfl_xor(s1, off, 64);
                s2 += __shfl_xor(s2, off, 64);
            }
            float mu  = s1 * (1.f / 128.f);
            float var = s2 * (1.f / 128.f) - mu * mu;
            mu_[r] = mu;
            rs_[r] = rsqrtf(var + LN_EPS);
        }
        #pragma unroll
        for (int n = 0; n < 8; ++n) {
            int cn = n * 16 + col;
            float gw = gg[cn], bw = beta[cn];
            #pragma unroll
            for (int r = 0; r < 4; ++r) {
                int row = mt * 16 + lg * 4 + r;
                float val = (acc[n][r] - mu_[r]) * rs_[r] * gw + bw;
                s_tok[((row * 16 + ((cn >> 3) ^ (row & 15))) << 3) + (cn & 7)] = f2bf(val);
            }
        }
    }
    __syncthreads();

    // ---- S7: mean-pool over 6 tokens ----
    if (t < 128) {
        int row = t >> 4, gch = t & 15;
        float fa[8] = {0, 0, 0, 0, 0, 0, 0, 0};
        #pragma unroll
        for (int c = 0; c < 6; ++c) {
            int tok = c * 8 + row;
            short8 v = *(const short8*)&s_tok[(tok * 16 + (gch ^ (tok & 15))) << 3];
            #pragma unroll
            for (int j = 0; j < 8; ++j) fa[j] += bf2f((u16)v[j]);
        }
        short8 o;
        #pragma unroll
        for (int j = 0; j < 8; ++j) o[j] = (short)f2bf(fa[j] * (1.f / 6.f));
        *(short8*)&s_pool[(row * 16 + (gch ^ row)) << 3] = o;
    }
    __syncthreads();

    // ---- S8: pooled @ Wp + bp, ReLU ----
    {
        int arow = col & 7;
        short8 A[4];
        #pragma unroll
        for (int kk = 0; kk < 4; ++kk) {
            int g = kk * 4 + lg;
            A[kk] = *(const short8*)&s_pool[(arow * 16 + (g ^ arow)) << 3];
        }
        #pragma unroll
        for (int ni = 0; ni < 2; ++ni) {
            int n = wv * 2 + ni;
            float b = bp[n * 16 + col];
            f32x4 acc = {b, b, b, b};
            #pragma unroll
            for (int kk = 0; kk < 4; ++kk) {
                short8 Bf = *(const short8*)&ws[OFF_WP + (((n * 4 + kk) * 64 + lane) << 3)];
                acc = __builtin_amdgcn_mfma_f32_16x16x32_bf16(A[kk], Bf, acc, 0, 0, 0);
            }
            if (lg < 2) {
                #pragma unroll
                for (int r = 0; r < 4; ++r) {
                    int row = lg * 4 + r;
                    s_out[row * 260 + n * 16 + col] = fmaxf(acc[r], 0.f);
                }
            }
        }
    }
    __syncthreads();

    // ---- S9: coalesced store ----
    if (t < 256) {
        int row = t >> 5, c8 = (t & 31) * 8;
        f32x4 v0 = *(const f32x4*)&s_out[row * 260 + c8];
        f32x4 v1 = *(const f32x4*)&s_out[row * 260 + c8 + 4];
        float* dst = out + ((size_t)blk * 8 + row) * 256 + c8;
        *(f32x4*)dst = v0;
        *(f32x4*)(dst + 4) = v1;
    }
}

extern "C" void kernel_launch(void* const* d_in, const int* in_sizes, int n_in,
                              void* d_out, int out_size, void* d_ws, size_t ws_size,
                              hipStream_t stream) {
    const float* x    = (const float*)d_in[0];
    const float* Wv   = (const float*)d_in[1];
    const float* bv   = (const float*)d_in[2];
    const float* Wm   = (const float*)d_in[3];
    const float* bm   = (const float*)d_in[4];
    const float* Wi   = (const float*)d_in[5];
    const float* bi   = (const float*)d_in[6];
    const float* Wb   = (const float*)d_in[7];
    const float* bb   = (const float*)d_in[8];
    const float* Wc   = (const float*)d_in[9];
    const float* bc   = (const float*)d_in[10];
    const float* Wf   = (const float*)d_in[11];
    const float* bf_  = (const float*)d_in[12];
    const float* Pv   = (const float*)d_in[13];
    const float* pv   = (const float*)d_in[14];
    const float* Pm   = (const float*)d_in[15];
    const float* pm   = (const float*)d_in[16];
    const float* Pi   = (const float*)d_in[17];
    const float* pii  = (const float*)d_in[18];
    const float* Pb   = (const float*)d_in[19];
    const float* pb   = (const float*)d_in[20];
    const float* Pc   = (const float*)d_in[21];
    const float* pc   = (const float*)d_in[22];
    const float* Pf   = (const float*)d_in[23];
    const float* pf   = (const float*)d_in[24];
    const float* Wqkv = (const float*)d_in[25];
    const float* bqkv = (const float*)d_in[26];
    const float* Wo   = (const float*)d_in[27];
    const float* bo   = (const float*)d_in[28];
    const float* gg   = (const float*)d_in[29];
    const float* beta = (const float*)d_in[30];
    const float* Wp   = (const float*)d_in[31];
    const float* bp   = (const float*)d_in[32];
    float* out = (float*)d_out;
    u16* ws = (u16*)d_ws;

    convert_weights<<<(CW_TOTAL + 511) / 512, 512, 0, stream>>>(
        Wqkv, Wo, Wp, Pv, Pm, Pi, Pb, Pc, Pf,
        Wv, Wm, Wi, Wb, Wc, Wf, bv, bm, bi, bb, bc, bf_, ws);

    const int Bn = in_sizes[0] / 29;       // 65536
    asmlp_mfma<<<Bn / 8, 512, 0, stream>>>(
        x, pv, pm, pii, pb, pc, pf,
        bqkv, bo, gg, beta, bp, ws, out);
}

// Round 6
// 294.469 us; speedup vs baseline: 6.0241x; 1.0522x over previous
//
#include <hip/hip_runtime.h>
#include <math.h>

typedef float f32x4 __attribute__((ext_vector_type(4)));
typedef short short8 __attribute__((ext_vector_type(8)));
typedef unsigned short u16;

#define LN_EPS 1e-5f

static __device__ __forceinline__ unsigned cvt_pk_bf16(float lo, float hi) {
    unsigned r;
    asm("v_cvt_pk_bf16_f32 %0, %1, %2" : "=v"(r) : "v"(lo), "v"(hi));
    return r;
}
static __device__ __forceinline__ u16 f2bf(float f) { return (u16)cvt_pk_bf16(f, f); }
static __device__ __forceinline__ float bf2f(u16 u) {
    return __uint_as_float(((unsigned)u) << 16);
}

// ws segment offsets (u16 elements). Fragment-linear layout (works as A- or B-operand):
// idx = ((ntile*Ksteps + kk)*64 + lane)*8 + j -> W[kk*32+(lane>>4)*8+j][ntile*16+(lane&15)]
#define OFF_QKV 0
#define OFF_WO  49152
#define OFF_WP  65536
#define OFF_PV  98304
#define OFF_PM  106496
#define OFF_PI  114688
#define OFF_PB  118784
#define OFF_PC  122880
#define OFF_PF  131072
#define OFF_WENC 147456     // block-diag encoder weight, hi/lo stacked: 24 ntiles x 2 ksteps
#define OFF_BENC 172032     // f32 region (384 floats) starts at this u16 index
#define CW_TOTAL 172416

__global__ __launch_bounds__(512) void convert_weights(
    const float* __restrict__ Wqkv, const float* __restrict__ Wo, const float* __restrict__ Wp,
    const float* __restrict__ Pv, const float* __restrict__ Pm, const float* __restrict__ Pi,
    const float* __restrict__ Pb, const float* __restrict__ Pc, const float* __restrict__ Pf,
    const float* __restrict__ Wv, const float* __restrict__ Wm, const float* __restrict__ Wi,
    const float* __restrict__ Wb, const float* __restrict__ Wc, const float* __restrict__ Wf,
    const float* __restrict__ bv, const float* __restrict__ bm, const float* __restrict__ bi,
    const float* __restrict__ bb, const float* __restrict__ bc, const float* __restrict__ bf_,
    u16* __restrict__ ws)
{
    int gid = blockIdx.x * 512 + threadIdx.x;
    if (gid < OFF_WENC) {
        const float* src; int N, Ksteps, local;
        if (gid < OFF_WO)      { src = Wqkv; N = 384; Ksteps = 4; local = gid; }
        else if (gid < OFF_WP) { src = Wo;   N = 128; Ksteps = 4; local = gid - OFF_WO; }
        else if (gid < OFF_PV) { src = Wp;   N = 256; Ksteps = 4; local = gid - OFF_WP; }
        else if (gid < OFF_PM) { src = Pv;   N = 128; Ksteps = 2; local = gid - OFF_PV; }
        else if (gid < OFF_PI) { src = Pm;   N = 128; Ksteps = 2; local = gid - OFF_PM; }
        else if (gid < OFF_PB) { src = Pi;   N = 128; Ksteps = 1; local = gid - OFF_PI; }
        else if (gid < OFF_PC) { src = Pb;   N = 128; Ksteps = 1; local = gid - OFF_PB; }
        else if (gid < OFF_PF) { src = Pc;   N = 128; Ksteps = 2; local = gid - OFF_PC; }
        else                   { src = Pf;   N = 128; Ksteps = 4; local = gid - OFF_PF; }
        int j  = local & 7;
        int l  = (local >> 3) & 63;
        int r2 = local >> 9;
        int kk = r2 % Ksteps;
        int nt = r2 / Ksteps;
        int srow = kk * 32 + (l >> 4) * 8 + j;
        int scol = nt * 16 + (l & 15);
        ws[gid] = f2bf(src[srow * N + scol]);
    } else if (gid < OFF_BENC) {
        int local = gid - OFF_WENC;
        int j = local & 7, l = (local >> 3) & 63, r2 = local >> 9;
        int kk = r2 & 1, nt = r2 >> 1;
        int k = kk * 32 + (l >> 4) * 8 + j;
        int r = k & 31;                    // x input dim (0..31, valid <29)
        int scol = nt * 16 + (l & 15);     // 0..383
        const float* W; int cb, xo, din, dout;
        if (scol < 64)       { W = Wv; cb = 0;   xo = 0;  din = 3;  dout = 64; }
        else if (scol < 128) { W = Wm; cb = 64;  xo = 3;  din = 5;  dout = 64; }
        else if (scol < 160) { W = Wi; cb = 128; xo = 8;  din = 2;  dout = 32; }
        else if (scol < 192) { W = Wb; cb = 160; xo = 10; din = 3;  dout = 32; }
        else if (scol < 256) { W = Wc; cb = 192; xo = 13; din = 6;  dout = 64; }
        else                 { W = Wf; cb = 256; xo = 19; din = 10; dout = 128; }
        int rr = r - xo;
        float val = (r < 29 && rr >= 0 && rr < din) ? W[rr * dout + (scol - cb)] : 0.f;
        ws[gid] = f2bf(val);
    } else if (gid < CW_TOTAL) {
        int j = gid - OFF_BENC;
        const float* b; int off;
        if (j < 64)       { b = bv;  off = 0; }
        else if (j < 128) { b = bm;  off = 64; }
        else if (j < 160) { b = bi;  off = 128; }
        else if (j < 192) { b = bb;  off = 160; }
        else if (j < 256) { b = bc;  off = 192; }
        else              { b = bf_; off = 256; }
        ((float*)(ws + OFF_BENC))[j] = b[j - off];
    }
}

// 8 rows/block, 48 tokens (token = comp*8 + row), 512 threads = 8 waves (wave = row).
// Upper half (S0/S1/S2): r5's transposed versions. Lower half (S3..S9): r3 validated.
__global__ __launch_bounds__(512, 4) void asmlp_mfma(
    const float* __restrict__ x,
    const float* __restrict__ pv, const float* __restrict__ pm,
    const float* __restrict__ pi_, const float* __restrict__ pb_,
    const float* __restrict__ pc_, const float* __restrict__ pf_,
    const float* __restrict__ bqkv, const float* __restrict__ bo,
    const float* __restrict__ gg, const float* __restrict__ beta,
    const float* __restrict__ bp,
    const u16* __restrict__ ws,
    float* __restrict__ out)
{
    const int blk  = blockIdx.x;
    const int t    = threadIdx.x;
    const int lane = t & 63;
    const int wv   = t >> 6;
    const int col  = lane & 15;
    const int lg   = lane >> 4;

    __shared__ __attribute__((aligned(16))) u16 sm[30720];   // 61440 B
    u16*   s_tok  = sm;                      // [48 tok][16 g][8] swz g^(tok&15)
    u16*   s_qk   = sm + 6144;               // col-major [256 col][48 tok]    24576 B
    u16*   s_vt   = sm + 18432;              // [16 g2=(rb,hp)][2 ch][16 nn][16 k=p*6+c2,pad12-15]
    u16*   s_ppad = sm + 26624;              // [8 wv][2 slot][16 k][16 m]      8192 B
    u16*   s_xa   = sm + 18432;              // [8 row][64 k] hi/lo, swz low2 (overlay vt)
    u16*   s_h    = sm + 18944;              // [8 row][48 g][8] swz g^row (overlay vt)
    u16*   s_ctx  = sm + 6144;               // [48 tok][16 g][8] (overlay qk low half)
    float* s_out  = (float*)(sm + 12288);    // [8][260] f32 (overlay qk upper; after S6)
    u16*   s_pool = sm + 26624;              // [8 row][16 g][8] (overlay ppad; after PV)

    // ---- S0: stage x as hi/lo bf16 (exact fp32 split), granule-swizzled ----
    if (t < 232) {
        int row = t / 29, cc = t - row * 29;
        float f = x[(size_t)blk * 232 + t];
        u16 hi = f2bf(f);
        float lo = f - bf2f(hi);
        s_xa[row * 64 + (((cc >> 3) ^ (row & 3)) << 3) + (cc & 7)] = hi;
        int c2 = cc + 32;
        s_xa[row * 64 + (((c2 >> 3) ^ (row & 3)) << 3) + (c2 & 7)] = f2bf(lo);
    }
    if (t < 48) {
        int row = t / 6, sl = t - (t / 6) * 6;
        int k = (sl < 3) ? (29 + sl) : (58 + sl);   // 29..31, 61..63
        s_xa[row * 64 + (((k >> 3) ^ (row & 3)) << 3) + (k & 7)] = 0;
    }
    __syncthreads();

    // ---- S1: encoders, transposed MFMA: C[enc_col][row] ----
    {
        int row8 = col & 7;
        short8 B0 = *(const short8*)&s_xa[row8 * 64 + ((lg ^ (row8 & 3)) << 3)];
        short8 B1 = *(const short8*)&s_xa[row8 * 64 + (((4 + lg) ^ (row8 & 3)) << 3)];
        const float* benc = (const float*)(ws + OFF_BENC);
        #pragma unroll
        for (int q = 0; q < 3; ++q) {
            int nt = wv * 3 + q;
            f32x4 acc = *(const f32x4*)&benc[nt * 16 + lg * 4];
            short8 A0 = *(const short8*)&ws[OFF_WENC + (((nt * 2 + 0) * 64 + lane) << 3)];
            short8 A1 = *(const short8*)&ws[OFF_WENC + (((nt * 2 + 1) * 64 + lane) << 3)];
            acc = __builtin_amdgcn_mfma_f32_16x16x32_bf16(A0, B0, acc, 0, 0, 0);
            acc = __builtin_amdgcn_mfma_f32_16x16x32_bf16(A1, B1, acc, 0, 0, 0);
            if (col < 8) {
                int ge = nt * 2 + (lg >> 1);
                uint2 w;
                w.x = cvt_pk_bf16(fmaxf(acc[0], 0.f), fmaxf(acc[1], 0.f));
                w.y = cvt_pk_bf16(fmaxf(acc[2], 0.f), fmaxf(acc[3], 0.f));
                *(uint2*)&s_h[((col * 48 + (ge ^ col)) << 3) + (lg & 1) * 4] = w;
            }
        }
    }
    __syncthreads();

    // ---- S2: projections, transposed: C[proj_col][row] ----
    #pragma unroll
    for (int q = 0; q < 6; ++q) {
        int unit = wv * 6 + q;
        int c = unit >> 3, n = unit & 7;
        const float* bias; int ks, hg, wso;
        switch (c) {
            case 0:  bias = pv;  ks = 2; hg = 0;  wso = OFF_PV; break;
            case 1:  bias = pm;  ks = 2; hg = 8;  wso = OFF_PM; break;
            case 2:  bias = pi_; ks = 1; hg = 16; wso = OFF_PI; break;
            case 3:  bias = pb_; ks = 1; hg = 20; wso = OFF_PB; break;
            case 4:  bias = pc_; ks = 2; hg = 24; wso = OFF_PC; break;
            default: bias = pf_; ks = 4; hg = 32; wso = OFF_PF; break;
        }
        f32x4 acc = *(const f32x4*)&bias[n * 16 + lg * 4];
        int hrow = col & 7;
        for (int kk = 0; kk < ks; ++kk) {
            short8 A = *(const short8*)&ws[wso + (((n * ks + kk) * 64 + lane) << 3)];
            short8 B = *(const short8*)&s_h[(hrow * 48 + ((hg + kk * 4 + lg) ^ hrow)) << 3];
            acc = __builtin_amdgcn_mfma_f32_16x16x32_bf16(A, B, acc, 0, 0, 0);
        }
        if (col < 8) {
            int tok = c * 8 + col;
            int gt = n * 2 + (lg >> 1);
            uint2 w;
            w.x = cvt_pk_bf16(acc[0], acc[1]);
            w.y = cvt_pk_bf16(acc[2], acc[3]);
            *(uint2*)&s_tok[((tok * 16 + (gt ^ (tok & 15))) << 3) + (lg & 1) * 4] = w;
        }
    }
    __syncthreads();

    // ======== lower half: r3 validated code, verbatim ========

    // ---- S3: QKV (MFMA). Q/K -> col-major s_qk (cvt_pk + b64); V -> s_vt ----
    {
        short8 Bf[3][4];
        float  bb_[3];
        #pragma unroll
        for (int ni = 0; ni < 3; ++ni) {
            int n = wv * 3 + ni;
            bb_[ni] = bqkv[n * 16 + col];
            #pragma unroll
            for (int kk = 0; kk < 4; ++kk)
                Bf[ni][kk] = *(const short8*)&ws[OFF_QKV + (((n * 4 + kk) * 64 + lane) << 3)];
        }
        // zero s_vt k-pad (k 12..15), one b64 per thread
        { uint2 z; z.x = 0u; z.y = 0u; *(uint2*)&s_vt[t * 16 + 12] = z; }
        for (int mt = 0; mt < 3; ++mt) {
            short8 A[4];
            int arow = mt * 16 + col;
            #pragma unroll
            for (int kk = 0; kk < 4; ++kk) {
                int g = kk * 4 + lg;
                A[kk] = *(const short8*)&s_tok[(arow * 16 + (g ^ (arow & 15))) << 3];
            }
            #pragma unroll
            for (int ni = 0; ni < 3; ++ni) {
                f32x4 acc = {bb_[ni], bb_[ni], bb_[ni], bb_[ni]};
                #pragma unroll
                for (int kk = 0; kk < 4; ++kk)
                    acc = __builtin_amdgcn_mfma_f32_16x16x32_bf16(A[kk], Bf[ni][kk], acc, 0, 0, 0);
                int cn = wv * 3 + ni;
                int cg = cn * 16 + col;                 // global qkv column
                if (cn < 16) {
                    // Q/K: col-major, token index XOR-swizzled by ((cg>>3)&3)<<2
                    int q4 = ((cg >> 3) & 3) << 2;
                    int tb = (mt * 16 + lg * 4) ^ q4;
                    uint2 w;
                    w.x = cvt_pk_bf16(acc[0], acc[1]);
                    w.y = cvt_pk_bf16(acc[2], acc[3]);
                    *(uint2*)&s_qk[cg * 48 + tb] = w;
                } else {
                    int d = cg - 256;
                    int h = d >> 5, ch = (d >> 4) & 1, nn = d & 15;
                    #pragma unroll
                    for (int r = 0; r < 4; ++r) {
                        int token = mt * 16 + lg * 4 + r;
                        int c2 = token >> 3, rb = token & 7;
                        int g2 = rb * 2 + (h >> 1);
                        int kidx = (h & 1) * 6 + c2;
                        s_vt[((g2 * 2 + ch) * 16 + nn) * 16 + kidx] = f2bf(acc[r]);
                    }
                }
            }
        }
    }
    __syncthreads();

    // ---- SCORES: 2 (row,head) pairs per MFMA; softmax in C-regs -> s_ppad ----
    {
        const int rb = wv;
        #pragma unroll
        for (int i = 0; i < 2; ++i) {
            const int hp = i;
            int p  = (col >= 6 && col < 12) ? 1 : 0;
            int qi = (col < 6) ? col : ((col < 12) ? col - 6 : 0);
            int tt = qi * 8 + rb;
            int h  = hp * 2 + p;
            int tsw = tt ^ (lg << 2);
            int abase = (h * 32 + lg * 8) * 48 + tsw;          // Q cols 0..127
            int bbase = (128 + h * 32 + lg * 8) * 48 + tsw;    // K cols 128..255
            short8 Aq, Bk;
            #pragma unroll
            for (int j = 0; j < 8; ++j) {
                Aq[j] = (short)s_qk[abase + j * 48];
                Bk[j] = (short)s_qk[bbase + j * 48];
            }
            f32x4 sc = {0.f, 0.f, 0.f, 0.f};
            sc = __builtin_amdgcn_mfma_f32_16x16x32_bf16(Aq, Bk, sc, 0, 0, 0);
            u16* pp = s_ppad + (wv * 2 + i) * 256;
            f32x4 pr4;
            #pragma unroll
            for (int r = 0; r < 4; ++r) {
                int mr = lg * 4 + r;
                int prr = (mr >= 6 && mr < 12) ? 1 : 0;
                float v = sc[r] * 0.17677669529663687f;   // 1/sqrt(32)
                bool inR = (col >= 6 * prr) && (col < 6 * prr + 6);
                float mv = inR ? v : -1e30f;
                #pragma unroll
                for (int off = 1; off < 16; off <<= 1)
                    mv = fmaxf(mv, __shfl_xor(mv, off, 16));
                float e = inR ? __expf(v - mv) : 0.f;
                float s = e;
                #pragma unroll
                for (int off = 1; off < 16; off <<= 1)
                    s += __shfl_xor(s, off, 16);
                pr4[r] = (mr < 12) ? (e / s) : 0.f;
            }
            uint2 w;
            w.x = cvt_pk_bf16(pr4[0], pr4[1]);
            w.y = cvt_pk_bf16(pr4[2], pr4[3]);
            *(uint2*)&pp[col * 16 + lg * 4] = w;   // Ppad[k=col][m quad]
        }
    }
    __syncthreads();

    // ---- PV: ctx = P @ V via MFMA (A from ppad block-diag, B b128 from s_vt) ----
    {
        const int rb = wv;
        #pragma unroll
        for (int i = 0; i < 2; ++i) {
            const int hp = i;
            u16* pp = s_ppad + (wv * 2 + i) * 256;
            short8 Ap;
            if (lg < 2) {
                #pragma unroll
                for (int j = 0; j < 8; ++j)
                    Ap[j] = (short)pp[(lg * 8 + j) * 16 + col];
            } else {
                #pragma unroll
                for (int j = 0; j < 8; ++j) Ap[j] = 0;
            }
            int g2 = rb * 2 + hp;
            #pragma unroll
            for (int ch = 0; ch < 2; ++ch) {
                short8 Bv = *(const short8*)&s_vt[(((g2 * 2 + ch) * 16 + col) * 16) + ((lg & 1) * 8)];
                f32x4 c = {0.f, 0.f, 0.f, 0.f};
                c = __builtin_amdgcn_mfma_f32_16x16x32_bf16(Ap, Bv, c, 0, 0, 0);
                #pragma unroll
                for (int r = 0; r < 4; ++r) {
                    int mr = lg * 4 + r;
                    if (mr < 12) {
                        int pq = mr >= 6 ? 1 : 0;
                        int qi = mr - 6 * pq;
                        int token = qi * 8 + rb;
                        int d = (hp * 2 + pq) * 32 + ch * 16 + col;
                        s_ctx[((token * 16 + ((d >> 3) ^ (token & 15))) << 3) + (d & 7)] = f2bf(c[r]);
                    }
                }
            }
        }
    }
    __syncthreads();

    // ---- S6: out-proj + residual + LayerNorm (MFMA + in-register LN) ----
    if (wv < 3) {
        int mt = wv;
        int arow = mt * 16 + col;
        short8 A[4];
        #pragma unroll
        for (int kk = 0; kk < 4; ++kk) {
            int g = kk * 4 + lg;
            A[kk] = *(const short8*)&s_ctx[(arow * 16 + (g ^ (arow & 15))) << 3];
        }
        f32x4 acc[8];
        #pragma unroll
        for (int n = 0; n < 8; ++n) {
            float b = bo[n * 16 + col];
            acc[n] = (f32x4){b, b, b, b};
            #pragma unroll
            for (int kk = 0; kk < 4; ++kk) {
                short8 Bf = *(const short8*)&ws[OFF_WO + (((n * 4 + kk) * 64 + lane) << 3)];
                acc[n] = __builtin_amdgcn_mfma_f32_16x16x32_bf16(A[kk], Bf, acc[n], 0, 0, 0);
            }
        }
        #pragma unroll
        for (int n = 0; n < 8; ++n) {     // residual
            int cn = n * 16 + col;
            #pragma unroll
            for (int r = 0; r < 4; ++r) {
                int row = mt * 16 + lg * 4 + r;
                acc[n][r] += bf2f(s_tok[((row * 16 + ((cn >> 3) ^ (row & 15))) << 3) + (cn & 7)]);
            }
        }
        float mu_[4], rs_[4];
        #pragma unroll
        for (int r = 0; r < 4; ++r) {
            float s1 = 0.f, s2 = 0.f;
            #pragma unroll
            for (int n = 0; n < 8; ++n) { float v = acc[n][r]; s1 += v; s2 += v * v; }
            #pragma unroll
            for (int off = 1; off <= 8; off <<= 1) {
                s1 += __shfl_xor(s1, off, 64);
                s2 += __shfl_xor(s2, off, 64);
            }
            float mu  = s1 * (1.f / 128.f);
            float var = s2 * (1.f / 128.f) - mu * mu;
            mu_[r] = mu;
            rs_[r] = rsqrtf(var + LN_EPS);
        }
        #pragma unroll
        for (int n = 0; n < 8; ++n) {
            int cn = n * 16 + col;
            float gw = gg[cn], bw = beta[cn];
            #pragma unroll
            for (int r = 0; r < 4; ++r) {
                int row = mt * 16 + lg * 4 + r;
                float val = (acc[n][r] - mu_[r]) * rs_[r] * gw + bw;
                s_tok[((row * 16 + ((cn >> 3) ^ (row & 15))) << 3) + (cn & 7)] = f2bf(val);
            }
        }
    }
    __syncthreads();

    // ---- S7: mean-pool over 6 tokens ----
    if (t < 128) {
        int row = t >> 4, gch = t & 15;
        float fa[8] = {0, 0, 0, 0, 0, 0, 0, 0};
        #pragma unroll
        for (int c = 0; c < 6; ++c) {
            int tok = c * 8 + row;
            short8 v = *(const short8*)&s_tok[(tok * 16 + (gch ^ (tok & 15))) << 3];
            #pragma unroll
            for (int j = 0; j < 8; ++j) fa[j] += bf2f((u16)v[j]);
        }
        short8 o;
        #pragma unroll
        for (int j = 0; j < 8; ++j) o[j] = (short)f2bf(fa[j] * (1.f / 6.f));
        *(short8*)&s_pool[(row * 16 + (gch ^ row)) << 3] = o;
    }
    __syncthreads();

    // ---- S8: pooled @ Wp + bp, ReLU ----
    {
        int arow = col & 7;
        short8 A[4];
        #pragma unroll
        for (int kk = 0; kk < 4; ++kk) {
            int g = kk * 4 + lg;
            A[kk] = *(const short8*)&s_pool[(arow * 16 + (g ^ arow)) << 3];
        }
        #pragma unroll
        for (int ni = 0; ni < 2; ++ni) {
            int n = wv * 2 + ni;
            float b = bp[n * 16 + col];
            f32x4 acc = {b, b, b, b};
            #pragma unroll
            for (int kk = 0; kk < 4; ++kk) {
                short8 Bf = *(const short8*)&ws[OFF_WP + (((n * 4 + kk) * 64 + lane) << 3)];
                acc = __builtin_amdgcn_mfma_f32_16x16x32_bf16(A[kk], Bf, acc, 0, 0, 0);
            }
            if (lg < 2) {
                #pragma unroll
                for (int r = 0; r < 4; ++r) {
                    int row = lg * 4 + r;
                    s_out[row * 260 + n * 16 + col] = fmaxf(acc[r], 0.f);
                }
            }
        }
    }
    __syncthreads();

    // ---- S9: coalesced store ----
    if (t < 256) {
        int row = t >> 5, c8 = (t & 31) * 8;
        f32x4 v0 = *(const f32x4*)&s_out[row * 260 + c8];
        f32x4 v1 = *(const f32x4*)&s_out[row * 260 + c8 + 4];
        float* dst = out + ((size_t)blk * 8 + row) * 256 + c8;
        *(f32x4*)dst = v0;
        *(f32x4*)(dst + 4) = v1;
    }
}

extern "C" void kernel_launch(void* const* d_in, const int* in_sizes, int n_in,
                              void* d_out, int out_size, void* d_ws, size_t ws_size,
                              hipStream_t stream) {
    const float* x    = (const float*)d_in[0];
    const float* Wv   = (const float*)d_in[1];
    const float* bv   = (const float*)d_in[2];
    const float* Wm   = (const float*)d_in[3];
    const float* bm   = (const float*)d_in[4];
    const float* Wi   = (const float*)d_in[5];
    const float* bi   = (const float*)d_in[6];
    const float* Wb   = (const float*)d_in[7];
    const float* bb   = (const float*)d_in[8];
    const float* Wc   = (const float*)d_in[9];
    const float* bc   = (const float*)d_in[10];
    const float* Wf   = (const float*)d_in[11];
    const float* bf_  = (const float*)d_in[12];
    const float* Pv   = (const float*)d_in[13];
    const float* pv   = (const float*)d_in[14];
    const float* Pm   = (const float*)d_in[15];
    const float* pm   = (const float*)d_in[16];
    const float* Pi   = (const float*)d_in[17];
    const float* pii  = (const float*)d_in[18];
    const float* Pb   = (const float*)d_in[19];
    const float* pb   = (const float*)d_in[20];
    const float* Pc   = (const float*)d_in[21];
    const float* pc   = (const float*)d_in[22];
    const float* Pf   = (const float*)d_in[23];
    const float* pf   = (const float*)d_in[24];
    const float* Wqkv = (const float*)d_in[25];
    const float* bqkv = (const float*)d_in[26];
    const float* Wo   = (const float*)d_in[27];
    const float* bo   = (const float*)d_in[28];
    const float* gg   = (const float*)d_in[29];
    const float* beta = (const float*)d_in[30];
    const float* Wp   = (const float*)d_in[31];
    const float* bp   = (const float*)d_in[32];
    float* out = (float*)d_out;
    u16* ws = (u16*)d_ws;

    convert_weights<<<(CW_TOTAL + 511) / 512, 512, 0, stream>>>(
        Wqkv, Wo, Wp, Pv, Pm, Pi, Pb, Pc, Pf,
        Wv, Wm, Wi, Wb, Wc, Wf, bv, bm, bi, bb, bc, bf_, ws);

    const int Bn = in_sizes[0] / 29;       // 65536
    asmlp_mfma<<<Bn / 8, 512, 0, stream>>>(
        x, pv, pm, pii, pb, pc, pf,
        bqkv, bo, gg, beta, bp, ws, out);
}

// Round 8
// 294.193 us; speedup vs baseline: 6.0297x; 1.0009x over previous
//
#include <hip/hip_runtime.h>
#include <math.h>

typedef float f32x4 __attribute__((ext_vector_type(4)));
typedef short short8 __attribute__((ext_vector_type(8)));
typedef unsigned short u16;

#define LN_EPS 1e-5f

static __device__ __forceinline__ unsigned cvt_pk_bf16(float lo, float hi) {
    unsigned r;
    asm("v_cvt_pk_bf16_f32 %0, %1, %2" : "=v"(r) : "v"(lo), "v"(hi));
    return r;
}
static __device__ __forceinline__ u16 f2bf(float f) { return (u16)cvt_pk_bf16(f, f); }
static __device__ __forceinline__ float bf2f(u16 u) {
    return __uint_as_float(((unsigned)u) << 16);
}

// ws segment offsets (u16 elements). Fragment-linear layout (works as A- or B-operand):
// idx = ((ntile*Ksteps + kk)*64 + lane)*8 + j -> W[kk*32+(lane>>4)*8+j][ntile*16+(lane&15)]
#define OFF_QKV 0
#define OFF_WO  49152
#define OFF_WP  65536
#define OFF_PV  98304
#define OFF_PM  106496
#define OFF_PI  114688
#define OFF_PB  118784
#define OFF_PC  122880
#define OFF_PF  131072
#define OFF_WENC 147456     // block-diag encoder weight, hi/lo stacked: 24 ntiles x 2 ksteps
#define OFF_BENC 172032     // f32 region (384 floats) starts at this u16 index
#define CW_TOTAL 172416

__global__ __launch_bounds__(512) void convert_weights(
    const float* __restrict__ Wqkv, const float* __restrict__ Wo, const float* __restrict__ Wp,
    const float* __restrict__ Pv, const float* __restrict__ Pm, const float* __restrict__ Pi,
    const float* __restrict__ Pb, const float* __restrict__ Pc, const float* __restrict__ Pf,
    const float* __restrict__ Wv, const float* __restrict__ Wm, const float* __restrict__ Wi,
    const float* __restrict__ Wb, const float* __restrict__ Wc, const float* __restrict__ Wf,
    const float* __restrict__ bv, const float* __restrict__ bm, const float* __restrict__ bi,
    const float* __restrict__ bb, const float* __restrict__ bc, const float* __restrict__ bf_,
    u16* __restrict__ ws)
{
    int gid = blockIdx.x * 512 + threadIdx.x;
    if (gid < OFF_WENC) {
        const float* src; int N, Ksteps, local;
        if (gid < OFF_WO)      { src = Wqkv; N = 384; Ksteps = 4; local = gid; }
        else if (gid < OFF_WP) { src = Wo;   N = 128; Ksteps = 4; local = gid - OFF_WO; }
        else if (gid < OFF_PV) { src = Wp;   N = 256; Ksteps = 4; local = gid - OFF_WP; }
        else if (gid < OFF_PM) { src = Pv;   N = 128; Ksteps = 2; local = gid - OFF_PV; }
        else if (gid < OFF_PI) { src = Pm;   N = 128; Ksteps = 2; local = gid - OFF_PM; }
        else if (gid < OFF_PB) { src = Pi;   N = 128; Ksteps = 1; local = gid - OFF_PI; }
        else if (gid < OFF_PC) { src = Pb;   N = 128; Ksteps = 1; local = gid - OFF_PB; }
        else if (gid < OFF_PF) { src = Pc;   N = 128; Ksteps = 2; local = gid - OFF_PC; }
        else                   { src = Pf;   N = 128; Ksteps = 4; local = gid - OFF_PF; }
        int j  = local & 7;
        int l  = (local >> 3) & 63;
        int r2 = local >> 9;
        int kk = r2 % Ksteps;
        int nt = r2 / Ksteps;
        int srow = kk * 32 + (l >> 4) * 8 + j;
        int scol = nt * 16 + (l & 15);
        ws[gid] = f2bf(src[srow * N + scol]);
    } else if (gid < OFF_BENC) {
        int local = gid - OFF_WENC;
        int j = local & 7, l = (local >> 3) & 63, r2 = local >> 9;
        int kk = r2 & 1, nt = r2 >> 1;
        int k = kk * 32 + (l >> 4) * 8 + j;
        int r = k & 31;                    // x input dim (0..31, valid <29)
        int scol = nt * 16 + (l & 15);     // 0..383
        const float* W; int cb, xo, din, dout;
        if (scol < 64)       { W = Wv; cb = 0;   xo = 0;  din = 3;  dout = 64; }
        else if (scol < 128) { W = Wm; cb = 64;  xo = 3;  din = 5;  dout = 64; }
        else if (scol < 160) { W = Wi; cb = 128; xo = 8;  din = 2;  dout = 32; }
        else if (scol < 192) { W = Wb; cb = 160; xo = 10; din = 3;  dout = 32; }
        else if (scol < 256) { W = Wc; cb = 192; xo = 13; din = 6;  dout = 64; }
        else                 { W = Wf; cb = 256; xo = 19; din = 10; dout = 128; }
        int rr = r - xo;
        float val = (r < 29 && rr >= 0 && rr < din) ? W[rr * dout + (scol - cb)] : 0.f;
        ws[gid] = f2bf(val);
    } else if (gid < CW_TOTAL) {
        int j = gid - OFF_BENC;
        const float* b; int off;
        if (j < 64)       { b = bv;  off = 0; }
        else if (j < 128) { b = bm;  off = 64; }
        else if (j < 160) { b = bi;  off = 128; }
        else if (j < 192) { b = bb;  off = 160; }
        else if (j < 256) { b = bc;  off = 192; }
        else              { b = bf_; off = 256; }
        ((float*)(ws + OFF_BENC))[j] = b[j - off];
    }
}

// 8 rows/block, 48 tokens (token = comp*8 + row), 512 threads = 8 waves (wave = row).
// r6 (validated) with LDS cut 61440 -> 53248 B: P-tile (s_pp) overlays the dead s_qk
// upper half after the scores MFMAs (score fragments persist in registers across a
// new barrier). 3 blocks/CU instead of 2.
__global__ __launch_bounds__(512, 4) void asmlp_mfma(
    const float* __restrict__ x,
    const float* __restrict__ pv, const float* __restrict__ pm,
    const float* __restrict__ pi_, const float* __restrict__ pb_,
    const float* __restrict__ pc_, const float* __restrict__ pf_,
    const float* __restrict__ bqkv, const float* __restrict__ bo,
    const float* __restrict__ gg, const float* __restrict__ beta,
    const float* __restrict__ bp,
    const u16* __restrict__ ws,
    float* __restrict__ out)
{
    const int blk  = blockIdx.x;
    const int t    = threadIdx.x;
    const int lane = t & 63;
    const int wv   = t >> 6;
    const int col  = lane & 15;
    const int lg   = lane >> 4;

    __shared__ __attribute__((aligned(16))) u16 sm[26624];   // 53248 B -> 3 blocks/CU
    u16*   s_tok  = sm;                      // [48 tok][16 g][8] swz g^(tok&15)   12288 B
    u16*   s_qk   = sm + 6144;               // col-major [256 col][48 tok]        24576 B (dead after scores MFMA)
    u16*   s_vt   = sm + 18432;              // [16 g2=(rb,hp)][2 ch][16 nn][16 k=p*6+c2,pad12-15] 16384 B
    u16*   s_xa   = sm + 18432;              // [8 row][64 k] hi/lo, swz low2 (overlay vt)
    u16*   s_h    = sm + 18944;              // [8 row][48 g][8] swz g^row (overlay vt)
    u16*   s_ctx  = sm + 6144;               // [48 tok][16 g][8] (overlay s_qk low half, after scores)
    u16*   s_pp   = sm + 12288;              // [8 wv][2 slot][16 k][16 m] 8192 B (overlay s_qk up half, after scores)
    float* s_out  = (float*)(sm + 12288);    // [8][260] f32 (overlay s_pp region; after PV/S6)
    u16*   s_pool = sm + 18432;              // [8 row][16 g][8] (overlay vt; after PV)

    // ---- S0: stage x as hi/lo bf16 (exact fp32 split), granule-swizzled ----
    if (t < 232) {
        int row = t / 29, cc = t - row * 29;
        float f = x[(size_t)blk * 232 + t];
        u16 hi = f2bf(f);
        float lo = f - bf2f(hi);
        s_xa[row * 64 + (((cc >> 3) ^ (row & 3)) << 3) + (cc & 7)] = hi;
        int c2 = cc + 32;
        s_xa[row * 64 + (((c2 >> 3) ^ (row & 3)) << 3) + (c2 & 7)] = f2bf(lo);
    }
    if (t < 48) {
        int row = t / 6, sl = t - (t / 6) * 6;
        int k = (sl < 3) ? (29 + sl) : (58 + sl);   // 29..31, 61..63
        s_xa[row * 64 + (((k >> 3) ^ (row & 3)) << 3) + (k & 7)] = 0;
    }
    __syncthreads();

    // ---- S1: encoders, transposed MFMA: C[enc_col][row] ----
    {
        int row8 = col & 7;
        short8 B0 = *(const short8*)&s_xa[row8 * 64 + ((lg ^ (row8 & 3)) << 3)];
        short8 B1 = *(const short8*)&s_xa[row8 * 64 + (((4 + lg) ^ (row8 & 3)) << 3)];
        const float* benc = (const float*)(ws + OFF_BENC);
        #pragma unroll
        for (int q = 0; q < 3; ++q) {
            int nt = wv * 3 + q;
            f32x4 acc = *(const f32x4*)&benc[nt * 16 + lg * 4];
            short8 A0 = *(const short8*)&ws[OFF_WENC + (((nt * 2 + 0) * 64 + lane) << 3)];
            short8 A1 = *(const short8*)&ws[OFF_WENC + (((nt * 2 + 1) * 64 + lane) << 3)];
            acc = __builtin_amdgcn_mfma_f32_16x16x32_bf16(A0, B0, acc, 0, 0, 0);
            acc = __builtin_amdgcn_mfma_f32_16x16x32_bf16(A1, B1, acc, 0, 0, 0);
            if (col < 8) {
                int ge = nt * 2 + (lg >> 1);
                uint2 w;
                w.x = cvt_pk_bf16(fmaxf(acc[0], 0.f), fmaxf(acc[1], 0.f));
                w.y = cvt_pk_bf16(fmaxf(acc[2], 0.f), fmaxf(acc[3], 0.f));
                *(uint2*)&s_h[((col * 48 + (ge ^ col)) << 3) + (lg & 1) * 4] = w;
            }
        }
    }
    __syncthreads();

    // ---- S2: projections, transposed: C[proj_col][row] ----
    #pragma unroll
    for (int q = 0; q < 6; ++q) {
        int unit = wv * 6 + q;
        int c = unit >> 3, n = unit & 7;
        const float* bias; int ks, hg, wso;
        switch (c) {
            case 0:  bias = pv;  ks = 2; hg = 0;  wso = OFF_PV; break;
            case 1:  bias = pm;  ks = 2; hg = 8;  wso = OFF_PM; break;
            case 2:  bias = pi_; ks = 1; hg = 16; wso = OFF_PI; break;
            case 3:  bias = pb_; ks = 1; hg = 20; wso = OFF_PB; break;
            case 4:  bias = pc_; ks = 2; hg = 24; wso = OFF_PC; break;
            default: bias = pf_; ks = 4; hg = 32; wso = OFF_PF; break;
        }
        f32x4 acc = *(const f32x4*)&bias[n * 16 + lg * 4];
        int hrow = col & 7;
        for (int kk = 0; kk < ks; ++kk) {
            short8 A = *(const short8*)&ws[wso + (((n * ks + kk) * 64 + lane) << 3)];
            short8 B = *(const short8*)&s_h[(hrow * 48 + ((hg + kk * 4 + lg) ^ hrow)) << 3];
            acc = __builtin_amdgcn_mfma_f32_16x16x32_bf16(A, B, acc, 0, 0, 0);
        }
        if (col < 8) {
            int tok = c * 8 + col;
            int gt = n * 2 + (lg >> 1);
            uint2 w;
            w.x = cvt_pk_bf16(acc[0], acc[1]);
            w.y = cvt_pk_bf16(acc[2], acc[3]);
            *(uint2*)&s_tok[((tok * 16 + (gt ^ (tok & 15))) << 3) + (lg & 1) * 4] = w;
        }
    }
    __syncthreads();

    // ---- S3: QKV (MFMA). Q/K -> col-major s_qk (cvt_pk + b64); V -> s_vt ----
    {
        short8 Bf[3][4];
        float  bb_[3];
        #pragma unroll
        for (int ni = 0; ni < 3; ++ni) {
            int n = wv * 3 + ni;
            bb_[ni] = bqkv[n * 16 + col];
            #pragma unroll
            for (int kk = 0; kk < 4; ++kk)
                Bf[ni][kk] = *(const short8*)&ws[OFF_QKV + (((n * 4 + kk) * 64 + lane) << 3)];
        }
        // zero s_vt k-pad (k 12..15), one b64 per thread
        { uint2 z; z.x = 0u; z.y = 0u; *(uint2*)&s_vt[t * 16 + 12] = z; }
        for (int mt = 0; mt < 3; ++mt) {
            short8 A[4];
            int arow = mt * 16 + col;
            #pragma unroll
            for (int kk = 0; kk < 4; ++kk) {
                int g = kk * 4 + lg;
                A[kk] = *(const short8*)&s_tok[(arow * 16 + (g ^ (arow & 15))) << 3];
            }
            #pragma unroll
            for (int ni = 0; ni < 3; ++ni) {
                f32x4 acc = {bb_[ni], bb_[ni], bb_[ni], bb_[ni]};
                #pragma unroll
                for (int kk = 0; kk < 4; ++kk)
                    acc = __builtin_amdgcn_mfma_f32_16x16x32_bf16(A[kk], Bf[ni][kk], acc, 0, 0, 0);
                int cn = wv * 3 + ni;
                int cg = cn * 16 + col;                 // global qkv column
                if (cn < 16) {
                    // Q/K: col-major, token index XOR-swizzled by ((cg>>3)&3)<<2
                    int q4 = ((cg >> 3) & 3) << 2;
                    int tb = (mt * 16 + lg * 4) ^ q4;
                    uint2 w;
                    w.x = cvt_pk_bf16(acc[0], acc[1]);
                    w.y = cvt_pk_bf16(acc[2], acc[3]);
                    *(uint2*)&s_qk[cg * 48 + tb] = w;
                } else {
                    int d = cg - 256;
                    int h = d >> 5, ch = (d >> 4) & 1, nn = d & 15;
                    #pragma unroll
                    for (int r = 0; r < 4; ++r) {
                        int token = mt * 16 + lg * 4 + r;
                        int c2 = token >> 3, rb = token & 7;
                        int g2 = rb * 2 + (h >> 1);
                        int kidx = (h & 1) * 6 + c2;
                        s_vt[((g2 * 2 + ch) * 16 + nn) * 16 + kidx] = f2bf(acc[r]);
                    }
                }
            }
        }
    }
    __syncthreads();

    // ---- SCORES phase 1: MFMAs only (last readers of s_qk) ----
    f32x4 scf[2];
    {
        const int rb = wv;
        #pragma unroll
        for (int i = 0; i < 2; ++i) {
            const int hp = i;
            int p  = (col >= 6 && col < 12) ? 1 : 0;
            int qi = (col < 6) ? col : ((col < 12) ? col - 6 : 0);
            int tt = qi * 8 + rb;
            int h  = hp * 2 + p;
            int tsw = tt ^ (lg << 2);
            int abase = (h * 32 + lg * 8) * 48 + tsw;          // Q cols 0..127
            int bbase = (128 + h * 32 + lg * 8) * 48 + tsw;    // K cols 128..255
            short8 Aq, Bk;
            #pragma unroll
            for (int j = 0; j < 8; ++j) {
                Aq[j] = (short)s_qk[abase + j * 48];
                Bk[j] = (short)s_qk[bbase + j * 48];
            }
            f32x4 sc = {0.f, 0.f, 0.f, 0.f};
            scf[i] = __builtin_amdgcn_mfma_f32_16x16x32_bf16(Aq, Bk, sc, 0, 0, 0);
        }
    }
    __syncthreads();   // s_qk now dead -> its space becomes s_ctx + s_pp

    // ---- SCORES phase 2: softmax in C-regs -> s_pp (overlay) ----
    {
        #pragma unroll
        for (int i = 0; i < 2; ++i) {
            u16* pp = s_pp + (wv * 2 + i) * 256;
            f32x4 pr4;
            #pragma unroll
            for (int r = 0; r < 4; ++r) {
                int mr = lg * 4 + r;
                int prr = (mr >= 6 && mr < 12) ? 1 : 0;
                float v = scf[i][r] * 0.17677669529663687f;   // 1/sqrt(32)
                bool inR = (col >= 6 * prr) && (col < 6 * prr + 6);
                float mv = inR ? v : -1e30f;
                #pragma unroll
                for (int off = 1; off < 16; off <<= 1)
                    mv = fmaxf(mv, __shfl_xor(mv, off, 16));
                float e = inR ? __expf(v - mv) : 0.f;
                float s = e;
                #pragma unroll
                for (int off = 1; off < 16; off <<= 1)
                    s += __shfl_xor(s, off, 16);
                pr4[r] = (mr < 12) ? (e / s) : 0.f;
            }
            uint2 w;
            w.x = cvt_pk_bf16(pr4[0], pr4[1]);
            w.y = cvt_pk_bf16(pr4[2], pr4[3]);
            *(uint2*)&pp[col * 16 + lg * 4] = w;   // Ppad[k=col][m quad]
        }
    }
    __syncthreads();

    // ---- PV: ctx = P @ V via MFMA (A from s_pp block-diag, B b128 from s_vt) ----
    {
        const int rb = wv;
        #pragma unroll
        for (int i = 0; i < 2; ++i) {
            const int hp = i;
            u16* pp = s_pp + (wv * 2 + i) * 256;
            short8 Ap;
            if (lg < 2) {
                #pragma unroll
                for (int j = 0; j < 8; ++j)
                    Ap[j] = (short)pp[(lg * 8 + j) * 16 + col];
            } else {
                #pragma unroll
                for (int j = 0; j < 8; ++j) Ap[j] = 0;
            }
            int g2 = rb * 2 + hp;
            #pragma unroll
            for (int ch = 0; ch < 2; ++ch) {
                short8 Bv = *(const short8*)&s_vt[(((g2 * 2 + ch) * 16 + col) * 16) + ((lg & 1) * 8)];
                f32x4 c = {0.f, 0.f, 0.f, 0.f};
                c = __builtin_amdgcn_mfma_f32_16x16x32_bf16(Ap, Bv, c, 0, 0, 0);
                #pragma unroll
                for (int r = 0; r < 4; ++r) {
                    int mr = lg * 4 + r;
                    if (mr < 12) {
                        int pq = mr >= 6 ? 1 : 0;
                        int qi = mr - 6 * pq;
                        int token = qi * 8 + rb;
                        int d = (hp * 2 + pq) * 32 + ch * 16 + col;
                        s_ctx[((token * 16 + ((d >> 3) ^ (token & 15))) << 3) + (d & 7)] = f2bf(c[r]);
                    }
                }
            }
        }
    }
    __syncthreads();

    // ---- S6: out-proj + residual + LayerNorm (MFMA + in-register LN) ----
    if (wv < 3) {
        int mt = wv;
        int arow = mt * 16 + col;
        short8 A[4];
        #pragma unroll
        for (int kk = 0; kk < 4; ++kk) {
            int g = kk * 4 + lg;
            A[kk] = *(const short8*)&s_ctx[(arow * 16 + (g ^ (arow & 15))) << 3];
        }
        f32x4 acc[8];
        #pragma unroll
        for (int n = 0; n < 8; ++n) {
            float b = bo[n * 16 + col];
            acc[n] = (f32x4){b, b, b, b};
            #pragma unroll
            for (int kk = 0; kk < 4; ++kk) {
                short8 Bf = *(const short8*)&ws[OFF_WO + (((n * 4 + kk) * 64 + lane) << 3)];
                acc[n] = __builtin_amdgcn_mfma_f32_16x16x32_bf16(A[kk], Bf, acc[n], 0, 0, 0);
            }
        }
        #pragma unroll
        for (int n = 0; n < 8; ++n) {     // residual
            int cn = n * 16 + col;
            #pragma unroll
            for (int r = 0; r < 4; ++r) {
                int row = mt * 16 + lg * 4 + r;
                acc[n][r] += bf2f(s_tok[((row * 16 + ((cn >> 3) ^ (row & 15))) << 3) + (cn & 7)]);
            }
        }
        float mu_[4], rs_[4];
        #pragma unroll
        for (int r = 0; r < 4; ++r) {
            float s1 = 0.f, s2 = 0.f;
            #pragma unroll
            for (int n = 0; n < 8; ++n) { float v = acc[n][r]; s1 += v; s2 += v * v; }
            #pragma unroll
            for (int off = 1; off <= 8; off <<= 1) {
                s1 += __shfl_xor(s1, off, 64);
                s2 += __shfl_xor(s2, off, 64);
            }
            float mu  = s1 * (1.f / 128.f);
            float var = s2 * (1.f / 128.f) - mu * mu;
            mu_[r] = mu;
            rs_[r] = rsqrtf(var + LN_EPS);
        }
        #pragma unroll
        for (int n = 0; n < 8; ++n) {
            int cn = n * 16 + col;
            float gw = gg[cn], bw = beta[cn];
            #pragma unroll
            for (int r = 0; r < 4; ++r) {
                int row = mt * 16 + lg * 4 + r;
                float val = (acc[n][r] - mu_[r]) * rs_[r] * gw + bw;
                s_tok[((row * 16 + ((cn >> 3) ^ (row & 15))) << 3) + (cn & 7)] = f2bf(val);
            }
        }
    }
    __syncthreads();

    // ---- S7: mean-pool over 6 tokens ----
    if (t < 128) {
        int row = t >> 4, gch = t & 15;
        float fa[8] = {0, 0, 0, 0, 0, 0, 0, 0};
        #pragma unroll
        for (int c = 0; c < 6; ++c) {
            int tok = c * 8 + row;
            short8 v = *(const short8*)&s_tok[(tok * 16 + (gch ^ (tok & 15))) << 3];
            #pragma unroll
            for (int j = 0; j < 8; ++j) fa[j] += bf2f((u16)v[j]);
        }
        short8 o;
        #pragma unroll
        for (int j = 0; j < 8; ++j) o[j] = (short)f2bf(fa[j] * (1.f / 6.f));
        *(short8*)&s_pool[(row * 16 + (gch ^ row)) << 3] = o;
    }
    __syncthreads();

    // ---- S8: pooled @ Wp + bp, ReLU ----
    {
        int arow = col & 7;
        short8 A[4];
        #pragma unroll
        for (int kk = 0; kk < 4; ++kk) {
            int g = kk * 4 + lg;
            A[kk] = *(const short8*)&s_pool[(arow * 16 + (g ^ arow)) << 3];
        }
        #pragma unroll
        for (int ni = 0; ni < 2; ++ni) {
            int n = wv * 2 + ni;
            float b = bp[n * 16 + col];
            f32x4 acc = {b, b, b, b};
            #pragma unroll
            for (int kk = 0; kk < 4; ++kk) {
                short8 Bf = *(const short8*)&ws[OFF_WP + (((n * 4 + kk) * 64 + lane) << 3)];
                acc = __builtin_amdgcn_mfma_f32_16x16x32_bf16(A[kk], Bf, acc, 0, 0, 0);
            }
            if (lg < 2) {
                #pragma unroll
                for (int r = 0; r < 4; ++r) {
                    int row = lg * 4 + r;
                    s_out[row * 260 + n * 16 + col] = fmaxf(acc[r], 0.f);
                }
            }
        }
    }
    __syncthreads();

    // ---- S9: coalesced store ----
    if (t < 256) {
        int row = t >> 5, c8 = (t & 31) * 8;
        f32x4 v0 = *(const f32x4*)&s_out[row * 260 + c8];
        f32x4 v1 = *(const f32x4*)&s_out[row * 260 + c8 + 4];
        float* dst = out + ((size_t)blk * 8 + row) * 256 + c8;
        *(f32x4*)dst = v0;
        *(f32x4*)(dst + 4) = v1;
    }
}

extern "C" void kernel_launch(void* const* d_in, const int* in_sizes, int n_in,
                              void* d_out, int out_size, void* d_ws, size_t ws_size,
                              hipStream_t stream) {
    const float* x    = (const float*)d_in[0];
    const float* Wv   = (const float*)d_in[1];
    const float* bv   = (const float*)d_in[2];
    const float* Wm   = (const float*)d_in[3];
    const float* bm   = (const float*)d_in[4];
    const float* Wi   = (const float*)d_in[5];
    const float* bi   = (const float*)d_in[6];
    const float* Wb   = (const float*)d_in[7];
    const float* bb   = (const float*)d_in[8];
    const float* Wc   = (const float*)d_in[9];
    const float* bc   = (const float*)d_in[10];
    const float* Wf   = (const float*)d_in[11];
    const float* bf_  = (const float*)d_in[12];
    const float* Pv   = (const float*)d_in[13];
    const float* pv   = (const float*)d_in[14];
    const float* Pm   = (const float*)d_in[15];
    const float* pm   = (const float*)d_in[16];
    const float* Pi   = (const float*)d_in[17];
    const float* pii  = (const float*)d_in[18];
    const float* Pb   = (const float*)d_in[19];
    const float* pb   = (const float*)d_in[20];
    const float* Pc   = (const float*)d_in[21];
    const float* pc   = (const float*)d_in[22];
    const float* Pf   = (const float*)d_in[23];
    const float* pf   = (const float*)d_in[24];
    const float* Wqkv = (const float*)d_in[25];
    const float* bqkv = (const float*)d_in[26];
    const float* Wo   = (const float*)d_in[27];
    const float* bo   = (const float*)d_in[28];
    const float* gg   = (const float*)d_in[29];
    const float* beta = (const float*)d_in[30];
    const float* Wp   = (const float*)d_in[31];
    const float* bp   = (const float*)d_in[32];
    float* out = (float*)d_out;
    u16* ws = (u16*)d_ws;

    convert_weights<<<(CW_TOTAL + 511) / 512, 512, 0, stream>>>(
        Wqkv, Wo, Wp, Pv, Pm, Pi, Pb, Pc, Pf,
        Wv, Wm, Wi, Wb, Wc, Wf, bv, bm, bi, bb, bc, bf_, ws);

    const int Bn = in_sizes[0] / 29;       // 65536
    asmlp_mfma<<<Bn / 8, 512, 0, stream>>>(
        x, pv, pm, pii, pb, pc, pf,
        bqkv, bo, gg, beta, bp, ws, out);
}

// Round 10
// 288.001 us; speedup vs baseline: 6.1594x; 1.0215x over previous
//
#include <hip/hip_runtime.h>
#include <math.h>

typedef float f32x4 __attribute__((ext_vector_type(4)));
typedef short short8 __attribute__((ext_vector_type(8)));
typedef unsigned short u16;

#define LN_EPS 1e-5f

static __device__ __forceinline__ unsigned cvt_pk_bf16(float lo, float hi) {
    unsigned r;
    asm("v_cvt_pk_bf16_f32 %0, %1, %2" : "=v"(r) : "v"(lo), "v"(hi));
    return r;
}
static __device__ __forceinline__ u16 f2bf(float f) { return (u16)cvt_pk_bf16(f, f); }
static __device__ __forceinline__ float bf2f(u16 u) {
    return __uint_as_float(((unsigned)u) << 16);
}

// ws segment offsets (u16 elements). Fragment-linear layout (works as A- or B-operand):
// idx = ((ntile*Ksteps + kk)*64 + lane)*8 + j -> W[kk*32+(lane>>4)*8+j][ntile*16+(lane&15)]
#define OFF_QKV 0
#define OFF_WO  49152
#define OFF_WP  65536
#define OFF_PV  98304
#define OFF_PM  106496
#define OFF_PI  114688
#define OFF_PB  118784
#define OFF_PC  122880
#define OFF_PF  131072
#define OFF_WENC 147456     // block-diag encoder weight, hi/lo stacked: 24 ntiles x 2 ksteps
#define OFF_BENC 172032     // f32 region (384 floats) starts at this u16 index
#define CW_TOTAL 172416

__global__ __launch_bounds__(512) void convert_weights(
    const float* __restrict__ Wqkv, const float* __restrict__ Wo, const float* __restrict__ Wp,
    const float* __restrict__ Pv, const float* __restrict__ Pm, const float* __restrict__ Pi,
    const float* __restrict__ Pb, const float* __restrict__ Pc, const float* __restrict__ Pf,
    const float* __restrict__ Wv, const float* __restrict__ Wm, const float* __restrict__ Wi,
    const float* __restrict__ Wb, const float* __restrict__ Wc, const float* __restrict__ Wf,
    const float* __restrict__ bv, const float* __restrict__ bm, const float* __restrict__ bi,
    const float* __restrict__ bb, const float* __restrict__ bc, const float* __restrict__ bf_,
    u16* __restrict__ ws)
{
    int gid = blockIdx.x * 512 + threadIdx.x;
    if (gid < OFF_WENC) {
        const float* src; int N, Ksteps, local;
        if (gid < OFF_WO)      { src = Wqkv; N = 384; Ksteps = 4; local = gid; }
        else if (gid < OFF_WP) { src = Wo;   N = 128; Ksteps = 4; local = gid - OFF_WO; }
        else if (gid < OFF_PV) { src = Wp;   N = 256; Ksteps = 4; local = gid - OFF_WP; }
        else if (gid < OFF_PM) { src = Pv;   N = 128; Ksteps = 2; local = gid - OFF_PV; }
        else if (gid < OFF_PI) { src = Pm;   N = 128; Ksteps = 2; local = gid - OFF_PM; }
        else if (gid < OFF_PB) { src = Pi;   N = 128; Ksteps = 1; local = gid - OFF_PI; }
        else if (gid < OFF_PC) { src = Pb;   N = 128; Ksteps = 1; local = gid - OFF_PB; }
        else if (gid < OFF_PF) { src = Pc;   N = 128; Ksteps = 2; local = gid - OFF_PC; }
        else                   { src = Pf;   N = 128; Ksteps = 4; local = gid - OFF_PF; }
        int j  = local & 7;
        int l  = (local >> 3) & 63;
        int r2 = local >> 9;
        int kk = r2 % Ksteps;
        int nt = r2 / Ksteps;
        int srow = kk * 32 + (l >> 4) * 8 + j;
        int scol = nt * 16 + (l & 15);
        ws[gid] = f2bf(src[srow * N + scol]);
    } else if (gid < OFF_BENC) {
        int local = gid - OFF_WENC;
        int j = local & 7, l = (local >> 3) & 63, r2 = local >> 9;
        int kk = r2 & 1, nt = r2 >> 1;
        int k = kk * 32 + (l >> 4) * 8 + j;
        int r = k & 31;                    // x input dim (0..31, valid <29)
        int scol = nt * 16 + (l & 15);     // 0..383
        const float* W; int cb, xo, din, dout;
        if (scol < 64)       { W = Wv; cb = 0;   xo = 0;  din = 3;  dout = 64; }
        else if (scol < 128) { W = Wm; cb = 64;  xo = 3;  din = 5;  dout = 64; }
        else if (scol < 160) { W = Wi; cb = 128; xo = 8;  din = 2;  dout = 32; }
        else if (scol < 192) { W = Wb; cb = 160; xo = 10; din = 3;  dout = 32; }
        else if (scol < 256) { W = Wc; cb = 192; xo = 13; din = 6;  dout = 64; }
        else                 { W = Wf; cb = 256; xo = 19; din = 10; dout = 128; }
        int rr = r - xo;
        float val = (r < 29 && rr >= 0 && rr < din) ? W[rr * dout + (scol - cb)] : 0.f;
        ws[gid] = f2bf(val);
    } else if (gid < CW_TOTAL) {
        int j = gid - OFF_BENC;
        const float* b; int off;
        if (j < 64)       { b = bv;  off = 0; }
        else if (j < 128) { b = bm;  off = 64; }
        else if (j < 160) { b = bi;  off = 128; }
        else if (j < 192) { b = bb;  off = 160; }
        else if (j < 256) { b = bc;  off = 192; }
        else              { b = bf_; off = 256; }
        ((float*)(ws + OFF_BENC))[j] = b[j - off];
    }
}

// 8 rows/block, 48 tokens (token = comp*8 + row), 512 threads = 8 waves (wave = row).
// r8 (validated) + 8-wave S6 (transposed out-proj, cross-wave LN partials in s_part).
__global__ __launch_bounds__(512, 4) void asmlp_mfma(
    const float* __restrict__ x,
    const float* __restrict__ pv, const float* __restrict__ pm,
    const float* __restrict__ pi_, const float* __restrict__ pb_,
    const float* __restrict__ pc_, const float* __restrict__ pf_,
    const float* __restrict__ bqkv, const float* __restrict__ bo,
    const float* __restrict__ gg, const float* __restrict__ beta,
    const float* __restrict__ bp,
    const u16* __restrict__ ws,
    float* __restrict__ out)
{
    const int blk  = blockIdx.x;
    const int t    = threadIdx.x;
    const int lane = t & 63;
    const int wv   = t >> 6;
    const int col  = lane & 15;
    const int lg   = lane >> 4;

    __shared__ __attribute__((aligned(16))) u16 sm[26624];   // 53248 B
    u16*   s_tok  = sm;                      // [48 tok][16 g][8] swz g^(tok&15)   12288 B
    u16*   s_qk   = sm + 6144;               // col-major [256 col][48 tok]        24576 B (dead after scores MFMA)
    u16*   s_vt   = sm + 18432;              // [16 g2][2 ch][16 nn][16 k=p*6+c2,pad12-15] 16384 B
    u16*   s_xa   = sm + 18432;              // [8 row][64 k] hi/lo (overlay vt)
    u16*   s_h    = sm + 18944;              // [8 row][48 g][8] (overlay vt)
    u16*   s_ctx  = sm + 6144;               // [48 tok][16 g][8] (overlay s_qk low half, after scores)
    u16*   s_pp   = sm + 12288;              // [8 wv][2 slot][16 k][16 m] 8192 B (overlay s_qk up half)
    float* s_part = (float*)(sm + 12288);    // [48 tok][8 wv][2] f32 3072 B (overlay s_pp; after PV)
    float* s_out  = (float*)(sm + 12288);    // [8][260] f32 (same region; after S6/S7)
    u16*   s_pool = sm + 18432;              // [8 row][16 g][8] (overlay vt; after PV)

    // ---- S0: stage x as hi/lo bf16 (exact fp32 split), granule-swizzled ----
    if (t < 232) {
        int row = t / 29, cc = t - row * 29;
        float f = x[(size_t)blk * 232 + t];
        u16 hi = f2bf(f);
        float lo = f - bf2f(hi);
        s_xa[row * 64 + (((cc >> 3) ^ (row & 3)) << 3) + (cc & 7)] = hi;
        int c2 = cc + 32;
        s_xa[row * 64 + (((c2 >> 3) ^ (row & 3)) << 3) + (c2 & 7)] = f2bf(lo);
    }
    if (t < 48) {
        int row = t / 6, sl = t - (t / 6) * 6;
        int k = (sl < 3) ? (29 + sl) : (58 + sl);   // 29..31, 61..63
        s_xa[row * 64 + (((k >> 3) ^ (row & 3)) << 3) + (k & 7)] = 0;
    }
    __syncthreads();

    // ---- S1: encoders, transposed MFMA: C[enc_col][row] ----
    {
        int row8 = col & 7;
        short8 B0 = *(const short8*)&s_xa[row8 * 64 + ((lg ^ (row8 & 3)) << 3)];
        short8 B1 = *(const short8*)&s_xa[row8 * 64 + (((4 + lg) ^ (row8 & 3)) << 3)];
        const float* benc = (const float*)(ws + OFF_BENC);
        #pragma unroll
        for (int q = 0; q < 3; ++q) {
            int nt = wv * 3 + q;
            f32x4 acc = *(const f32x4*)&benc[nt * 16 + lg * 4];
            short8 A0 = *(const short8*)&ws[OFF_WENC + (((nt * 2 + 0) * 64 + lane) << 3)];
            short8 A1 = *(const short8*)&ws[OFF_WENC + (((nt * 2 + 1) * 64 + lane) << 3)];
            acc = __builtin_amdgcn_mfma_f32_16x16x32_bf16(A0, B0, acc, 0, 0, 0);
            acc = __builtin_amdgcn_mfma_f32_16x16x32_bf16(A1, B1, acc, 0, 0, 0);
            if (col < 8) {
                int ge = nt * 2 + (lg >> 1);
                uint2 w;
                w.x = cvt_pk_bf16(fmaxf(acc[0], 0.f), fmaxf(acc[1], 0.f));
                w.y = cvt_pk_bf16(fmaxf(acc[2], 0.f), fmaxf(acc[3], 0.f));
                *(uint2*)&s_h[((col * 48 + (ge ^ col)) << 3) + (lg & 1) * 4] = w;
            }
        }
    }
    __syncthreads();

    // ---- S2: projections, transposed: C[proj_col][row] ----
    #pragma unroll
    for (int q = 0; q < 6; ++q) {
        int unit = wv * 6 + q;
        int c = unit >> 3, n = unit & 7;
        const float* bias; int ks, hg, wso;
        switch (c) {
            case 0:  bias = pv;  ks = 2; hg = 0;  wso = OFF_PV; break;
            case 1:  bias = pm;  ks = 2; hg = 8;  wso = OFF_PM; break;
            case 2:  bias = pi_; ks = 1; hg = 16; wso = OFF_PI; break;
            case 3:  bias = pb_; ks = 1; hg = 20; wso = OFF_PB; break;
            case 4:  bias = pc_; ks = 2; hg = 24; wso = OFF_PC; break;
            default: bias = pf_; ks = 4; hg = 32; wso = OFF_PF; break;
        }
        f32x4 acc = *(const f32x4*)&bias[n * 16 + lg * 4];
        int hrow = col & 7;
        for (int kk = 0; kk < ks; ++kk) {
            short8 A = *(const short8*)&ws[wso + (((n * ks + kk) * 64 + lane) << 3)];
            short8 B = *(const short8*)&s_h[(hrow * 48 + ((hg + kk * 4 + lg) ^ hrow)) << 3];
            acc = __builtin_amdgcn_mfma_f32_16x16x32_bf16(A, B, acc, 0, 0, 0);
        }
        if (col < 8) {
            int tok = c * 8 + col;
            int gt = n * 2 + (lg >> 1);
            uint2 w;
            w.x = cvt_pk_bf16(acc[0], acc[1]);
            w.y = cvt_pk_bf16(acc[2], acc[3]);
            *(uint2*)&s_tok[((tok * 16 + (gt ^ (tok & 15))) << 3) + (lg & 1) * 4] = w;
        }
    }
    __syncthreads();

    // ---- S3: QKV (MFMA). Q/K -> col-major s_qk (cvt_pk + b64); V -> s_vt ----
    {
        short8 Bf[3][4];
        float  bb_[3];
        #pragma unroll
        for (int ni = 0; ni < 3; ++ni) {
            int n = wv * 3 + ni;
            bb_[ni] = bqkv[n * 16 + col];
            #pragma unroll
            for (int kk = 0; kk < 4; ++kk)
                Bf[ni][kk] = *(const short8*)&ws[OFF_QKV + (((n * 4 + kk) * 64 + lane) << 3)];
        }
        // zero s_vt k-pad (k 12..15), one b64 per thread
        { uint2 z; z.x = 0u; z.y = 0u; *(uint2*)&s_vt[t * 16 + 12] = z; }
        for (int mt = 0; mt < 3; ++mt) {
            short8 A[4];
            int arow = mt * 16 + col;
            #pragma unroll
            for (int kk = 0; kk < 4; ++kk) {
                int g = kk * 4 + lg;
                A[kk] = *(const short8*)&s_tok[(arow * 16 + (g ^ (arow & 15))) << 3];
            }
            #pragma unroll
            for (int ni = 0; ni < 3; ++ni) {
                f32x4 acc = {bb_[ni], bb_[ni], bb_[ni], bb_[ni]};
                #pragma unroll
                for (int kk = 0; kk < 4; ++kk)
                    acc = __builtin_amdgcn_mfma_f32_16x16x32_bf16(A[kk], Bf[ni][kk], acc, 0, 0, 0);
                int cn = wv * 3 + ni;
                int cg = cn * 16 + col;                 // global qkv column
                if (cn < 16) {
                    // Q/K: col-major, token index XOR-swizzled by ((cg>>3)&3)<<2
                    int q4 = ((cg >> 3) & 3) << 2;
                    int tb = (mt * 16 + lg * 4) ^ q4;
                    uint2 w;
                    w.x = cvt_pk_bf16(acc[0], acc[1]);
                    w.y = cvt_pk_bf16(acc[2], acc[3]);
                    *(uint2*)&s_qk[cg * 48 + tb] = w;
                } else {
                    int d = cg - 256;
                    int h = d >> 5, ch = (d >> 4) & 1, nn = d & 15;
                    #pragma unroll
                    for (int r = 0; r < 4; ++r) {
                        int token = mt * 16 + lg * 4 + r;
                        int c2 = token >> 3, rb = token & 7;
                        int g2 = rb * 2 + (h >> 1);
                        int kidx = (h & 1) * 6 + c2;
                        s_vt[((g2 * 2 + ch) * 16 + nn) * 16 + kidx] = f2bf(acc[r]);
                    }
                }
            }
        }
    }
    __syncthreads();

    // ---- SCORES phase 1: MFMAs only (last readers of s_qk) ----
    f32x4 scf[2];
    {
        const int rb = wv;
        #pragma unroll
        for (int i = 0; i < 2; ++i) {
            const int hp = i;
            int p  = (col >= 6 && col < 12) ? 1 : 0;
            int qi = (col < 6) ? col : ((col < 12) ? col - 6 : 0);
            int tt = qi * 8 + rb;
            int h  = hp * 2 + p;
            int tsw = tt ^ (lg << 2);
            int abase = (h * 32 + lg * 8) * 48 + tsw;          // Q cols 0..127
            int bbase = (128 + h * 32 + lg * 8) * 48 + tsw;    // K cols 128..255
            short8 Aq, Bk;
            #pragma unroll
            for (int j = 0; j < 8; ++j) {
                Aq[j] = (short)s_qk[abase + j * 48];
                Bk[j] = (short)s_qk[bbase + j * 48];
            }
            f32x4 sc = {0.f, 0.f, 0.f, 0.f};
            scf[i] = __builtin_amdgcn_mfma_f32_16x16x32_bf16(Aq, Bk, sc, 0, 0, 0);
        }
    }
    __syncthreads();   // s_qk now dead -> its space becomes s_ctx + s_pp

    // ---- SCORES phase 2: softmax in C-regs -> s_pp (overlay) ----
    {
        #pragma unroll
        for (int i = 0; i < 2; ++i) {
            u16* pp = s_pp + (wv * 2 + i) * 256;
            f32x4 pr4;
            #pragma unroll
            for (int r = 0; r < 4; ++r) {
                int mr = lg * 4 + r;
                int prr = (mr >= 6 && mr < 12) ? 1 : 0;
                float v = scf[i][r] * 0.17677669529663687f;   // 1/sqrt(32)
                bool inR = (col >= 6 * prr) && (col < 6 * prr + 6);
                float mv = inR ? v : -1e30f;
                #pragma unroll
                for (int off = 1; off < 16; off <<= 1)
                    mv = fmaxf(mv, __shfl_xor(mv, off, 16));
                float e = inR ? __expf(v - mv) : 0.f;
                float s = e;
                #pragma unroll
                for (int off = 1; off < 16; off <<= 1)
                    s += __shfl_xor(s, off, 16);
                pr4[r] = (mr < 12) ? (e / s) : 0.f;
            }
            uint2 w;
            w.x = cvt_pk_bf16(pr4[0], pr4[1]);
            w.y = cvt_pk_bf16(pr4[2], pr4[3]);
            *(uint2*)&pp[col * 16 + lg * 4] = w;   // Ppad[k=col][m quad]
        }
    }
    __syncthreads();

    // ---- PV: ctx = P @ V via MFMA (A from s_pp block-diag, B b128 from s_vt) ----
    {
        const int rb = wv;
        #pragma unroll
        for (int i = 0; i < 2; ++i) {
            const int hp = i;
            u16* pp = s_pp + (wv * 2 + i) * 256;
            short8 Ap;
            if (lg < 2) {
                #pragma unroll
                for (int j = 0; j < 8; ++j)
                    Ap[j] = (short)pp[(lg * 8 + j) * 16 + col];
            } else {
                #pragma unroll
                for (int j = 0; j < 8; ++j) Ap[j] = 0;
            }
            int g2 = rb * 2 + hp;
            #pragma unroll
            for (int ch = 0; ch < 2; ++ch) {
                short8 Bv = *(const short8*)&s_vt[(((g2 * 2 + ch) * 16 + col) * 16) + ((lg & 1) * 8)];
                f32x4 c = {0.f, 0.f, 0.f, 0.f};
                c = __builtin_amdgcn_mfma_f32_16x16x32_bf16(Ap, Bv, c, 0, 0, 0);
                #pragma unroll
                for (int r = 0; r < 4; ++r) {
                    int mr = lg * 4 + r;
                    if (mr < 12) {
                        int pq = mr >= 6 ? 1 : 0;
                        int qi = mr - 6 * pq;
                        int token = qi * 8 + rb;
                        int d = (hp * 2 + pq) * 32 + ch * 16 + col;
                        s_ctx[((token * 16 + ((d >> 3) ^ (token & 15))) << 3) + (d & 7)] = f2bf(c[r]);
                    }
                }
            }
        }
    }
    __syncthreads();   // s_pp dead -> region becomes s_part

    // ---- S6 (8-wave): out-proj transposed + residual + LN w/ cross-wave partials ----
    {
        const int mo = wv;                     // this wave's 16 output cols
        short8 Afr[4];
        #pragma unroll
        for (int kk = 0; kk < 4; ++kk)
            Afr[kk] = *(const short8*)&ws[OFF_WO + (((mo * 4 + kk) * 64 + lane) << 3)];
        f32x4 biasv = *(const f32x4*)&bo[mo * 16 + lg * 4];
        f32x4 accs[3];
        #pragma unroll
        for (int tt = 0; tt < 3; ++tt) {
            int tokr = tt * 16 + col;
            f32x4 acc = biasv;
            #pragma unroll
            for (int kk = 0; kk < 4; ++kk) {
                short8 Bf = *(const short8*)&s_ctx[(tokr * 16 + ((kk * 4 + lg) ^ (tokr & 15))) << 3];
                acc = __builtin_amdgcn_mfma_f32_16x16x32_bf16(Afr[kk], Bf, acc, 0, 0, 0);
            }
            const u16* rp = &s_tok[((tokr * 16 + ((mo * 2 + (lg >> 1)) ^ (tokr & 15))) << 3) + (lg & 1) * 4];
            #pragma unroll
            for (int r = 0; r < 4; ++r) acc[r] += bf2f(rp[r]);
            accs[tt] = acc;
            float s1 = acc[0] + acc[1] + acc[2] + acc[3];
            float s2 = acc[0]*acc[0] + acc[1]*acc[1] + acc[2]*acc[2] + acc[3]*acc[3];
            s1 += __shfl_xor(s1, 16, 64); s1 += __shfl_xor(s1, 32, 64);
            s2 += __shfl_xor(s2, 16, 64); s2 += __shfl_xor(s2, 32, 64);
            if (lg == 0) {
                float2 pw; pw.x = s1; pw.y = s2;
                *(float2*)&s_part[(tokr * 8 + wv) * 2] = pw;
            }
        }
        __syncthreads();
        f32x4 gv = *(const f32x4*)&gg[mo * 16 + lg * 4];
        f32x4 bv = *(const f32x4*)&beta[mo * 16 + lg * 4];
        #pragma unroll
        for (int tt = 0; tt < 3; ++tt) {
            int tokr = tt * 16 + col;
            const float* pr = &s_part[tokr * 16];
            f32x4 p0 = *(const f32x4*)pr;
            f32x4 p1 = *(const f32x4*)(pr + 4);
            f32x4 p2 = *(const f32x4*)(pr + 8);
            f32x4 p3 = *(const f32x4*)(pr + 12);
            float S1 = p0[0]+p0[2]+p1[0]+p1[2]+p2[0]+p2[2]+p3[0]+p3[2];
            float S2 = p0[1]+p0[3]+p1[1]+p1[3]+p2[1]+p2[3]+p3[1]+p3[3];
            float mu = S1 * (1.f / 128.f);
            float var = S2 * (1.f / 128.f) - mu * mu;
            float rs = rsqrtf(var + LN_EPS);
            f32x4 a = accs[tt];
            uint2 w;
            w.x = cvt_pk_bf16((a[0]-mu)*rs*gv[0]+bv[0], (a[1]-mu)*rs*gv[1]+bv[1]);
            w.y = cvt_pk_bf16((a[2]-mu)*rs*gv[2]+bv[2], (a[3]-mu)*rs*gv[3]+bv[3]);
            *(uint2*)&s_tok[((tokr * 16 + ((mo * 2 + (lg >> 1)) ^ (tokr & 15))) << 3) + (lg & 1) * 4] = w;
        }
    }
    __syncthreads();

    // ---- S7: mean-pool over 6 tokens ----
    if (t < 128) {
        int row = t >> 4, gch = t & 15;
        float fa[8] = {0, 0, 0, 0, 0, 0, 0, 0};
        #pragma unroll
        for (int c = 0; c < 6; ++c) {
            int tok = c * 8 + row;
            short8 v = *(const short8*)&s_tok[(tok * 16 + (gch ^ (tok & 15))) << 3];
            #pragma unroll
            for (int j = 0; j < 8; ++j) fa[j] += bf2f((u16)v[j]);
        }
        short8 o;
        #pragma unroll
        for (int j = 0; j < 8; ++j) o[j] = (short)f2bf(fa[j] * (1.f / 6.f));
        *(short8*)&s_pool[(row * 16 + (gch ^ row)) << 3] = o;
    }
    __syncthreads();

    // ---- S8: pooled @ Wp + bp, ReLU ----
    {
        int arow = col & 7;
        short8 A[4];
        #pragma unroll
        for (int kk = 0; kk < 4; ++kk) {
            int g = kk * 4 + lg;
            A[kk] = *(const short8*)&s_pool[(arow * 16 + (g ^ arow)) << 3];
        }
        #pragma unroll
        for (int ni = 0; ni < 2; ++ni) {
            int n = wv * 2 + ni;
            float b = bp[n * 16 + col];
            f32x4 acc = {b, b, b, b};
            #pragma unroll
            for (int kk = 0; kk < 4; ++kk) {
                short8 Bf = *(const short8*)&ws[OFF_WP + (((n * 4 + kk) * 64 + lane) << 3)];
                acc = __builtin_amdgcn_mfma_f32_16x16x32_bf16(A[kk], Bf, acc, 0, 0, 0);
            }
            if (lg < 2) {
                #pragma unroll
                for (int r = 0; r < 4; ++r) {
                    int row = lg * 4 + r;
                    s_out[row * 260 + n * 16 + col] = fmaxf(acc[r], 0.f);
                }
            }
        }
    }
    __syncthreads();

    // ---- S9: coalesced store ----
    if (t < 256) {
        int row = t >> 5, c8 = (t & 31) * 8;
        f32x4 v0 = *(const f32x4*)&s_out[row * 260 + c8];
        f32x4 v1 = *(const f32x4*)&s_out[row * 260 + c8 + 4];
        float* dst = out + ((size_t)blk * 8 + row) * 256 + c8;
        *(f32x4*)dst = v0;
        *(f32x4*)(dst + 4) = v1;
    }
}

extern "C" void kernel_launch(void* const* d_in, const int* in_sizes, int n_in,
                              void* d_out, int out_size, void* d_ws, size_t ws_size,
                              hipStream_t stream) {
    const float* x    = (const float*)d_in[0];
    const float* Wv   = (const float*)d_in[1];
    const float* bv   = (const float*)d_in[2];
    const float* Wm   = (const float*)d_in[3];
    const float* bm   = (const float*)d_in[4];
    const float* Wi   = (const float*)d_in[5];
    const float* bi   = (const float*)d_in[6];
    const float* Wb   = (const float*)d_in[7];
    const float* bb   = (const float*)d_in[8];
    const float* Wc   = (const float*)d_in[9];
    const float* bc   = (const float*)d_in[10];
    const float* Wf   = (const float*)d_in[11];
    const float* bf_  = (const float*)d_in[12];
    const float* Pv   = (const float*)d_in[13];
    const float* pv   = (const float*)d_in[14];
    const float* Pm   = (const float*)d_in[15];
    const float* pm   = (const float*)d_in[16];
    const float* Pi   = (const float*)d_in[17];
    const float* pii  = (const float*)d_in[18];
    const float* Pb   = (const float*)d_in[19];
    const float* pb   = (const float*)d_in[20];
    const float* Pc   = (const float*)d_in[21];
    const float* pc   = (const float*)d_in[22];
    const float* Pf   = (const float*)d_in[23];
    const float* pf   = (const float*)d_in[24];
    const float* Wqkv = (const float*)d_in[25];
    const float* bqkv = (const float*)d_in[26];
    const float* Wo   = (const float*)d_in[27];
    const float* bo   = (const float*)d_in[28];
    const float* gg   = (const float*)d_in[29];
    const float* beta = (const float*)d_in[30];
    const float* Wp   = (const float*)d_in[31];
    const float* bp   = (const float*)d_in[32];
    float* out = (float*)d_out;
    u16* ws = (u16*)d_ws;

    convert_weights<<<(CW_TOTAL + 511) / 512, 512, 0, stream>>>(
        Wqkv, Wo, Wp, Pv, Pm, Pi, Pb, Pc, Pf,
        Wv, Wm, Wi, Wb, Wc, Wf, bv, bm, bi, bb, bc, bf_, ws);

    const int Bn = in_sizes[0] / 29;       // 65536
    asmlp_mfma<<<Bn / 8, 512, 0, stream>>>(
        x, pv, pm, pii, pb, pc, pf,
        bqkv, bo, gg, beta, bp, ws, out);
}

// Round 11
// 286.744 us; speedup vs baseline: 6.1864x; 1.0044x over previous
//
#include <hip/hip_runtime.h>
#include <math.h>

typedef float f32x4 __attribute__((ext_vector_type(4)));
typedef short short8 __attribute__((ext_vector_type(8)));
typedef unsigned short u16;

#define LN_EPS 1e-5f

static __device__ __forceinline__ unsigned cvt_pk_bf16(float lo, float hi) {
    unsigned r;
    asm("v_cvt_pk_bf16_f32 %0, %1, %2" : "=v"(r) : "v"(lo), "v"(hi));
    return r;
}
static __device__ __forceinline__ u16 f2bf(float f) { return (u16)cvt_pk_bf16(f, f); }
static __device__ __forceinline__ float bf2f(u16 u) {
    return __uint_as_float(((unsigned)u) << 16);
}

// ws segment offsets (u16 elements). Fragment-linear layout (works as A- or B-operand):
// idx = ((ntile*Ksteps + kk)*64 + lane)*8 + j -> W[kk*32+(lane>>4)*8+j][ntile*16+(lane&15)]
#define OFF_QKV 0
#define OFF_WO  49152
#define OFF_WP  65536
#define OFF_PV  98304
#define OFF_PM  106496
#define OFF_PI  114688
#define OFF_PB  118784
#define OFF_PC  122880
#define OFF_PF  131072
#define OFF_WENC 147456     // block-diag encoder weight, hi/lo stacked: 24 ntiles x 2 ksteps
#define OFF_BENC 172032     // f32 region (384 floats) starts at this u16 index
#define CW_TOTAL 172416

__global__ __launch_bounds__(512) void convert_weights(
    const float* __restrict__ Wqkv, const float* __restrict__ Wo, const float* __restrict__ Wp,
    const float* __restrict__ Pv, const float* __restrict__ Pm, const float* __restrict__ Pi,
    const float* __restrict__ Pb, const float* __restrict__ Pc, const float* __restrict__ Pf,
    const float* __restrict__ Wv, const float* __restrict__ Wm, const float* __restrict__ Wi,
    const float* __restrict__ Wb, const float* __restrict__ Wc, const float* __restrict__ Wf,
    const float* __restrict__ bv, const float* __restrict__ bm, const float* __restrict__ bi,
    const float* __restrict__ bb, const float* __restrict__ bc, const float* __restrict__ bf_,
    u16* __restrict__ ws)
{
    int gid = blockIdx.x * 512 + threadIdx.x;
    if (gid < OFF_WENC) {
        const float* src; int N, Ksteps, local;
        if (gid < OFF_WO)      { src = Wqkv; N = 384; Ksteps = 4; local = gid; }
        else if (gid < OFF_WP) { src = Wo;   N = 128; Ksteps = 4; local = gid - OFF_WO; }
        else if (gid < OFF_PV) { src = Wp;   N = 256; Ksteps = 4; local = gid - OFF_WP; }
        else if (gid < OFF_PM) { src = Pv;   N = 128; Ksteps = 2; local = gid - OFF_PV; }
        else if (gid < OFF_PI) { src = Pm;   N = 128; Ksteps = 2; local = gid - OFF_PM; }
        else if (gid < OFF_PB) { src = Pi;   N = 128; Ksteps = 1; local = gid - OFF_PI; }
        else if (gid < OFF_PC) { src = Pb;   N = 128; Ksteps = 1; local = gid - OFF_PB; }
        else if (gid < OFF_PF) { src = Pc;   N = 128; Ksteps = 2; local = gid - OFF_PC; }
        else                   { src = Pf;   N = 128; Ksteps = 4; local = gid - OFF_PF; }
        int j  = local & 7;
        int l  = (local >> 3) & 63;
        int r2 = local >> 9;
        int kk = r2 % Ksteps;
        int nt = r2 / Ksteps;
        int srow = kk * 32 + (l >> 4) * 8 + j;
        int scol = nt * 16 + (l & 15);
        ws[gid] = f2bf(src[srow * N + scol]);
    } else if (gid < OFF_BENC) {
        int local = gid - OFF_WENC;
        int j = local & 7, l = (local >> 3) & 63, r2 = local >> 9;
        int kk = r2 & 1, nt = r2 >> 1;
        int k = kk * 32 + (l >> 4) * 8 + j;
        int r = k & 31;                    // x input dim (0..31, valid <29)
        int scol = nt * 16 + (l & 15);     // 0..383
        const float* W; int cb, xo, din, dout;
        if (scol < 64)       { W = Wv; cb = 0;   xo = 0;  din = 3;  dout = 64; }
        else if (scol < 128) { W = Wm; cb = 64;  xo = 3;  din = 5;  dout = 64; }
        else if (scol < 160) { W = Wi; cb = 128; xo = 8;  din = 2;  dout = 32; }
        else if (scol < 192) { W = Wb; cb = 160; xo = 10; din = 3;  dout = 32; }
        else if (scol < 256) { W = Wc; cb = 192; xo = 13; din = 6;  dout = 64; }
        else                 { W = Wf; cb = 256; xo = 19; din = 10; dout = 128; }
        int rr = r - xo;
        float val = (r < 29 && rr >= 0 && rr < din) ? W[rr * dout + (scol - cb)] : 0.f;
        ws[gid] = f2bf(val);
    } else if (gid < CW_TOTAL) {
        int j = gid - OFF_BENC;
        const float* b; int off;
        if (j < 64)       { b = bv;  off = 0; }
        else if (j < 128) { b = bm;  off = 64; }
        else if (j < 160) { b = bi;  off = 128; }
        else if (j < 192) { b = bb;  off = 160; }
        else if (j < 256) { b = bc;  off = 192; }
        else              { b = bf_; off = 256; }
        ((float*)(ws + OFF_BENC))[j] = b[j - off];
    }
}

// 8 rows/block, 48 tokens (token = comp*8 + row), 512 threads = 8 waves (wave = row).
// r10 (validated) with LDS cut 53248 -> 49152 B via s_vt k-dim 16 -> 12 (no pads;
// PV upper-half spill slots multiply pp rows 12..15 which are exact zeros).
__global__ __launch_bounds__(512, 4) void asmlp_mfma(
    const float* __restrict__ x,
    const float* __restrict__ pv, const float* __restrict__ pm,
    const float* __restrict__ pi_, const float* __restrict__ pb_,
    const float* __restrict__ pc_, const float* __restrict__ pf_,
    const float* __restrict__ bqkv, const float* __restrict__ bo,
    const float* __restrict__ gg, const float* __restrict__ beta,
    const float* __restrict__ bp,
    const u16* __restrict__ ws,
    float* __restrict__ out)
{
    const int blk  = blockIdx.x;
    const int t    = threadIdx.x;
    const int lane = t & 63;
    const int wv   = t >> 6;
    const int col  = lane & 15;
    const int lg   = lane >> 4;

    __shared__ __attribute__((aligned(16))) u16 sm[24576];   // 49152 B
    u16*   s_tok  = sm;                      // [48 tok][16 g][8] swz g^(tok&15)      12288 B
    u16*   s_vt   = sm + 6144;               // [16 g2][2 ch][16 nn][12 k=p*6+c2]     12288 B
    u16*   s_qk   = sm + 12288;              // col-major [256 col][48 tok]           24576 B
    u16*   s_xa   = sm + 12288;              // [8 row][64 k] hi/lo (overlay qk, S0-S2)
    u16*   s_h    = sm + 12800;              // [8 row][48 g][8] (overlay qk, S1-S2)
    u16*   s_ctx  = sm + 12288;              // [48 tok][16 g][8] (overlay qk, after scores)
    u16*   s_pp   = sm + 18432;              // [8 wv][2 slot][16 k][16 m] (overlay qk upper)
    float* s_part = (float*)(sm + 18432);    // [48 tok][8 wv][2] f32 (overlay pp; S6)
    u16*   s_pool = sm + 6144;               // [8 row][16 g][8] (overlay vt; S7+)
    float* s_out  = (float*)(sm + 7168);     // [8][260] f32 (overlay vt; S8+)

    // ---- S0: stage x as hi/lo bf16 (exact fp32 split), granule-swizzled ----
    if (t < 232) {
        int row = t / 29, cc = t - row * 29;
        float f = x[(size_t)blk * 232 + t];
        u16 hi = f2bf(f);
        float lo = f - bf2f(hi);
        s_xa[row * 64 + (((cc >> 3) ^ (row & 3)) << 3) + (cc & 7)] = hi;
        int c2 = cc + 32;
        s_xa[row * 64 + (((c2 >> 3) ^ (row & 3)) << 3) + (c2 & 7)] = f2bf(lo);
    }
    if (t < 48) {
        int row = t / 6, sl = t - (t / 6) * 6;
        int k = (sl < 3) ? (29 + sl) : (58 + sl);   // 29..31, 61..63
        s_xa[row * 64 + (((k >> 3) ^ (row & 3)) << 3) + (k & 7)] = 0;
    }
    __syncthreads();

    // ---- S1: encoders, transposed MFMA: C[enc_col][row] ----
    {
        int row8 = col & 7;
        short8 B0 = *(const short8*)&s_xa[row8 * 64 + ((lg ^ (row8 & 3)) << 3)];
        short8 B1 = *(const short8*)&s_xa[row8 * 64 + (((4 + lg) ^ (row8 & 3)) << 3)];
        const float* benc = (const float*)(ws + OFF_BENC);
        #pragma unroll
        for (int q = 0; q < 3; ++q) {
            int nt = wv * 3 + q;
            f32x4 acc = *(const f32x4*)&benc[nt * 16 + lg * 4];
            short8 A0 = *(const short8*)&ws[OFF_WENC + (((nt * 2 + 0) * 64 + lane) << 3)];
            short8 A1 = *(const short8*)&ws[OFF_WENC + (((nt * 2 + 1) * 64 + lane) << 3)];
            acc = __builtin_amdgcn_mfma_f32_16x16x32_bf16(A0, B0, acc, 0, 0, 0);
            acc = __builtin_amdgcn_mfma_f32_16x16x32_bf16(A1, B1, acc, 0, 0, 0);
            if (col < 8) {
                int ge = nt * 2 + (lg >> 1);
                uint2 w;
                w.x = cvt_pk_bf16(fmaxf(acc[0], 0.f), fmaxf(acc[1], 0.f));
                w.y = cvt_pk_bf16(fmaxf(acc[2], 0.f), fmaxf(acc[3], 0.f));
                *(uint2*)&s_h[((col * 48 + (ge ^ col)) << 3) + (lg & 1) * 4] = w;
            }
        }
    }
    __syncthreads();

    // ---- S2: projections, transposed: C[proj_col][row] ----
    #pragma unroll
    for (int q = 0; q < 6; ++q) {
        int unit = wv * 6 + q;
        int c = unit >> 3, n = unit & 7;
        const float* bias; int ks, hg, wso;
        switch (c) {
            case 0:  bias = pv;  ks = 2; hg = 0;  wso = OFF_PV; break;
            case 1:  bias = pm;  ks = 2; hg = 8;  wso = OFF_PM; break;
            case 2:  bias = pi_; ks = 1; hg = 16; wso = OFF_PI; break;
            case 3:  bias = pb_; ks = 1; hg = 20; wso = OFF_PB; break;
            case 4:  bias = pc_; ks = 2; hg = 24; wso = OFF_PC; break;
            default: bias = pf_; ks = 4; hg = 32; wso = OFF_PF; break;
        }
        f32x4 acc = *(const f32x4*)&bias[n * 16 + lg * 4];
        int hrow = col & 7;
        for (int kk = 0; kk < ks; ++kk) {
            short8 A = *(const short8*)&ws[wso + (((n * ks + kk) * 64 + lane) << 3)];
            short8 B = *(const short8*)&s_h[(hrow * 48 + ((hg + kk * 4 + lg) ^ hrow)) << 3];
            acc = __builtin_amdgcn_mfma_f32_16x16x32_bf16(A, B, acc, 0, 0, 0);
        }
        if (col < 8) {
            int tok = c * 8 + col;
            int gt = n * 2 + (lg >> 1);
            uint2 w;
            w.x = cvt_pk_bf16(acc[0], acc[1]);
            w.y = cvt_pk_bf16(acc[2], acc[3]);
            *(uint2*)&s_tok[((tok * 16 + (gt ^ (tok & 15))) << 3) + (lg & 1) * 4] = w;
        }
    }
    __syncthreads();

    // ---- S3: QKV (MFMA). Q/K -> col-major s_qk (cvt_pk + b64); V -> s_vt [*12] ----
    {
        short8 Bf[3][4];
        float  bb_[3];
        #pragma unroll
        for (int ni = 0; ni < 3; ++ni) {
            int n = wv * 3 + ni;
            bb_[ni] = bqkv[n * 16 + col];
            #pragma unroll
            for (int kk = 0; kk < 4; ++kk)
                Bf[ni][kk] = *(const short8*)&ws[OFF_QKV + (((n * 4 + kk) * 64 + lane) << 3)];
        }
        for (int mt = 0; mt < 3; ++mt) {
            short8 A[4];
            int arow = mt * 16 + col;
            #pragma unroll
            for (int kk = 0; kk < 4; ++kk) {
                int g = kk * 4 + lg;
                A[kk] = *(const short8*)&s_tok[(arow * 16 + (g ^ (arow & 15))) << 3];
            }
            #pragma unroll
            for (int ni = 0; ni < 3; ++ni) {
                f32x4 acc = {bb_[ni], bb_[ni], bb_[ni], bb_[ni]};
                #pragma unroll
                for (int kk = 0; kk < 4; ++kk)
                    acc = __builtin_amdgcn_mfma_f32_16x16x32_bf16(A[kk], Bf[ni][kk], acc, 0, 0, 0);
                int cn = wv * 3 + ni;
                int cg = cn * 16 + col;                 // global qkv column
                if (cn < 16) {
                    // Q/K: col-major, token index XOR-swizzled by ((cg>>3)&3)<<2
                    int q4 = ((cg >> 3) & 3) << 2;
                    int tb = (mt * 16 + lg * 4) ^ q4;
                    uint2 w;
                    w.x = cvt_pk_bf16(acc[0], acc[1]);
                    w.y = cvt_pk_bf16(acc[2], acc[3]);
                    *(uint2*)&s_qk[cg * 48 + tb] = w;
                } else {
                    int d = cg - 256;
                    int h = d >> 5, ch = (d >> 4) & 1, nn = d & 15;
                    #pragma unroll
                    for (int r = 0; r < 4; ++r) {
                        int token = mt * 16 + lg * 4 + r;
                        int c2 = token >> 3, rb = token & 7;
                        int g2 = rb * 2 + (h >> 1);
                        int kidx = (h & 1) * 6 + c2;
                        s_vt[((g2 * 2 + ch) * 16 + nn) * 12 + kidx] = f2bf(acc[r]);
                    }
                }
            }
        }
    }
    __syncthreads();

    // ---- SCORES phase 1: MFMAs only (last readers of s_qk) ----
    f32x4 scf[2];
    {
        const int rb = wv;
        #pragma unroll
        for (int i = 0; i < 2; ++i) {
            const int hp = i;
            int p  = (col >= 6 && col < 12) ? 1 : 0;
            int qi = (col < 6) ? col : ((col < 12) ? col - 6 : 0);
            int tt = qi * 8 + rb;
            int h  = hp * 2 + p;
            int tsw = tt ^ (lg << 2);
            int abase = (h * 32 + lg * 8) * 48 + tsw;          // Q cols 0..127
            int bbase = (128 + h * 32 + lg * 8) * 48 + tsw;    // K cols 128..255
            short8 Aq, Bk;
            #pragma unroll
            for (int j = 0; j < 8; ++j) {
                Aq[j] = (short)s_qk[abase + j * 48];
                Bk[j] = (short)s_qk[bbase + j * 48];
            }
            f32x4 sc = {0.f, 0.f, 0.f, 0.f};
            scf[i] = __builtin_amdgcn_mfma_f32_16x16x32_bf16(Aq, Bk, sc, 0, 0, 0);
        }
    }
    __syncthreads();   // s_qk now dead -> its space becomes s_ctx + s_pp

    // ---- SCORES phase 2: softmax in C-regs -> s_pp (overlay) ----
    {
        #pragma unroll
        for (int i = 0; i < 2; ++i) {
            u16* pp = s_pp + (wv * 2 + i) * 256;
            f32x4 pr4;
            #pragma unroll
            for (int r = 0; r < 4; ++r) {
                int mr = lg * 4 + r;
                int prr = (mr >= 6 && mr < 12) ? 1 : 0;
                float v = scf[i][r] * 0.17677669529663687f;   // 1/sqrt(32)
                bool inR = (col >= 6 * prr) && (col < 6 * prr + 6);
                float mv = inR ? v : -1e30f;
                #pragma unroll
                for (int off = 1; off < 16; off <<= 1)
                    mv = fmaxf(mv, __shfl_xor(mv, off, 16));
                float e = inR ? __expf(v - mv) : 0.f;
                float s = e;
                #pragma unroll
                for (int off = 1; off < 16; off <<= 1)
                    s += __shfl_xor(s, off, 16);
                pr4[r] = (mr < 12) ? (e / s) : 0.f;
            }
            uint2 w;
            w.x = cvt_pk_bf16(pr4[0], pr4[1]);
            w.y = cvt_pk_bf16(pr4[2], pr4[3]);
            *(uint2*)&pp[col * 16 + lg * 4] = w;   // Ppad[k=col][m quad]
        }
    }
    __syncthreads();

    // ---- PV: ctx = P @ V via MFMA (A from s_pp block-diag, B 2x b64 from s_vt) ----
    {
        const int rb = wv;
        #pragma unroll
        for (int i = 0; i < 2; ++i) {
            const int hp = i;
            u16* pp = s_pp + (wv * 2 + i) * 256;
            short8 Ap;
            if (lg < 2) {
                #pragma unroll
                for (int j = 0; j < 8; ++j)
                    Ap[j] = (short)pp[(lg * 8 + j) * 16 + col];
            } else {
                #pragma unroll
                for (int j = 0; j < 8; ++j) Ap[j] = 0;
            }
            int g2 = rb * 2 + hp;
            #pragma unroll
            for (int ch = 0; ch < 2; ++ch) {
                // 12-wide rows: two 8B-aligned b64 reads; upper half's last 4 slots
                // (k=12..15) read the next row / region (finite) x pp rows 12..15 == 0.
                int vbase = ((g2 * 2 + ch) * 16 + col) * 12 + ((lg & 1) * 8);
                uint2 vlo = *(const uint2*)&s_vt[vbase];
                uint2 vhi = *(const uint2*)&s_vt[vbase + 4];
                union { uint4 u; short8 s; } cvu;
                cvu.u.x = vlo.x; cvu.u.y = vlo.y; cvu.u.z = vhi.x; cvu.u.w = vhi.y;
                short8 Bv = cvu.s;
                f32x4 c = {0.f, 0.f, 0.f, 0.f};
                c = __builtin_amdgcn_mfma_f32_16x16x32_bf16(Ap, Bv, c, 0, 0, 0);
                #pragma unroll
                for (int r = 0; r < 4; ++r) {
                    int mr = lg * 4 + r;
                    if (mr < 12) {
                        int pq = mr >= 6 ? 1 : 0;
                        int qi = mr - 6 * pq;
                        int token = qi * 8 + rb;
                        int d = (hp * 2 + pq) * 32 + ch * 16 + col;
                        s_ctx[((token * 16 + ((d >> 3) ^ (token & 15))) << 3) + (d & 7)] = f2bf(c[r]);
                    }
                }
            }
        }
    }
    __syncthreads();   // s_pp dead -> region becomes s_part

    // ---- S6 (8-wave): out-proj transposed + residual + LN w/ cross-wave partials ----
    {
        const int mo = wv;                     // this wave's 16 output cols
        short8 Afr[4];
        #pragma unroll
        for (int kk = 0; kk < 4; ++kk)
            Afr[kk] = *(const short8*)&ws[OFF_WO + (((mo * 4 + kk) * 64 + lane) << 3)];
        f32x4 biasv = *(const f32x4*)&bo[mo * 16 + lg * 4];
        f32x4 accs[3];
        #pragma unroll
        for (int tt = 0; tt < 3; ++tt) {
            int tokr = tt * 16 + col;
            f32x4 acc = biasv;
            #pragma unroll
            for (int kk = 0; kk < 4; ++kk) {
                short8 Bf = *(const short8*)&s_ctx[(tokr * 16 + ((kk * 4 + lg) ^ (tokr & 15))) << 3];
                acc = __builtin_amdgcn_mfma_f32_16x16x32_bf16(Afr[kk], Bf, acc, 0, 0, 0);
            }
            const u16* rp = &s_tok[((tokr * 16 + ((mo * 2 + (lg >> 1)) ^ (tokr & 15))) << 3) + (lg & 1) * 4];
            #pragma unroll
            for (int r = 0; r < 4; ++r) acc[r] += bf2f(rp[r]);
            accs[tt] = acc;
            float s1 = acc[0] + acc[1] + acc[2] + acc[3];
            float s2 = acc[0]*acc[0] + acc[1]*acc[1] + acc[2]*acc[2] + acc[3]*acc[3];
            s1 += __shfl_xor(s1, 16, 64); s1 += __shfl_xor(s1, 32, 64);
            s2 += __shfl_xor(s2, 16, 64); s2 += __shfl_xor(s2, 32, 64);
            if (lg == 0) {
                float2 pw; pw.x = s1; pw.y = s2;
                *(float2*)&s_part[(tokr * 8 + wv) * 2] = pw;
            }
        }
        __syncthreads();
        f32x4 gv = *(const f32x4*)&gg[mo * 16 + lg * 4];
        f32x4 bv = *(const f32x4*)&beta[mo * 16 + lg * 4];
        #pragma unroll
        for (int tt = 0; tt < 3; ++tt) {
            int tokr = tt * 16 + col;
            const float* pr = &s_part[tokr * 16];
            f32x4 p0 = *(const f32x4*)pr;
            f32x4 p1 = *(const f32x4*)(pr + 4);
            f32x4 p2 = *(const f32x4*)(pr + 8);
            f32x4 p3 = *(const f32x4*)(pr + 12);
            float S1 = p0[0]+p0[2]+p1[0]+p1[2]+p2[0]+p2[2]+p3[0]+p3[2];
            float S2 = p0[1]+p0[3]+p1[1]+p1[3]+p2[1]+p2[3]+p3[1]+p3[3];
            float mu = S1 * (1.f / 128.f);
            float var = S2 * (1.f / 128.f) - mu * mu;
            float rs = rsqrtf(var + LN_EPS);
            f32x4 a = accs[tt];
            uint2 w;
            w.x = cvt_pk_bf16((a[0]-mu)*rs*gv[0]+bv[0], (a[1]-mu)*rs*gv[1]+bv[1]);
            w.y = cvt_pk_bf16((a[2]-mu)*rs*gv[2]+bv[2], (a[3]-mu)*rs*gv[3]+bv[3]);
            *(uint2*)&s_tok[((tokr * 16 + ((mo * 2 + (lg >> 1)) ^ (tokr & 15))) << 3) + (lg & 1) * 4] = w;
        }
    }
    __syncthreads();

    // ---- S7: mean-pool over 6 tokens ----
    if (t < 128) {
        int row = t >> 4, gch = t & 15;
        float fa[8] = {0, 0, 0, 0, 0, 0, 0, 0};
        #pragma unroll
        for (int c = 0; c < 6; ++c) {
            int tok = c * 8 + row;
            short8 v = *(const short8*)&s_tok[(tok * 16 + (gch ^ (tok & 15))) << 3];
            #pragma unroll
            for (int j = 0; j < 8; ++j) fa[j] += bf2f((u16)v[j]);
        }
        short8 o;
        #pragma unroll
        for (int j = 0; j < 8; ++j) o[j] = (short)f2bf(fa[j] * (1.f / 6.f));
        *(short8*)&s_pool[(row * 16 + (gch ^ row)) << 3] = o;
    }
    __syncthreads();

    // ---- S8: pooled @ Wp + bp, ReLU ----
    {
        int arow = col & 7;
        short8 A[4];
        #pragma unroll
        for (int kk = 0; kk < 4; ++kk) {
            int g = kk * 4 + lg;
            A[kk] = *(const short8*)&s_pool[(arow * 16 + (g ^ arow)) << 3];
        }
        #pragma unroll
        for (int ni = 0; ni < 2; ++ni) {
            int n = wv * 2 + ni;
            float b = bp[n * 16 + col];
            f32x4 acc = {b, b, b, b};
            #pragma unroll
            for (int kk = 0; kk < 4; ++kk) {
                short8 Bf = *(const short8*)&ws[OFF_WP + (((n * 4 + kk) * 64 + lane) << 3)];
                acc = __builtin_amdgcn_mfma_f32_16x16x32_bf16(A[kk], Bf, acc, 0, 0, 0);
            }
            if (lg < 2) {
                #pragma unroll
                for (int r = 0; r < 4; ++r) {
                    int row = lg * 4 + r;
                    s_out[row * 260 + n * 16 + col] = fmaxf(acc[r], 0.f);
                }
            }
        }
    }
    __syncthreads();

    // ---- S9: coalesced store ----
    if (t < 256) {
        int row = t >> 5, c8 = (t & 31) * 8;
        f32x4 v0 = *(const f32x4*)&s_out[row * 260 + c8];
        f32x4 v1 = *(const f32x4*)&s_out[row * 260 + c8 + 4];
        float* dst = out + ((size_t)blk * 8 + row) * 256 + c8;
        *(f32x4*)dst = v0;
        *(f32x4*)(dst + 4) = v1;
    }
}

extern "C" void kernel_launch(void* const* d_in, const int* in_sizes, int n_in,
                              void* d_out, int out_size, void* d_ws, size_t ws_size,
                              hipStream_t stream) {
    const float* x    = (const float*)d_in[0];
    const float* Wv   = (const float*)d_in[1];
    const float* bv   = (const float*)d_in[2];
    const float* Wm   = (const float*)d_in[3];
    const float* bm   = (const float*)d_in[4];
    const float* Wi   = (const float*)d_in[5];
    const float* bi   = (const float*)d_in[6];
    const float* Wb   = (const float*)d_in[7];
    const float* bb   = (const float*)d_in[8];
    const float* Wc   = (const float*)d_in[9];
    const float* bc   = (const float*)d_in[10];
    const float* Wf   = (const float*)d_in[11];
    const float* bf_  = (const float*)d_in[12];
    const float* Pv   = (const float*)d_in[13];
    const float* pv   = (const float*)d_in[14];
    const float* Pm   = (const float*)d_in[15];
    const float* pm   = (const float*)d_in[16];
    const float* Pi   = (const float*)d_in[17];
    const float* pii  = (const float*)d_in[18];
    const float* Pb   = (const float*)d_in[19];
    const float* pb   = (const float*)d_in[20];
    const float* Pc   = (const float*)d_in[21];
    const float* pc   = (const float*)d_in[22];
    const float* Pf   = (const float*)d_in[23];
    const float* pf   = (const float*)d_in[24];
    const float* Wqkv = (const float*)d_in[25];
    const float* bqkv = (const float*)d_in[26];
    const float* Wo   = (const float*)d_in[27];
    const float* bo   = (const float*)d_in[28];
    const float* gg   = (const float*)d_in[29];
    const float* beta = (const float*)d_in[30];
    const float* Wp   = (const float*)d_in[31];
    const float* bp   = (const float*)d_in[32];
    float* out = (float*)d_out;
    u16* ws = (u16*)d_ws;

    convert_weights<<<(CW_TOTAL + 511) / 512, 512, 0, stream>>>(
        Wqkv, Wo, Wp, Pv, Pm, Pi, Pb, Pc, Pf,
        Wv, Wm, Wi, Wb, Wc, Wf, bv, bm, bi, bb, bc, bf_, ws);

    const int Bn = in_sizes[0] / 29;       // 65536
    asmlp_mfma<<<Bn / 8, 512, 0, stream>>>(
        x, pv, pm, pii, pb, pc, pf,
        bqkv, bo, gg, beta, bp, ws, out);
}

// Round 13
// 279.304 us; speedup vs baseline: 6.3512x; 1.0266x over previous
//
#include <hip/hip_runtime.h>
#include <math.h>

typedef float f32x4 __attribute__((ext_vector_type(4)));
typedef short short8 __attribute__((ext_vector_type(8)));
typedef unsigned short u16;

#define LN_EPS 1e-5f

static __device__ __forceinline__ unsigned cvt_pk_bf16(float lo, float hi) {
    unsigned r;
    asm("v_cvt_pk_bf16_f32 %0, %1, %2" : "=v"(r) : "v"(lo), "v"(hi));
    return r;
}
static __device__ __forceinline__ u16 f2bf(float f) { return (u16)cvt_pk_bf16(f, f); }
static __device__ __forceinline__ float bf2f(u16 u) {
    return __uint_as_float(((unsigned)u) << 16);
}

// ws segment offsets (u16 elements). Fragment-linear layout (works as A- or B-operand):
// idx = ((ntile*Ksteps + kk)*64 + lane)*8 + j -> W[kk*32+(lane>>4)*8+j][ntile*16+(lane&15)]
#define OFF_QKV 0
#define OFF_WO  49152
#define OFF_WP  65536
#define OFF_PV  98304
#define OFF_PM  106496
#define OFF_PI  114688
#define OFF_PB  118784
#define OFF_PC  122880
#define OFF_PF  131072
#define OFF_WENC 147456     // block-diag encoder weight, hi/lo stacked: 24 ntiles x 2 ksteps
#define OFF_BENC 172032     // f32 region (384 floats) starts at this u16 index
#define CW_TOTAL 172416

__global__ __launch_bounds__(512) void convert_weights(
    const float* __restrict__ Wqkv, const float* __restrict__ Wo, const float* __restrict__ Wp,
    const float* __restrict__ Pv, const float* __restrict__ Pm, const float* __restrict__ Pi,
    const float* __restrict__ Pb, const float* __restrict__ Pc, const float* __restrict__ Pf,
    const float* __restrict__ Wv, const float* __restrict__ Wm, const float* __restrict__ Wi,
    const float* __restrict__ Wb, const float* __restrict__ Wc, const float* __restrict__ Wf,
    const float* __restrict__ bv, const float* __restrict__ bm, const float* __restrict__ bi,
    const float* __restrict__ bb, const float* __restrict__ bc, const float* __restrict__ bf_,
    u16* __restrict__ ws)
{
    int gid = blockIdx.x * 512 + threadIdx.x;
    if (gid < OFF_WENC) {
        const float* src; int N, Ksteps, local;
        if (gid < OFF_WO)      { src = Wqkv; N = 384; Ksteps = 4; local = gid; }
        else if (gid < OFF_WP) { src = Wo;   N = 128; Ksteps = 4; local = gid - OFF_WO; }
        else if (gid < OFF_PV) { src = Wp;   N = 256; Ksteps = 4; local = gid - OFF_WP; }
        else if (gid < OFF_PM) { src = Pv;   N = 128; Ksteps = 2; local = gid - OFF_PV; }
        else if (gid < OFF_PI) { src = Pm;   N = 128; Ksteps = 2; local = gid - OFF_PM; }
        else if (gid < OFF_PB) { src = Pi;   N = 128; Ksteps = 1; local = gid - OFF_PI; }
        else if (gid < OFF_PC) { src = Pb;   N = 128; Ksteps = 1; local = gid - OFF_PB; }
        else if (gid < OFF_PF) { src = Pc;   N = 128; Ksteps = 2; local = gid - OFF_PC; }
        else                   { src = Pf;   N = 128; Ksteps = 4; local = gid - OFF_PF; }
        int j  = local & 7;
        int l  = (local >> 3) & 63;
        int r2 = local >> 9;
        int kk = r2 % Ksteps;
        int nt = r2 / Ksteps;
        int srow = kk * 32 + (l >> 4) * 8 + j;
        int scol = nt * 16 + (l & 15);
        ws[gid] = f2bf(src[srow * N + scol]);
    } else if (gid < OFF_BENC) {
        int local = gid - OFF_WENC;
        int j = local & 7, l = (local >> 3) & 63, r2 = local >> 9;
        int kk = r2 & 1, nt = r2 >> 1;
        int k = kk * 32 + (l >> 4) * 8 + j;
        int r = k & 31;                    // x input dim (0..31, valid <29)
        int scol = nt * 16 + (l & 15);     // 0..383
        const float* W; int cb, xo, din, dout;
        if (scol < 64)       { W = Wv; cb = 0;   xo = 0;  din = 3;  dout = 64; }
        else if (scol < 128) { W = Wm; cb = 64;  xo = 3;  din = 5;  dout = 64; }
        else if (scol < 160) { W = Wi; cb = 128; xo = 8;  din = 2;  dout = 32; }
        else if (scol < 192) { W = Wb; cb = 160; xo = 10; din = 3;  dout = 32; }
        else if (scol < 256) { W = Wc; cb = 192; xo = 13; din = 6;  dout = 64; }
        else                 { W = Wf; cb = 256; xo = 19; din = 10; dout = 128; }
        int rr = r - xo;
        float val = (r < 29 && rr >= 0 && rr < din) ? W[rr * dout + (scol - cb)] : 0.f;
        ws[gid] = f2bf(val);
    } else if (gid < CW_TOTAL) {
        int j = gid - OFF_BENC;
        const float* b; int off;
        if (j < 64)       { b = bv;  off = 0; }
        else if (j < 128) { b = bm;  off = 64; }
        else if (j < 160) { b = bi;  off = 128; }
        else if (j < 192) { b = bb;  off = 160; }
        else if (j < 256) { b = bc;  off = 192; }
        else              { b = bf_; off = 256; }
        ((float*)(ws + OFF_BENC))[j] = b[j - off];
    }
}

// 8 rows/block, 48 tokens (token = comp*8 + row), 512 threads = 8 waves (wave = row).
// r11 (validated) + ONLY: max-free softmax (clamp@60) + removed P2->PV barrier
// (wave-local s_pp; same-wave DS ops are program-ordered). Pool fusion NOT applied
// (r12's bundle failed; this isolates it).
__global__ __launch_bounds__(512, 4) void asmlp_mfma(
    const float* __restrict__ x,
    const float* __restrict__ pv, const float* __restrict__ pm,
    const float* __restrict__ pi_, const float* __restrict__ pb_,
    const float* __restrict__ pc_, const float* __restrict__ pf_,
    const float* __restrict__ bqkv, const float* __restrict__ bo,
    const float* __restrict__ gg, const float* __restrict__ beta,
    const float* __restrict__ bp,
    const u16* __restrict__ ws,
    float* __restrict__ out)
{
    const int blk  = blockIdx.x;
    const int t    = threadIdx.x;
    const int lane = t & 63;
    const int wv   = t >> 6;
    const int col  = lane & 15;
    const int lg   = lane >> 4;

    __shared__ __attribute__((aligned(16))) u16 sm[24576];   // 49152 B
    u16*   s_tok  = sm;                      // [48 tok][16 g][8] swz g^(tok&15)      12288 B
    u16*   s_vt   = sm + 6144;               // [16 g2][2 ch][16 nn][12 k=p*6+c2]     12288 B
    u16*   s_qk   = sm + 12288;              // col-major [256 col][48 tok]           24576 B
    u16*   s_xa   = sm + 12288;              // [8 row][64 k] hi/lo (overlay qk, S0-S2)
    u16*   s_h    = sm + 12800;              // [8 row][48 g][8] (overlay qk, S1-S2)
    u16*   s_ctx  = sm + 12288;              // [48 tok][16 g][8] (overlay qk, after scores)
    u16*   s_pp   = sm + 18432;              // [8 wv][2 slot][16 k][16 m] (overlay qk upper)
    float* s_part = (float*)(sm + 18432);    // [48 tok][8 wv][2] f32 (overlay pp; S6)
    u16*   s_pool = sm + 6144;               // [8 row][16 g][8] (overlay vt; S7+)
    float* s_out  = (float*)(sm + 7168);     // [8][260] f32 (overlay vt; S8+)

    // ---- S0: stage x as hi/lo bf16 (exact fp32 split), granule-swizzled ----
    if (t < 232) {
        int row = t / 29, cc = t - row * 29;
        float f = x[(size_t)blk * 232 + t];
        u16 hi = f2bf(f);
        float lo = f - bf2f(hi);
        s_xa[row * 64 + (((cc >> 3) ^ (row & 3)) << 3) + (cc & 7)] = hi;
        int c2 = cc + 32;
        s_xa[row * 64 + (((c2 >> 3) ^ (row & 3)) << 3) + (c2 & 7)] = f2bf(lo);
    }
    if (t < 48) {
        int row = t / 6, sl = t - (t / 6) * 6;
        int k = (sl < 3) ? (29 + sl) : (58 + sl);   // 29..31, 61..63
        s_xa[row * 64 + (((k >> 3) ^ (row & 3)) << 3) + (k & 7)] = 0;
    }
    __syncthreads();

    // ---- S1: encoders, transposed MFMA: C[enc_col][row] ----
    {
        int row8 = col & 7;
        short8 B0 = *(const short8*)&s_xa[row8 * 64 + ((lg ^ (row8 & 3)) << 3)];
        short8 B1 = *(const short8*)&s_xa[row8 * 64 + (((4 + lg) ^ (row8 & 3)) << 3)];
        const float* benc = (const float*)(ws + OFF_BENC);
        #pragma unroll
        for (int q = 0; q < 3; ++q) {
            int nt = wv * 3 + q;
            f32x4 acc = *(const f32x4*)&benc[nt * 16 + lg * 4];
            short8 A0 = *(const short8*)&ws[OFF_WENC + (((nt * 2 + 0) * 64 + lane) << 3)];
            short8 A1 = *(const short8*)&ws[OFF_WENC + (((nt * 2 + 1) * 64 + lane) << 3)];
            acc = __builtin_amdgcn_mfma_f32_16x16x32_bf16(A0, B0, acc, 0, 0, 0);
            acc = __builtin_amdgcn_mfma_f32_16x16x32_bf16(A1, B1, acc, 0, 0, 0);
            if (col < 8) {
                int ge = nt * 2 + (lg >> 1);
                uint2 w;
                w.x = cvt_pk_bf16(fmaxf(acc[0], 0.f), fmaxf(acc[1], 0.f));
                w.y = cvt_pk_bf16(fmaxf(acc[2], 0.f), fmaxf(acc[3], 0.f));
                *(uint2*)&s_h[((col * 48 + (ge ^ col)) << 3) + (lg & 1) * 4] = w;
            }
        }
    }
    __syncthreads();

    // ---- S2: projections, transposed: C[proj_col][row] ----
    #pragma unroll
    for (int q = 0; q < 6; ++q) {
        int unit = wv * 6 + q;
        int c = unit >> 3, n = unit & 7;
        const float* bias; int ks, hg, wso;
        switch (c) {
            case 0:  bias = pv;  ks = 2; hg = 0;  wso = OFF_PV; break;
            case 1:  bias = pm;  ks = 2; hg = 8;  wso = OFF_PM; break;
            case 2:  bias = pi_; ks = 1; hg = 16; wso = OFF_PI; break;
            case 3:  bias = pb_; ks = 1; hg = 20; wso = OFF_PB; break;
            case 4:  bias = pc_; ks = 2; hg = 24; wso = OFF_PC; break;
            default: bias = pf_; ks = 4; hg = 32; wso = OFF_PF; break;
        }
        f32x4 acc = *(const f32x4*)&bias[n * 16 + lg * 4];
        int hrow = col & 7;
        for (int kk = 0; kk < ks; ++kk) {
            short8 A = *(const short8*)&ws[wso + (((n * ks + kk) * 64 + lane) << 3)];
            short8 B = *(const short8*)&s_h[(hrow * 48 + ((hg + kk * 4 + lg) ^ hrow)) << 3];
            acc = __builtin_amdgcn_mfma_f32_16x16x32_bf16(A, B, acc, 0, 0, 0);
        }
        if (col < 8) {
            int tok = c * 8 + col;
            int gt = n * 2 + (lg >> 1);
            uint2 w;
            w.x = cvt_pk_bf16(acc[0], acc[1]);
            w.y = cvt_pk_bf16(acc[2], acc[3]);
            *(uint2*)&s_tok[((tok * 16 + (gt ^ (tok & 15))) << 3) + (lg & 1) * 4] = w;
        }
    }
    __syncthreads();

    // ---- S3: QKV (MFMA). Q/K -> col-major s_qk (cvt_pk + b64); V -> s_vt [*12] ----
    {
        short8 Bf[3][4];
        float  bb_[3];
        #pragma unroll
        for (int ni = 0; ni < 3; ++ni) {
            int n = wv * 3 + ni;
            bb_[ni] = bqkv[n * 16 + col];
            #pragma unroll
            for (int kk = 0; kk < 4; ++kk)
                Bf[ni][kk] = *(const short8*)&ws[OFF_QKV + (((n * 4 + kk) * 64 + lane) << 3)];
        }
        for (int mt = 0; mt < 3; ++mt) {
            short8 A[4];
            int arow = mt * 16 + col;
            #pragma unroll
            for (int kk = 0; kk < 4; ++kk) {
                int g = kk * 4 + lg;
                A[kk] = *(const short8*)&s_tok[(arow * 16 + (g ^ (arow & 15))) << 3];
            }
            #pragma unroll
            for (int ni = 0; ni < 3; ++ni) {
                f32x4 acc = {bb_[ni], bb_[ni], bb_[ni], bb_[ni]};
                #pragma unroll
                for (int kk = 0; kk < 4; ++kk)
                    acc = __builtin_amdgcn_mfma_f32_16x16x32_bf16(A[kk], Bf[ni][kk], acc, 0, 0, 0);
                int cn = wv * 3 + ni;
                int cg = cn * 16 + col;                 // global qkv column
                if (cn < 16) {
                    // Q/K: col-major, token index XOR-swizzled by ((cg>>3)&3)<<2
                    int q4 = ((cg >> 3) & 3) << 2;
                    int tb = (mt * 16 + lg * 4) ^ q4;
                    uint2 w;
                    w.x = cvt_pk_bf16(acc[0], acc[1]);
                    w.y = cvt_pk_bf16(acc[2], acc[3]);
                    *(uint2*)&s_qk[cg * 48 + tb] = w;
                } else {
                    int d = cg - 256;
                    int h = d >> 5, ch = (d >> 4) & 1, nn = d & 15;
                    #pragma unroll
                    for (int r = 0; r < 4; ++r) {
                        int token = mt * 16 + lg * 4 + r;
                        int c2 = token >> 3, rb = token & 7;
                        int g2 = rb * 2 + (h >> 1);
                        int kidx = (h & 1) * 6 + c2;
                        s_vt[((g2 * 2 + ch) * 16 + nn) * 12 + kidx] = f2bf(acc[r]);
                    }
                }
            }
        }
    }
    __syncthreads();

    // ---- SCORES phase 1: MFMAs only (last readers of s_qk) ----
    f32x4 scf[2];
    {
        const int rb = wv;
        #pragma unroll
        for (int i = 0; i < 2; ++i) {
            const int hp = i;
            int p  = (col >= 6 && col < 12) ? 1 : 0;
            int qi = (col < 6) ? col : ((col < 12) ? col - 6 : 0);
            int tt = qi * 8 + rb;
            int h  = hp * 2 + p;
            int tsw = tt ^ (lg << 2);
            int abase = (h * 32 + lg * 8) * 48 + tsw;          // Q cols 0..127
            int bbase = (128 + h * 32 + lg * 8) * 48 + tsw;    // K cols 128..255
            short8 Aq, Bk;
            #pragma unroll
            for (int j = 0; j < 8; ++j) {
                Aq[j] = (short)s_qk[abase + j * 48];
                Bk[j] = (short)s_qk[bbase + j * 48];
            }
            f32x4 sc = {0.f, 0.f, 0.f, 0.f};
            scf[i] = __builtin_amdgcn_mfma_f32_16x16x32_bf16(Aq, Bk, sc, 0, 0, 0);
        }
    }
    __syncthreads();   // s_qk now dead -> its space becomes s_ctx + s_pp

    // ---- SCORES phase 2: max-free softmax in C-regs -> s_pp (wave-local) ----
    {
        #pragma unroll
        for (int i = 0; i < 2; ++i) {
            u16* pp = s_pp + (wv * 2 + i) * 256;
            f32x4 pr4;
            #pragma unroll
            for (int r = 0; r < 4; ++r) {
                int mr = lg * 4 + r;
                int prr = (mr >= 6 && mr < 12) ? 1 : 0;
                // softmax is shift-invariant; scores are O(1), clamp@60 guards overflow
                float v = fminf(scf[i][r] * 0.17677669529663687f, 60.f);
                bool inR = (col >= 6 * prr) && (col < 6 * prr + 6);
                float e = inR ? __expf(v) : 0.f;
                float s = e;
                #pragma unroll
                for (int off = 1; off < 16; off <<= 1)
                    s += __shfl_xor(s, off, 16);
                pr4[r] = (mr < 12) ? (e / s) : 0.f;
            }
            uint2 w;
            w.x = cvt_pk_bf16(pr4[0], pr4[1]);
            w.y = cvt_pk_bf16(pr4[2], pr4[3]);
            *(uint2*)&pp[col * 16 + lg * 4] = w;   // Ppad[k=col][m quad]
        }
    }
    // no barrier: s_pp is wave-local (same-wave DS ops are program-ordered;
    // s_vt/s_ctx overlay protected by the scores-P1 barrier)

    // ---- PV: ctx = P @ V via MFMA (A from s_pp block-diag, B 2x b64 from s_vt) ----
    {
        const int rb = wv;
        #pragma unroll
        for (int i = 0; i < 2; ++i) {
            const int hp = i;
            u16* pp = s_pp + (wv * 2 + i) * 256;
            short8 Ap;
            if (lg < 2) {
                #pragma unroll
                for (int j = 0; j < 8; ++j)
                    Ap[j] = (short)pp[(lg * 8 + j) * 16 + col];
            } else {
                #pragma unroll
                for (int j = 0; j < 8; ++j) Ap[j] = 0;
            }
            int g2 = rb * 2 + hp;
            #pragma unroll
            for (int ch = 0; ch < 2; ++ch) {
                // 12-wide rows: two 8B-aligned b64 reads; upper half's last 4 slots
                // (k=12..15) read the next row / region (finite) x pp rows 12..15 == 0.
                int vbase = ((g2 * 2 + ch) * 16 + col) * 12 + ((lg & 1) * 8);
                uint2 vlo = *(const uint2*)&s_vt[vbase];
                uint2 vhi = *(const uint2*)&s_vt[vbase + 4];
                union { uint4 u; short8 s; } cvu;
                cvu.u.x = vlo.x; cvu.u.y = vlo.y; cvu.u.z = vhi.x; cvu.u.w = vhi.y;
                short8 Bv = cvu.s;
                f32x4 c = {0.f, 0.f, 0.f, 0.f};
                c = __builtin_amdgcn_mfma_f32_16x16x32_bf16(Ap, Bv, c, 0, 0, 0);
                #pragma unroll
                for (int r = 0; r < 4; ++r) {
                    int mr = lg * 4 + r;
                    if (mr < 12) {
                        int pq = mr >= 6 ? 1 : 0;
                        int qi = mr - 6 * pq;
                        int token = qi * 8 + rb;
                        int d = (hp * 2 + pq) * 32 + ch * 16 + col;
                        s_ctx[((token * 16 + ((d >> 3) ^ (token & 15))) << 3) + (d & 7)] = f2bf(c[r]);
                    }
                }
            }
        }
    }
    __syncthreads();   // s_pp dead -> region becomes s_part

    // ---- S6 (8-wave): out-proj transposed + residual + LN w/ cross-wave partials ----
    {
        const int mo = wv;                     // this wave's 16 output cols
        short8 Afr[4];
        #pragma unroll
        for (int kk = 0; kk < 4; ++kk)
            Afr[kk] = *(const short8*)&ws[OFF_WO + (((mo * 4 + kk) * 64 + lane) << 3)];
        f32x4 biasv = *(const f32x4*)&bo[mo * 16 + lg * 4];
        f32x4 accs[3];
        #pragma unroll
        for (int tt = 0; tt < 3; ++tt) {
            int tokr = tt * 16 + col;
            f32x4 acc = biasv;
            #pragma unroll
            for (int kk = 0; kk < 4; ++kk) {
                short8 Bf = *(const short8*)&s_ctx[(tokr * 16 + ((kk * 4 + lg) ^ (tokr & 15))) << 3];
                acc = __builtin_amdgcn_mfma_f32_16x16x32_bf16(Afr[kk], Bf, acc, 0, 0, 0);
            }
            const u16* rp = &s_tok[((tokr * 16 + ((mo * 2 + (lg >> 1)) ^ (tokr & 15))) << 3) + (lg & 1) * 4];
            #pragma unroll
            for (int r = 0; r < 4; ++r) acc[r] += bf2f(rp[r]);
            accs[tt] = acc;
            float s1 = acc[0] + acc[1] + acc[2] + acc[3];
            float s2 = acc[0]*acc[0] + acc[1]*acc[1] + acc[2]*acc[2] + acc[3]*acc[3];
            s1 += __shfl_xor(s1, 16, 64); s1 += __shfl_xor(s1, 32, 64);
            s2 += __shfl_xor(s2, 16, 64); s2 += __shfl_xor(s2, 32, 64);
            if (lg == 0) {
                float2 pw; pw.x = s1; pw.y = s2;
                *(float2*)&s_part[(tokr * 8 + wv) * 2] = pw;
            }
        }
        __syncthreads();
        f32x4 gv = *(const f32x4*)&gg[mo * 16 + lg * 4];
        f32x4 bv = *(const f32x4*)&beta[mo * 16 + lg * 4];
        #pragma unroll
        for (int tt = 0; tt < 3; ++tt) {
            int tokr = tt * 16 + col;
            const float* pr = &s_part[tokr * 16];
            f32x4 p0 = *(const f32x4*)pr;
            f32x4 p1 = *(const f32x4*)(pr + 4);
            f32x4 p2 = *(const f32x4*)(pr + 8);
            f32x4 p3 = *(const f32x4*)(pr + 12);
            float S1 = p0[0]+p0[2]+p1[0]+p1[2]+p2[0]+p2[2]+p3[0]+p3[2];
            float S2 = p0[1]+p0[3]+p1[1]+p1[3]+p2[1]+p2[3]+p3[1]+p3[3];
            float mu = S1 * (1.f / 128.f);
            float var = S2 * (1.f / 128.f) - mu * mu;
            float rs = rsqrtf(var + LN_EPS);
            f32x4 a = accs[tt];
            uint2 w;
            w.x = cvt_pk_bf16((a[0]-mu)*rs*gv[0]+bv[0], (a[1]-mu)*rs*gv[1]+bv[1]);
            w.y = cvt_pk_bf16((a[2]-mu)*rs*gv[2]+bv[2], (a[3]-mu)*rs*gv[3]+bv[3]);
            *(uint2*)&s_tok[((tokr * 16 + ((mo * 2 + (lg >> 1)) ^ (tokr & 15))) << 3) + (lg & 1) * 4] = w;
        }
    }
    __syncthreads();

    // ---- S7: mean-pool over 6 tokens ----
    if (t < 128) {
        int row = t >> 4, gch = t & 15;
        float fa[8] = {0, 0, 0, 0, 0, 0, 0, 0};
        #pragma unroll
        for (int c = 0; c < 6; ++c) {
            int tok = c * 8 + row;
            short8 v = *(const short8*)&s_tok[(tok * 16 + (gch ^ (tok & 15))) << 3];
            #pragma unroll
            for (int j = 0; j < 8; ++j) fa[j] += bf2f((u16)v[j]);
        }
        short8 o;
        #pragma unroll
        for (int j = 0; j < 8; ++j) o[j] = (short)f2bf(fa[j] * (1.f / 6.f));
        *(short8*)&s_pool[(row * 16 + (gch ^ row)) << 3] = o;
    }
    __syncthreads();

    // ---- S8: pooled @ Wp + bp, ReLU ----
    {
        int arow = col & 7;
        short8 A[4];
        #pragma unroll
        for (int kk = 0; kk < 4; ++kk) {
            int g = kk * 4 + lg;
            A[kk] = *(const short8*)&s_pool[(arow * 16 + (g ^ arow)) << 3];
        }
        #pragma unroll
        for (int ni = 0; ni < 2; ++ni) {
            int n = wv * 2 + ni;
            float b = bp[n * 16 + col];
            f32x4 acc = {b, b, b, b};
            #pragma unroll
            for (int kk = 0; kk < 4; ++kk) {
                short8 Bf = *(const short8*)&ws[OFF_WP + (((n * 4 + kk) * 64 + lane) << 3)];
                acc = __builtin_amdgcn_mfma_f32_16x16x32_bf16(A[kk], Bf, acc, 0, 0, 0);
            }
            if (lg < 2) {
                #pragma unroll
                for (int r = 0; r < 4; ++r) {
                    int row = lg * 4 + r;
                    s_out[row * 260 + n * 16 + col] = fmaxf(acc[r], 0.f);
                }
            }
        }
    }
    __syncthreads();

    // ---- S9: coalesced store ----
    if (t < 256) {
        int row = t >> 5, c8 = (t & 31) * 8;
        f32x4 v0 = *(const f32x4*)&s_out[row * 260 + c8];
        f32x4 v1 = *(const f32x4*)&s_out[row * 260 + c8 + 4];
        float* dst = out + ((size_t)blk * 8 + row) * 256 + c8;
        *(f32x4*)dst = v0;
        *(f32x4*)(dst + 4) = v1;
    }
}

extern "C" void kernel_launch(void* const* d_in, const int* in_sizes, int n_in,
                              void* d_out, int out_size, void* d_ws, size_t ws_size,
                              hipStream_t stream) {
    const float* x    = (const float*)d_in[0];
    const float* Wv   = (const float*)d_in[1];
    const float* bv   = (const float*)d_in[2];
    const float* Wm   = (const float*)d_in[3];
    const float* bm   = (const float*)d_in[4];
    const float* Wi   = (const float*)d_in[5];
    const float* bi   = (const float*)d_in[6];
    const float* Wb   = (const float*)d_in[7];
    const float* bb   = (const float*)d_in[8];
    const float* Wc   = (const float*)d_in[9];
    const float* bc   = (const float*)d_in[10];
    const float* Wf   = (const float*)d_in[11];
    const float* bf_  = (const float*)d_in[12];
    const float* Pv   = (const float*)d_in[13];
    const float* pv   = (const float*)d_in[14];
    const float* Pm   = (const float*)d_in[15];
    const float* pm   = (const float*)d_in[16];
    const float* Pi   = (const float*)d_in[17];
    const float* pii  = (const float*)d_in[18];
    const float* Pb   = (const float*)d_in[19];
    const float* pb   = (const float*)d_in[20];
    const float* Pc   = (const float*)d_in[21];
    const float* pc   = (const float*)d_in[22];
    const float* Pf   = (const float*)d_in[23];
    const float* pf   = (const float*)d_in[24];
    const float* Wqkv = (const float*)d_in[25];
    const float* bqkv = (const float*)d_in[26];
    const float* Wo   = (const float*)d_in[27];
    const float* bo   = (const float*)d_in[28];
    const float* gg   = (const float*)d_in[29];
    const float* beta = (const float*)d_in[30];
    const float* Wp   = (const float*)d_in[31];
    const float* bp   = (const float*)d_in[32];
    float* out = (float*)d_out;
    u16* ws = (u16*)d_ws;

    convert_weights<<<(CW_TOTAL + 511) / 512, 512, 0, stream>>>(
        Wqkv, Wo, Wp, Pv, Pm, Pi, Pb, Pc, Pf,
        Wv, Wm, Wi, Wb, Wc, Wf, bv, bm, bi, bb, bc, bf_, ws);

    const int Bn = in_sizes[0] / 29;       // 65536
    asmlp_mfma<<<Bn / 8, 512, 0, stream>>>(
        x, pv, pm, pii, pb, pc, pf,
        bqkv, bo, gg, beta, bp, ws, out);
}

// Round 15
// 277.733 us; speedup vs baseline: 6.3871x; 1.0057x over previous
//
#include <hip/hip_runtime.h>
#include <math.h>

typedef float f32x4 __attribute__((ext_vector_type(4)));
typedef short short8 __attribute__((ext_vector_type(8)));
typedef unsigned short u16;

#define LN_EPS 1e-5f

static __device__ __forceinline__ unsigned cvt_pk_bf16(float lo, float hi) {
    unsigned r;
    asm("v_cvt_pk_bf16_f32 %0, %1, %2" : "=v"(r) : "v"(lo), "v"(hi));
    return r;
}
static __device__ __forceinline__ u16 f2bf(float f) { return (u16)cvt_pk_bf16(f, f); }
static __device__ __forceinline__ float bf2f(u16 u) {
    return __uint_as_float(((unsigned)u) << 16);
}

// ws segment offsets (u16 elements). Fragment-linear layout (works as A- or B-operand):
// idx = ((ntile*Ksteps + kk)*64 + lane)*8 + j -> W[kk*32+(lane>>4)*8+j][ntile*16+(lane&15)]
#define OFF_QKV 0
#define OFF_WO  49152
#define OFF_WP  65536
#define OFF_PV  98304
#define OFF_PM  106496
#define OFF_PI  114688
#define OFF_PB  118784
#define OFF_PC  122880
#define OFF_PF  131072
#define OFF_WENC 147456     // block-diag encoder weight, hi/lo stacked: 24 ntiles x 2 ksteps
#define OFF_BENC 172032     // f32 region (384 floats) starts at this u16 index
#define CW_TOTAL 172416

__global__ __launch_bounds__(512) void convert_weights(
    const float* __restrict__ Wqkv, const float* __restrict__ Wo, const float* __restrict__ Wp,
    const float* __restrict__ Pv, const float* __restrict__ Pm, const float* __restrict__ Pi,
    const float* __restrict__ Pb, const float* __restrict__ Pc, const float* __restrict__ Pf,
    const float* __restrict__ Wv, const float* __restrict__ Wm, const float* __restrict__ Wi,
    const float* __restrict__ Wb, const float* __restrict__ Wc, const float* __restrict__ Wf,
    const float* __restrict__ bv, const float* __restrict__ bm, const float* __restrict__ bi,
    const float* __restrict__ bb, const float* __restrict__ bc, const float* __restrict__ bf_,
    u16* __restrict__ ws)
{
    int gid = blockIdx.x * 512 + threadIdx.x;
    if (gid < OFF_WENC) {
        const float* src; int N, Ksteps, local;
        if (gid < OFF_WO)      { src = Wqkv; N = 384; Ksteps = 4; local = gid; }
        else if (gid < OFF_WP) { src = Wo;   N = 128; Ksteps = 4; local = gid - OFF_WO; }
        else if (gid < OFF_PV) { src = Wp;   N = 256; Ksteps = 4; local = gid - OFF_WP; }
        else if (gid < OFF_PM) { src = Pv;   N = 128; Ksteps = 2; local = gid - OFF_PV; }
        else if (gid < OFF_PI) { src = Pm;   N = 128; Ksteps = 2; local = gid - OFF_PM; }
        else if (gid < OFF_PB) { src = Pi;   N = 128; Ksteps = 1; local = gid - OFF_PI; }
        else if (gid < OFF_PC) { src = Pb;   N = 128; Ksteps = 1; local = gid - OFF_PB; }
        else if (gid < OFF_PF) { src = Pc;   N = 128; Ksteps = 2; local = gid - OFF_PC; }
        else                   { src = Pf;   N = 128; Ksteps = 4; local = gid - OFF_PF; }
        int j  = local & 7;
        int l  = (local >> 3) & 63;
        int r2 = local >> 9;
        int kk = r2 % Ksteps;
        int nt = r2 / Ksteps;
        int srow = kk * 32 + (l >> 4) * 8 + j;
        int scol = nt * 16 + (l & 15);
        ws[gid] = f2bf(src[srow * N + scol]);
    } else if (gid < OFF_BENC) {
        int local = gid - OFF_WENC;
        int j = local & 7, l = (local >> 3) & 63, r2 = local >> 9;
        int kk = r2 & 1, nt = r2 >> 1;
        int k = kk * 32 + (l >> 4) * 8 + j;
        int r = k & 31;                    // x input dim (0..31, valid <29)
        int scol = nt * 16 + (l & 15);     // 0..383
        const float* W; int cb, xo, din, dout;
        if (scol < 64)       { W = Wv; cb = 0;   xo = 0;  din = 3;  dout = 64; }
        else if (scol < 128) { W = Wm; cb = 64;  xo = 3;  din = 5;  dout = 64; }
        else if (scol < 160) { W = Wi; cb = 128; xo = 8;  din = 2;  dout = 32; }
        else if (scol < 192) { W = Wb; cb = 160; xo = 10; din = 3;  dout = 32; }
        else if (scol < 256) { W = Wc; cb = 192; xo = 13; din = 6;  dout = 64; }
        else                 { W = Wf; cb = 256; xo = 19; din = 10; dout = 128; }
        int rr = r - xo;
        float val = (r < 29 && rr >= 0 && rr < din) ? W[rr * dout + (scol - cb)] : 0.f;
        ws[gid] = f2bf(val);
    } else if (gid < CW_TOTAL) {
        int j = gid - OFF_BENC;
        const float* b; int off;
        if (j < 64)       { b = bv;  off = 0; }
        else if (j < 128) { b = bm;  off = 64; }
        else if (j < 160) { b = bi;  off = 128; }
        else if (j < 192) { b = bb;  off = 160; }
        else if (j < 256) { b = bc;  off = 192; }
        else              { b = bf_; off = 256; }
        ((float*)(ws + OFF_BENC))[j] = b[j - off];
    }
}

// 8 rows/block, 48 tokens (token = comp*8 + row), 512 threads = 8 waves (wave = row).
// r13 (validated, 279 us) + S8 stores directly to global (bit-identical values;
// s_out staging, final barrier, and S9 deleted).
__global__ __launch_bounds__(512, 4) void asmlp_mfma(
    const float* __restrict__ x,
    const float* __restrict__ pv, const float* __restrict__ pm,
    const float* __restrict__ pi_, const float* __restrict__ pb_,
    const float* __restrict__ pc_, const float* __restrict__ pf_,
    const float* __restrict__ bqkv, const float* __restrict__ bo,
    const float* __restrict__ gg, const float* __restrict__ beta,
    const float* __restrict__ bp,
    const u16* __restrict__ ws,
    float* __restrict__ out)
{
    const int blk  = blockIdx.x;
    const int t    = threadIdx.x;
    const int lane = t & 63;
    const int wv   = t >> 6;
    const int col  = lane & 15;
    const int lg   = lane >> 4;

    __shared__ __attribute__((aligned(16))) u16 sm[24576];   // 49152 B
    u16*   s_tok  = sm;                      // [48 tok][16 g][8] swz g^(tok&15)      12288 B
    u16*   s_vt   = sm + 6144;               // [16 g2][2 ch][16 nn][12 k=p*6+c2]     12288 B
    u16*   s_qk   = sm + 12288;              // col-major [256 col][48 tok]           24576 B
    u16*   s_xa   = sm + 12288;              // [8 row][64 k] hi/lo (overlay qk, S0-S2)
    u16*   s_h    = sm + 12800;              // [8 row][48 g][8] (overlay qk, S1-S2)
    u16*   s_ctx  = sm + 12288;              // [48 tok][16 g][8] (overlay qk, after scores)
    u16*   s_pp   = sm + 18432;              // [8 wv][2 slot][16 k][16 m] (overlay qk upper)
    float* s_part = (float*)(sm + 18432);    // [48 tok][8 wv][2] f32 (overlay pp; S6)
    u16*   s_pool = sm + 6144;               // [8 row][16 g][8] (overlay vt; S7+)

    // ---- S0: stage x as hi/lo bf16 (exact fp32 split), granule-swizzled ----
    if (t < 232) {
        int row = t / 29, cc = t - row * 29;
        float f = x[(size_t)blk * 232 + t];
        u16 hi = f2bf(f);
        float lo = f - bf2f(hi);
        s_xa[row * 64 + (((cc >> 3) ^ (row & 3)) << 3) + (cc & 7)] = hi;
        int c2 = cc + 32;
        s_xa[row * 64 + (((c2 >> 3) ^ (row & 3)) << 3) + (c2 & 7)] = f2bf(lo);
    }
    if (t < 48) {
        int row = t / 6, sl = t - (t / 6) * 6;
        int k = (sl < 3) ? (29 + sl) : (58 + sl);   // 29..31, 61..63
        s_xa[row * 64 + (((k >> 3) ^ (row & 3)) << 3) + (k & 7)] = 0;
    }
    __syncthreads();

    // ---- S1: encoders, transposed MFMA: C[enc_col][row] ----
    {
        int row8 = col & 7;
        short8 B0 = *(const short8*)&s_xa[row8 * 64 + ((lg ^ (row8 & 3)) << 3)];
        short8 B1 = *(const short8*)&s_xa[row8 * 64 + (((4 + lg) ^ (row8 & 3)) << 3)];
        const float* benc = (const float*)(ws + OFF_BENC);
        #pragma unroll
        for (int q = 0; q < 3; ++q) {
            int nt = wv * 3 + q;
            f32x4 acc = *(const f32x4*)&benc[nt * 16 + lg * 4];
            short8 A0 = *(const short8*)&ws[OFF_WENC + (((nt * 2 + 0) * 64 + lane) << 3)];
            short8 A1 = *(const short8*)&ws[OFF_WENC + (((nt * 2 + 1) * 64 + lane) << 3)];
            acc = __builtin_amdgcn_mfma_f32_16x16x32_bf16(A0, B0, acc, 0, 0, 0);
            acc = __builtin_amdgcn_mfma_f32_16x16x32_bf16(A1, B1, acc, 0, 0, 0);
            if (col < 8) {
                int ge = nt * 2 + (lg >> 1);
                uint2 w;
                w.x = cvt_pk_bf16(fmaxf(acc[0], 0.f), fmaxf(acc[1], 0.f));
                w.y = cvt_pk_bf16(fmaxf(acc[2], 0.f), fmaxf(acc[3], 0.f));
                *(uint2*)&s_h[((col * 48 + (ge ^ col)) << 3) + (lg & 1) * 4] = w;
            }
        }
    }
    __syncthreads();

    // ---- S2: projections, transposed: C[proj_col][row] ----
    #pragma unroll
    for (int q = 0; q < 6; ++q) {
        int unit = wv * 6 + q;
        int c = unit >> 3, n = unit & 7;
        const float* bias; int ks, hg, wso;
        switch (c) {
            case 0:  bias = pv;  ks = 2; hg = 0;  wso = OFF_PV; break;
            case 1:  bias = pm;  ks = 2; hg = 8;  wso = OFF_PM; break;
            case 2:  bias = pi_; ks = 1; hg = 16; wso = OFF_PI; break;
            case 3:  bias = pb_; ks = 1; hg = 20; wso = OFF_PB; break;
            case 4:  bias = pc_; ks = 2; hg = 24; wso = OFF_PC; break;
            default: bias = pf_; ks = 4; hg = 32; wso = OFF_PF; break;
        }
        f32x4 acc = *(const f32x4*)&bias[n * 16 + lg * 4];
        int hrow = col & 7;
        for (int kk = 0; kk < ks; ++kk) {
            short8 A = *(const short8*)&ws[wso + (((n * ks + kk) * 64 + lane) << 3)];
            short8 B = *(const short8*)&s_h[(hrow * 48 + ((hg + kk * 4 + lg) ^ hrow)) << 3];
            acc = __builtin_amdgcn_mfma_f32_16x16x32_bf16(A, B, acc, 0, 0, 0);
        }
        if (col < 8) {
            int tok = c * 8 + col;
            int gt = n * 2 + (lg >> 1);
            uint2 w;
            w.x = cvt_pk_bf16(acc[0], acc[1]);
            w.y = cvt_pk_bf16(acc[2], acc[3]);
            *(uint2*)&s_tok[((tok * 16 + (gt ^ (tok & 15))) << 3) + (lg & 1) * 4] = w;
        }
    }
    __syncthreads();

    // ---- S3: QKV (MFMA). Q/K -> col-major s_qk (cvt_pk + b64); V -> s_vt [*12] ----
    {
        short8 Bf[3][4];
        float  bb_[3];
        #pragma unroll
        for (int ni = 0; ni < 3; ++ni) {
            int n = wv * 3 + ni;
            bb_[ni] = bqkv[n * 16 + col];
            #pragma unroll
            for (int kk = 0; kk < 4; ++kk)
                Bf[ni][kk] = *(const short8*)&ws[OFF_QKV + (((n * 4 + kk) * 64 + lane) << 3)];
        }
        for (int mt = 0; mt < 3; ++mt) {
            short8 A[4];
            int arow = mt * 16 + col;
            #pragma unroll
            for (int kk = 0; kk < 4; ++kk) {
                int g = kk * 4 + lg;
                A[kk] = *(const short8*)&s_tok[(arow * 16 + (g ^ (arow & 15))) << 3];
            }
            #pragma unroll
            for (int ni = 0; ni < 3; ++ni) {
                f32x4 acc = {bb_[ni], bb_[ni], bb_[ni], bb_[ni]};
                #pragma unroll
                for (int kk = 0; kk < 4; ++kk)
                    acc = __builtin_amdgcn_mfma_f32_16x16x32_bf16(A[kk], Bf[ni][kk], acc, 0, 0, 0);
                int cn = wv * 3 + ni;
                int cg = cn * 16 + col;                 // global qkv column
                if (cn < 16) {
                    // Q/K: col-major, token index XOR-swizzled by ((cg>>3)&3)<<2
                    int q4 = ((cg >> 3) & 3) << 2;
                    int tb = (mt * 16 + lg * 4) ^ q4;
                    uint2 w;
                    w.x = cvt_pk_bf16(acc[0], acc[1]);
                    w.y = cvt_pk_bf16(acc[2], acc[3]);
                    *(uint2*)&s_qk[cg * 48 + tb] = w;
                } else {
                    int d = cg - 256;
                    int h = d >> 5, ch = (d >> 4) & 1, nn = d & 15;
                    #pragma unroll
                    for (int r = 0; r < 4; ++r) {
                        int token = mt * 16 + lg * 4 + r;
                        int c2 = token >> 3, rb = token & 7;
                        int g2 = rb * 2 + (h >> 1);
                        int kidx = (h & 1) * 6 + c2;
                        s_vt[((g2 * 2 + ch) * 16 + nn) * 12 + kidx] = f2bf(acc[r]);
                    }
                }
            }
        }
    }
    __syncthreads();

    // ---- SCORES phase 1: MFMAs only (last readers of s_qk) ----
    f32x4 scf[2];
    {
        const int rb = wv;
        #pragma unroll
        for (int i = 0; i < 2; ++i) {
            const int hp = i;
            int p  = (col >= 6 && col < 12) ? 1 : 0;
            int qi = (col < 6) ? col : ((col < 12) ? col - 6 : 0);
            int tt = qi * 8 + rb;
            int h  = hp * 2 + p;
            int tsw = tt ^ (lg << 2);
            int abase = (h * 32 + lg * 8) * 48 + tsw;          // Q cols 0..127
            int bbase = (128 + h * 32 + lg * 8) * 48 + tsw;    // K cols 128..255
            short8 Aq, Bk;
            #pragma unroll
            for (int j = 0; j < 8; ++j) {
                Aq[j] = (short)s_qk[abase + j * 48];
                Bk[j] = (short)s_qk[bbase + j * 48];
            }
            f32x4 sc = {0.f, 0.f, 0.f, 0.f};
            scf[i] = __builtin_amdgcn_mfma_f32_16x16x32_bf16(Aq, Bk, sc, 0, 0, 0);
        }
    }
    __syncthreads();   // s_qk now dead -> its space becomes s_ctx + s_pp

    // ---- SCORES phase 2: max-free softmax in C-regs -> s_pp (wave-local) ----
    {
        #pragma unroll
        for (int i = 0; i < 2; ++i) {
            u16* pp = s_pp + (wv * 2 + i) * 256;
            f32x4 pr4;
            #pragma unroll
            for (int r = 0; r < 4; ++r) {
                int mr = lg * 4 + r;
                int prr = (mr >= 6 && mr < 12) ? 1 : 0;
                // softmax is shift-invariant; scores are O(1), clamp@60 guards overflow
                float v = fminf(scf[i][r] * 0.17677669529663687f, 60.f);
                bool inR = (col >= 6 * prr) && (col < 6 * prr + 6);
                float e = inR ? __expf(v) : 0.f;
                float s = e;
                #pragma unroll
                for (int off = 1; off < 16; off <<= 1)
                    s += __shfl_xor(s, off, 16);
                pr4[r] = (mr < 12) ? (e / s) : 0.f;
            }
            uint2 w;
            w.x = cvt_pk_bf16(pr4[0], pr4[1]);
            w.y = cvt_pk_bf16(pr4[2], pr4[3]);
            *(uint2*)&pp[col * 16 + lg * 4] = w;   // Ppad[k=col][m quad]
        }
    }
    // no barrier: s_pp is wave-local (same-wave DS ops are program-ordered;
    // s_vt/s_ctx overlay protected by the scores-P1 barrier)

    // ---- PV: ctx = P @ V via MFMA (A from s_pp block-diag, B 2x b64 from s_vt) ----
    {
        const int rb = wv;
        #pragma unroll
        for (int i = 0; i < 2; ++i) {
            const int hp = i;
            u16* pp = s_pp + (wv * 2 + i) * 256;
            short8 Ap;
            if (lg < 2) {
                #pragma unroll
                for (int j = 0; j < 8; ++j)
                    Ap[j] = (short)pp[(lg * 8 + j) * 16 + col];
            } else {
                #pragma unroll
                for (int j = 0; j < 8; ++j) Ap[j] = 0;
            }
            int g2 = rb * 2 + hp;
            #pragma unroll
            for (int ch = 0; ch < 2; ++ch) {
                // 12-wide rows: two 8B-aligned b64 reads; upper half's last 4 slots
                // (k=12..15) read the next row / region (finite) x pp rows 12..15 == 0.
                int vbase = ((g2 * 2 + ch) * 16 + col) * 12 + ((lg & 1) * 8);
                uint2 vlo = *(const uint2*)&s_vt[vbase];
                uint2 vhi = *(const uint2*)&s_vt[vbase + 4];
                union { uint4 u; short8 s; } cvu;
                cvu.u.x = vlo.x; cvu.u.y = vlo.y; cvu.u.z = vhi.x; cvu.u.w = vhi.y;
                short8 Bv = cvu.s;
                f32x4 c = {0.f, 0.f, 0.f, 0.f};
                c = __builtin_amdgcn_mfma_f32_16x16x32_bf16(Ap, Bv, c, 0, 0, 0);
                #pragma unroll
                for (int r = 0; r < 4; ++r) {
                    int mr = lg * 4 + r;
                    if (mr < 12) {
                        int pq = mr >= 6 ? 1 : 0;
                        int qi = mr - 6 * pq;
                        int token = qi * 8 + rb;
                        int d = (hp * 2 + pq) * 32 + ch * 16 + col;
                        s_ctx[((token * 16 + ((d >> 3) ^ (token & 15))) << 3) + (d & 7)] = f2bf(c[r]);
                    }
                }
            }
        }
    }
    __syncthreads();   // s_pp dead -> region becomes s_part

    // ---- S6 (8-wave): out-proj transposed + residual + LN w/ cross-wave partials ----
    {
        const int mo = wv;                     // this wave's 16 output cols
        short8 Afr[4];
        #pragma unroll
        for (int kk = 0; kk < 4; ++kk)
            Afr[kk] = *(const short8*)&ws[OFF_WO + (((mo * 4 + kk) * 64 + lane) << 3)];
        f32x4 biasv = *(const f32x4*)&bo[mo * 16 + lg * 4];
        f32x4 accs[3];
        #pragma unroll
        for (int tt = 0; tt < 3; ++tt) {
            int tokr = tt * 16 + col;
            f32x4 acc = biasv;
            #pragma unroll
            for (int kk = 0; kk < 4; ++kk) {
                short8 Bf = *(const short8*)&s_ctx[(tokr * 16 + ((kk * 4 + lg) ^ (tokr & 15))) << 3];
                acc = __builtin_amdgcn_mfma_f32_16x16x32_bf16(Afr[kk], Bf, acc, 0, 0, 0);
            }
            const u16* rp = &s_tok[((tokr * 16 + ((mo * 2 + (lg >> 1)) ^ (tokr & 15))) << 3) + (lg & 1) * 4];
            #pragma unroll
            for (int r = 0; r < 4; ++r) acc[r] += bf2f(rp[r]);
            accs[tt] = acc;
            float s1 = acc[0] + acc[1] + acc[2] + acc[3];
            float s2 = acc[0]*acc[0] + acc[1]*acc[1] + acc[2]*acc[2] + acc[3]*acc[3];
            s1 += __shfl_xor(s1, 16, 64); s1 += __shfl_xor(s1, 32, 64);
            s2 += __shfl_xor(s2, 16, 64); s2 += __shfl_xor(s2, 32, 64);
            if (lg == 0) {
                float2 pw; pw.x = s1; pw.y = s2;
                *(float2*)&s_part[(tokr * 8 + wv) * 2] = pw;
            }
        }
        __syncthreads();
        f32x4 gv = *(const f32x4*)&gg[mo * 16 + lg * 4];
        f32x4 bv = *(const f32x4*)&beta[mo * 16 + lg * 4];
        #pragma unroll
        for (int tt = 0; tt < 3; ++tt) {
            int tokr = tt * 16 + col;
            const float* pr = &s_part[tokr * 16];
            f32x4 p0 = *(const f32x4*)pr;
            f32x4 p1 = *(const f32x4*)(pr + 4);
            f32x4 p2 = *(const f32x4*)(pr + 8);
            f32x4 p3 = *(const f32x4*)(pr + 12);
            float S1 = p0[0]+p0[2]+p1[0]+p1[2]+p2[0]+p2[2]+p3[0]+p3[2];
            float S2 = p0[1]+p0[3]+p1[1]+p1[3]+p2[1]+p2[3]+p3[1]+p3[3];
            float mu = S1 * (1.f / 128.f);
            float var = S2 * (1.f / 128.f) - mu * mu;
            float rs = rsqrtf(var + LN_EPS);
            f32x4 a = accs[tt];
            uint2 w;
            w.x = cvt_pk_bf16((a[0]-mu)*rs*gv[0]+bv[0], (a[1]-mu)*rs*gv[1]+bv[1]);
            w.y = cvt_pk_bf16((a[2]-mu)*rs*gv[2]+bv[2], (a[3]-mu)*rs*gv[3]+bv[3]);
            *(uint2*)&s_tok[((tokr * 16 + ((mo * 2 + (lg >> 1)) ^ (tokr & 15))) << 3) + (lg & 1) * 4] = w;
        }
    }
    __syncthreads();

    // ---- S7: mean-pool over 6 tokens ----
    if (t < 128) {
        int row = t >> 4, gch = t & 15;
        float fa[8] = {0, 0, 0, 0, 0, 0, 0, 0};
        #pragma unroll
        for (int c = 0; c < 6; ++c) {
            int tok = c * 8 + row;
            short8 v = *(const short8*)&s_tok[(tok * 16 + (gch ^ (tok & 15))) << 3];
            #pragma unroll
            for (int j = 0; j < 8; ++j) fa[j] += bf2f((u16)v[j]);
        }
        short8 o;
        #pragma unroll
        for (int j = 0; j < 8; ++j) o[j] = (short)f2bf(fa[j] * (1.f / 6.f));
        *(short8*)&s_pool[(row * 16 + (gch ^ row)) << 3] = o;
    }
    __syncthreads();

    // ---- S8: pooled @ Wp + bp, ReLU -> direct coalesced global store ----
    {
        int arow = col & 7;
        short8 A[4];
        #pragma unroll
        for (int kk = 0; kk < 4; ++kk) {
            int g = kk * 4 + lg;
            A[kk] = *(const short8*)&s_pool[(arow * 16 + (g ^ arow)) << 3];
        }
        #pragma unroll
        for (int ni = 0; ni < 2; ++ni) {
            int n = wv * 2 + ni;
            float b = bp[n * 16 + col];
            f32x4 acc = {b, b, b, b};
            #pragma unroll
            for (int kk = 0; kk < 4; ++kk) {
                short8 Bf = *(const short8*)&ws[OFF_WP + (((n * 4 + kk) * 64 + lane) << 3)];
                acc = __builtin_amdgcn_mfma_f32_16x16x32_bf16(A[kk], Bf, acc, 0, 0, 0);
            }
            if (lg < 2) {
                // D[m=lg*4+r][n=col]: per (n,r), lanes 0-15 / 16-31 each cover one
                // contiguous 64B row segment -> coalesced without LDS staging.
                #pragma unroll
                for (int r = 0; r < 4; ++r) {
                    int row = lg * 4 + r;
                    out[((size_t)blk * 8 + row) * 256 + n * 16 + col] = fmaxf(acc[r], 0.f);
                }
            }
        }
    }
}

extern "C" void kernel_launch(void* const* d_in, const int* in_sizes, int n_in,
                              void* d_out, int out_size, void* d_ws, size_t ws_size,
                              hipStream_t stream) {
    const float* x    = (const float*)d_in[0];
    const float* Wv   = (const float*)d_in[1];
    const float* bv   = (const float*)d_in[2];
    const float* Wm   = (const float*)d_in[3];
    const float* bm   = (const float*)d_in[4];
    const float* Wi   = (const float*)d_in[5];
    const float* bi   = (const float*)d_in[6];
    const float* Wb   = (const float*)d_in[7];
    const float* bb   = (const float*)d_in[8];
    const float* Wc   = (const float*)d_in[9];
    const float* bc   = (const float*)d_in[10];
    const float* Wf   = (const float*)d_in[11];
    const float* bf_  = (const float*)d_in[12];
    const float* Pv   = (const float*)d_in[13];
    const float* pv   = (const float*)d_in[14];
    const float* Pm   = (const float*)d_in[15];
    const float* pm   = (const float*)d_in[16];
    const float* Pi   = (const float*)d_in[17];
    const float* pii  = (const float*)d_in[18];
    const float* Pb   = (const float*)d_in[19];
    const float* pb   = (const float*)d_in[20];
    const float* Pc   = (const float*)d_in[21];
    const float* pc   = (const float*)d_in[22];
    const float* Pf   = (const float*)d_in[23];
    const float* pf   = (const float*)d_in[24];
    const float* Wqkv = (const float*)d_in[25];
    const float* bqkv = (const float*)d_in[26];
    const float* Wo   = (const float*)d_in[27];
    const float* bo   = (const float*)d_in[28];
    const float* gg   = (const float*)d_in[29];
    const float* beta = (const float*)d_in[30];
    const float* Wp   = (const float*)d_in[31];
    const float* bp   = (const float*)d_in[32];
    float* out = (float*)d_out;
    u16* ws = (u16*)d_ws;

    convert_weights<<<(CW_TOTAL + 511) / 512, 512, 0, stream>>>(
        Wqkv, Wo, Wp, Pv, Pm, Pi, Pb, Pc, Pf,
        Wv, Wm, Wi, Wb, Wc, Wf, bv, bm, bi, bb, bc, bf_, ws);

    const int Bn = in_sizes[0] / 29;       // 65536
    asmlp_mfma<<<Bn / 8, 512, 0, stream>>>(
        x, pv, pm, pii, pb, pc, pf,
        bqkv, bo, gg, beta, bp, ws, out);
}